// Round 7
// baseline (808.941 us; speedup 1.0000x reference)
//
#include <hip/hip_runtime.h>
#include <hip/hip_bf16.h>
#include <math.h>
#include <stdint.h>

typedef __hip_bfloat16 bf16;

#define NN 16384
#define EE 65536
#define BB 512

typedef __attribute__((ext_vector_type(8))) short short8;
typedef __attribute__((ext_vector_type(4))) float floatx4;

__device__ __forceinline__ float lrelu_f(float x){ return x >= 0.f ? x : 0.01f*x; }

__device__ __forceinline__ float b2f(short s){
    unsigned int u = ((unsigned int)(unsigned short)s) << 16;
    float f; __builtin_memcpy(&f, &u, 4); return f;
}
__device__ __forceinline__ short f2b(float f){
    bf16 b = (bf16)f;
    short s; __builtin_memcpy(&s, &b, 2); return s;
}

// async 16B global->LDS. LDS dest is wave-uniform base; lane i lands at base+16*i.
__device__ __forceinline__ void gl2lds16(const void* g, void* l){
    __builtin_amdgcn_global_load_lds(
        (__attribute__((address_space(1))) unsigned int*)(uintptr_t)g,
        (__attribute__((address_space(3))) unsigned int*)(uintptr_t)l, 16, 0, 0);
}

// ================= MFMA bf16 GEMM: C[m,n] = A[m,:K] @ W[:,n] + bias[n] =================
// A: bf16 [M, lda] row-major. Bt: bf16 [N, ldb] N-MAJOR k-contiguous. C: bf16 [M, ldc].
// M,N multiples of 128; K mult of 32. Epilogue: LDS swizzle -> dwordx4 stores
// (scalar 2B C-stores were VMEM-issue-bound: 1.3 stores/cyc/CU measured R5).
__global__ __launch_bounds__(256)
void mfma_gemm(const bf16* __restrict__ A, int lda,
               const bf16* __restrict__ Bt, int ldb,
               const float* __restrict__ bias,
               bf16* __restrict__ C, int ldc, int K)
{
    __shared__ bf16 As[128*32];     // As[r][k]
    __shared__ bf16 Bs[128*32];     // Bs[n][k]
    __shared__ bf16 epi[4*64*40];   // per-wave 64x32 epilogue tile, row stride 40 (16B-aligned)
    const int tid  = threadIdx.x;
    const int wave = tid >> 6;
    const int lane = tid & 63;
    const int wm = (wave & 1) * 64;
    const int wn = (wave >> 1) * 64;
    const int m0 = blockIdx.y * 128;
    const int n0 = blockIdx.x * 128;

    const int srow = lane >> 2;
    const int scol = (lane & 3) * 8;
    const int arow = lane & 15;
    const int aq   = (lane >> 4) * 8;

    floatx4 acc[4][4];
    #pragma unroll
    for (int i=0;i<4;i++)
        #pragma unroll
        for (int j=0;j<4;j++) acc[i][j] = (floatx4){0.f,0.f,0.f,0.f};

    for (int k0 = 0; k0 < K; k0 += 32) {
        #pragma unroll
        for (int i = 0; i < 2; i++) {
            const int chunk = wave*2 + i;
            const int r = chunk*16 + srow;
            gl2lds16(A  + (size_t)(m0 + r)*lda + k0 + scol, As + chunk*512);
            gl2lds16(Bt + (size_t)(n0 + r)*ldb + k0 + scol, Bs + chunk*512);
        }
        __syncthreads();
        short8 af[4], bf_[4];
        #pragma unroll
        for (int i=0;i<4;i++) af[i]  = *(const short8*)(As + (wm + i*16 + arow)*32 + aq);
        #pragma unroll
        for (int j=0;j<4;j++) bf_[j] = *(const short8*)(Bs + (wn + j*16 + arow)*32 + aq);
        #pragma unroll
        for (int i=0;i<4;i++)
            #pragma unroll
            for (int j=0;j<4;j++)
                acc[i][j] = __builtin_amdgcn_mfma_f32_16x16x32_bf16(af[i], bf_[j], acc[i][j], 0,0,0);
        __syncthreads();
    }
    // epilogue: C-layout (col=lane&15, row=(lane>>4)*4+r) -> LDS -> contiguous 16B stores
    const int crow = (lane >> 4) * 4;
    const int ccol = lane & 15;
    const int erow = lane >> 2;
    const int ecol = (lane & 3) * 8;
    bf16* ep = epi + wave * (64*40);
    #pragma unroll
    for (int j2 = 0; j2 < 2; j2++){
        if (j2) __syncthreads();
        #pragma unroll
        for (int jj = 0; jj < 2; jj++){
            const int j = j2*2 + jj;
            const float bsv = bias[n0 + wn + j*16 + ccol];
            #pragma unroll
            for (int i = 0; i < 4; i++)
                #pragma unroll
                for (int r = 0; r < 4; r++)
                    ep[(i*16 + crow + r)*40 + jj*16 + ccol] = (bf16)(acc[i][j][r] + bsv);
        }
        __syncthreads();
        #pragma unroll
        for (int q = 0; q < 4; q++){
            const int rr = q*16 + erow;
            short8 vv = *(const short8*)(ep + rr*40 + ecol);
            *(short8*)(C + (size_t)(m0 + wm + rr)*ldc + n0 + wn + j2*32 + ecol) = vv;
        }
    }
}

// ================= combined weight/bias prep (1 dispatch) =================
__global__ void prep_all_kernel(const float* __restrict__ wq1, const float* __restrict__ wk1,
                                const float* __restrict__ wv1, const float* __restrict__ ws1,
                                const float* __restrict__ bq1, const float* __restrict__ bk1,
                                const float* __restrict__ bv1, const float* __restrict__ bs1,
                                const float* __restrict__ wq2, const float* __restrict__ wk2,
                                const float* __restrict__ wv2, const float* __restrict__ ws2,
                                const float* __restrict__ bq2, const float* __restrict__ bk2,
                                const float* __restrict__ bv2, const float* __restrict__ bs2v,
                                bf16* __restrict__ W1t, float* __restrict__ b1c,
                                bf16* __restrict__ W2t, float* __restrict__ b2c)
{
    int i = blockIdx.x*256 + threadIdx.x;
    if (i < 98304){                      // W1t: [1024][96]
        int n = i / 96, k = i - n*96;
        const float* w = (n<256)?wq1:(n<512)?wk1:(n<768)?wv1:ws1;
        W1t[i] = (k < 78) ? (bf16)w[(size_t)k*256 + (n & 255)] : (bf16)0.f;
        return;
    }
    i -= 98304;
    if (i < 1024){                       // b1c
        const float* b = (i<256)?bq1:(i<512)?bk1:(i<768)?bv1:bs1;
        b1c[i] = b[i & 255];
        return;
    }
    i -= 1024;
    if (i < 1048576){                    // W2t: [2][2048][256]
        int k = i & 255;
        int j = (i >> 8) & 2047;
        int h = i >> 19;
        const float* w = (j<512)?wq2:(j<1024)?wk2:(j<1536)?wv2:ws2;
        W2t[i] = (bf16)w[(size_t)k*1024 + h*512 + (j & 511)];
        return;
    }
    i -= 1048576;
    if (i < 4096){                       // b2c
        int j = i & 2047, h = i >> 11;
        const float* b = (j<512)?bq2:(j<1024)?bk2:(j<1536)?bv2:bs2v;
        b2c[i] = b[h*512 + (j & 511)];
    }
}

__global__ void cvt_x_kernel(const float* __restrict__ x1, const float* __restrict__ x2,
                             bf16* __restrict__ xa){
    int i = blockIdx.x*256 + threadIdx.x;          // 2*NN*96
    int r = i / 96, c = i - r*96;
    const float* x = (r >= NN) ? x2 : x1;
    int lr = r & (NN-1);
    xa[i] = (c < 78) ? (bf16)x[(size_t)lr*78 + c] : (bf16)0.f;
}

// ================= fp32 GEMM, split-K via atomicAdd; input transform on A-load =========
// TIN: 0 raw; 2 lrelu(v+inb[k]); 3 lrelu((v+inb[k])*bns*gam[k]+bet[k]).
// Output is RAW sums (bias/act folded into the consumer). C must be pre-zeroed.
template<int TIN>
__global__ __launch_bounds__(256)
void skgemm(const float* __restrict__ A, int lda,
            const float* __restrict__ W, int ldw,
            const float* __restrict__ inb, const float* __restrict__ gam,
            const float* __restrict__ bet, float bns,
            float* __restrict__ C, int ldc,
            int M, int N, int K, int Kc)
{
    __shared__ float As[16][68];
    __shared__ float Bs[16][68];
    const int tid = threadIdx.x;
    const int tx = tid & 15;
    const int ty = tid >> 4;
    const int m0 = blockIdx.y * 64;
    const int n0 = blockIdx.x * 64;
    const int kb = blockIdx.z * Kc;
    const int ke = min(K, kb + Kc);
    float acc[4][4];
    #pragma unroll
    for (int i=0;i<4;i++)
        #pragma unroll
        for (int j=0;j<4;j++) acc[i][j]=0.f;

    for (int k0=kb; k0<ke; k0+=16) {
        #pragma unroll
        for (int i=0;i<4;i++){
            int idx = tid + i*256;
            int r = idx >> 4, c = idx & 15;
            int kk = k0 + c;
            float v = 0.f;
            if (kk < ke){
                v = A[(size_t)(m0+r)*lda + kk];
                if (TIN==2) v = lrelu_f(v + inb[kk]);
                if (TIN==3) v = lrelu_f((v + inb[kk])*bns*gam[kk] + bet[kk]);
            }
            As[c][r] = v;
        }
        #pragma unroll
        for (int i=0;i<4;i++){
            int idx = tid + i*256;
            int r = idx >> 6, c = idx & 63;
            int kk = k0 + r;
            Bs[r][c] = (kk < ke) ? W[(size_t)kk*ldw + n0 + c] : 0.f;
        }
        __syncthreads();
        #pragma unroll
        for (int kk=0;kk<16;kk++){
            float a[4], b[4];
            #pragma unroll
            for (int i=0;i<4;i++) a[i] = As[kk][ty*4+i];
            #pragma unroll
            for (int j=0;j<4;j++) b[j] = Bs[kk][tx*4+j];
            #pragma unroll
            for (int i=0;i<4;i++)
                #pragma unroll
                for (int j=0;j<4;j++) acc[i][j] += a[i]*b[j];
        }
        __syncthreads();
    }
    #pragma unroll
    for (int i=0;i<4;i++){
        int m = m0 + ty*4 + i;
        #pragma unroll
        for (int j=0;j<4;j++){
            int n = n0 + tx*4 + j;
            atomicAdd(&C[(size_t)m*ldc + n], acc[i][j]);
        }
    }
}

// ================= CSR build (both branches, stacked) =================
__global__ void hist_kernel(const int* __restrict__ ei1, const int* __restrict__ ei2,
                            int* __restrict__ cnt){
    int eg = blockIdx.x*256 + threadIdx.x;     // 0..2EE
    int br = eg >> 16, e = eg & (EE-1);
    const int* ei = br ? ei2 : ei1;
    atomicAdd(&cnt[br*NN + ei[EE + e]], 1);
}

__global__ __launch_bounds__(1024)
void scan_kernel(const int* __restrict__ hist, int* __restrict__ rowptr){
    const int br = blockIdx.x;
    hist   += br*NN;
    rowptr += br*(NN+1);
    __shared__ int sums[1024];
    const int t = threadIdx.x;
    const int base = t*16;
    int loc[16]; int s = 0;
    #pragma unroll
    for (int i=0;i<16;i++){ loc[i]=s; s += hist[base+i]; }
    sums[t] = s; __syncthreads();
    for (int o=1;o<1024;o<<=1){
        int v = (t>=o) ? sums[t-o] : 0;
        __syncthreads();
        sums[t] += v;
        __syncthreads();
    }
    int pref = (t>0) ? sums[t-1] : 0;
    #pragma unroll
    for (int i=0;i<16;i++) rowptr[base+i] = pref + loc[i];
    if (t==1023) rowptr[NN] = sums[1023];
}

__global__ void scatter_kernel(const int* __restrict__ ei1, const int* __restrict__ ei2,
                               const int* __restrict__ rowptr,
                               int* __restrict__ cnt, int* __restrict__ srcs){
    int eg = blockIdx.x*256 + threadIdx.x;
    int br = eg >> 16, e = eg & (EE-1);
    const int* ei = br ? ei2 : ei1;
    int d = ei[EE + e];
    int pos = rowptr[br*(NN+1) + d] + atomicAdd(&cnt[br*NN + d], 1);
    srcs[br*EE + pos] = ei[e];
}

__global__ void range_kernel(const int* __restrict__ bt1, const int* __restrict__ bt2,
                             int* __restrict__ bps, int* __restrict__ bpe){
    int ng = blockIdx.x*256 + threadIdx.x;     // 0..2NN
    int br = ng >> 14, n = ng & (NN-1);
    const int* bt = br ? bt2 : bt1;
    int b = bt[n];
    if (n==0     || bt[n-1]!=b) bps[br*BB + b] = n;
    if (n==NN-1  || bt[n+1]!=b) bpe[br*BB + b] = n+1;
}

// ================= attention: one wave per (dst node, head), chunked online softmax ====
template<int D, int STACKED>
__global__ __launch_bounds__(256)
void attn_kernel(const bf16* __restrict__ qkvs, int ld, int qo, int ko, int vo, int so, int H,
                 bf16* __restrict__ hout, int ldo,
                 const int* __restrict__ rowptr, const int* __restrict__ srcs)
{
    constexpr int PER = D / 64;
    typedef __attribute__((ext_vector_type(PER))) short shortP;
    const int lane = threadIdx.x & 63;
    const int gw = blockIdx.x * 4 + (threadIdx.x >> 6);
    const int n = gw / H;                 // global node id (stacked: 0..2NN)
    const int h = gw - n*H;
    int nl = n, brNN = 0;
    if (STACKED){
        int br = n >> 14;
        brNN = br*NN; nl = n - brNN;
        rowptr += br*(NN+1); srcs += br*EE;
    }
    const float qscale = rsqrtf((float)D) * 1.44269504f;
    const int hd = h*D + lane*PER;

    const shortP qv = *(const shortP*)(qkvs + (size_t)n*ld + qo + hd);
    float qr[PER];
    #pragma unroll
    for (int i=0;i<PER;i++) qr[i] = b2f(qv[i]) * qscale;

    const int e0 = rowptr[nl], e1 = rowptr[nl+1];
    float m = -INFINITY, z = 0.f;
    float acc[PER];
    #pragma unroll
    for (int i=0;i<PER;i++) acc[i] = 0.f;

    for (int base = e0; base < e1; base += 4){
        const int cnt = min(4, e1 - base);
        int sl = srcs[min(base + (lane & 3), e1 - 1)];
        int src[4];
        #pragma unroll
        for (int j=0;j<4;j++) src[j] = __shfl(sl, j, 64);

        shortP kv[4], vv[4];
        #pragma unroll
        for (int j=0;j<4;j++){
            if (j < cnt){
                const bf16* rp = qkvs + (size_t)(brNN + src[j])*ld;
                kv[j] = *(const shortP*)(rp + ko + hd);
                vv[j] = *(const shortP*)(rp + vo + hd);
            }
        }
        float dt[4];
        #pragma unroll
        for (int j=0;j<4;j++){
            float d = 0.f;
            if (j < cnt){
                #pragma unroll
                for (int i=0;i<PER;i++) d += qr[i]*b2f(kv[j][i]);
            }
            dt[j] = d;
        }
        #pragma unroll
        for (int o=32;o;o>>=1){
            #pragma unroll
            for (int j=0;j<4;j++) dt[j] += __shfl_xor(dt[j], o, 64);
        }
        float cm = -INFINITY;
        #pragma unroll
        for (int j=0;j<4;j++) if (j < cnt) cm = fmaxf(cm, dt[j]);
        const float mn = fmaxf(m, cm);
        const float cs = exp2f(m - mn);
        z *= cs;
        #pragma unroll
        for (int i=0;i<PER;i++) acc[i] *= cs;
        #pragma unroll
        for (int j=0;j<4;j++){
            if (j < cnt){
                const float w = exp2f(dt[j] - mn);
                z += w;
                #pragma unroll
                for (int i=0;i<PER;i++) acc[i] += w*b2f(vv[j][i]);
            }
        }
        m = mn;
    }
    const float invz = 1.0f/(z + 1e-16f);
    const shortP sv = *(const shortP*)(qkvs + (size_t)n*ld + so + hd);
    shortP ov;
    #pragma unroll
    for (int i=0;i<PER;i++) ov[i] = f2b(lrelu_f(b2f(sv[i]) + acc[i]*invz));
    *(shortP*)(hout + (size_t)n*ldo + hd) = ov;
}

// ================= segment-max pool (512 cols, one block per graph) =================
__global__ __launch_bounds__(256)
void pool_kernel(const bf16* __restrict__ h,
                 const int* __restrict__ bps, const int* __restrict__ bpe,
                 float* __restrict__ g, int grow0, int gc0)
{
    typedef __attribute__((ext_vector_type(2))) short short2v;
    const int c = threadIdx.x * 2;
    const int b = blockIdx.x;
    float m0 = -INFINITY, m1 = -INFINITY;
    for (int n = bps[b]; n < bpe[b]; n++){
        const short2v hv = *(const short2v*)(h + (size_t)n*512 + c);
        m0 = fmaxf(m0, b2f(hv[0]));
        m1 = fmaxf(m1, b2f(hv[1]));
    }
    float* gp = g + (size_t)(grow0 + b)*1024 + gc0 + c;
    gp[0] = (m0 == -INFINITY) ? 0.f : m0;
    gp[1] = (m1 == -INFINITY) ? 0.f : m1;
}

// ================= row L2 normalize (generic, used for cell) =================
__global__ __launch_bounds__(256)
void l2n_kernel(const float* __restrict__ in, float* __restrict__ outp,
                int cols, int ldi, int ldo)
{
    __shared__ float red[4];
    const int r = blockIdx.x;
    const int t = threadIdx.x;
    const float* ip = in + (size_t)r*ldi;
    float* op = outp + (size_t)r*ldo;
    float s = 0.f;
    for (int c=t; c<cols; c+=256){ float v = ip[c]; s += v*v; }
    #pragma unroll
    for (int o=32;o;o>>=1) s += __shfl_xor(s, o, 64);
    if ((t & 63) == 0) red[t>>6] = s;
    __syncthreads();
    float tot = red[0]+red[1]+red[2]+red[3];
    float inv = 1.0f / fmaxf(sqrtf(tot), 1e-12f);
    for (int c=t; c<cols; c+=256) op[c] = ip[c]*inv;
}

// gout[2B,128] raw sums -> +bg2 -> per-row l2n -> xc[b*384 + br*128 + c]
__global__ __launch_bounds__(128)
void l2n_gout_kernel(const float* __restrict__ gout, const float* __restrict__ bg2,
                     float* __restrict__ xc)
{
    __shared__ float red[2];
    const int r = blockIdx.x;            // 0..1023
    const int br = r >> 9, b = r & 511;
    const int t = threadIdx.x;           // 128
    float v = gout[(size_t)r*128 + t] + bg2[t];
    float s = v*v;
    #pragma unroll
    for (int o=32;o;o>>=1) s += __shfl_xor(s, o, 64);
    if ((t & 63) == 0) red[t>>6] = s;
    __syncthreads();
    float inv = 1.0f / fmaxf(sqrtf(red[0]+red[1]), 1e-12f);
    xc[(size_t)b*384 + br*128 + t] = v*inv;
}

// xc cols 0-255 in place; cols 256-383 from c3 + br3; l2n over 384
__global__ __launch_bounds__(384)
void l2n_xc_kernel(float* __restrict__ xc, const float* __restrict__ c3,
                   const float* __restrict__ br3)
{
    __shared__ float red[6];
    const int b = blockIdx.x;
    const int t = threadIdx.x;           // 384
    float v = (t < 256) ? xc[(size_t)b*384 + t] : (c3[(size_t)b*128 + (t-256)] + br3[t-256]);
    float s = v*v;
    #pragma unroll
    for (int o=32;o;o>>=1) s += __shfl_xor(s, o, 64);
    if ((t & 63) == 0) red[t>>6] = s;
    __syncthreads();
    float tot = 0.f;
    #pragma unroll
    for (int i=0;i<6;i++) tot += red[i];
    float inv = 1.0f / fmaxf(sqrtf(tot), 1e-12f);
    xc[(size_t)b*384 + t] = v*inv;
}

// f2 raw -> +bf2 -> BN2 -> lrelu -> dot wf3 -> sigmoid
__global__ __launch_bounds__(64)
void final_kernel(const float* __restrict__ f2, const float* __restrict__ bf2,
                  const float* __restrict__ gbn2, const float* __restrict__ bbn2, float bns,
                  const float* __restrict__ w, const float* __restrict__ b,
                  float* __restrict__ outp)
{
    const int r = blockIdx.x;
    const int lane = threadIdx.x;
    float s = 0.f;
    for (int c=lane; c<256; c+=64){
        float t = (f2[(size_t)r*256 + c] + bf2[c])*bns*gbn2[c] + bbn2[c];
        s += lrelu_f(t)*w[c];
    }
    #pragma unroll
    for (int o=32;o;o>>=1) s += __shfl_xor(s, o, 64);
    if (lane==0) outp[r] = 1.0f/(1.0f + expf(-(s + b[0])));
}

extern "C" void kernel_launch(void* const* d_in, const int* in_sizes, int n_in,
                              void* d_out, int out_size, void* d_ws, size_t ws_size,
                              hipStream_t stream)
{
    const float* x1  = (const float*)d_in[0];
    const int*   ei1 = (const int*)  d_in[1];
    const int*   bt1 = (const int*)  d_in[2];
    const float* x2  = (const float*)d_in[3];
    const int*   ei2 = (const int*)  d_in[4];
    const int*   bt2 = (const int*)  d_in[5];
    const float* cell= (const float*)d_in[6];
    const float* wq1=(const float*)d_in[7];  const float* bq1=(const float*)d_in[8];
    const float* wk1=(const float*)d_in[9];  const float* bk1=(const float*)d_in[10];
    const float* wv1=(const float*)d_in[11]; const float* bv1=(const float*)d_in[12];
    const float* ws1=(const float*)d_in[13]; const float* bs1=(const float*)d_in[14];
    const float* wq2=(const float*)d_in[15]; const float* bq2=(const float*)d_in[16];
    const float* wk2=(const float*)d_in[17]; const float* bk2=(const float*)d_in[18];
    const float* wv2=(const float*)d_in[19]; const float* bv2=(const float*)d_in[20];
    const float* ws2=(const float*)d_in[21]; const float* bs2q=(const float*)d_in[22];
    const float* wg1=(const float*)d_in[23]; const float* bg1=(const float*)d_in[24];
    const float* wg2=(const float*)d_in[25]; const float* bg2=(const float*)d_in[26];
    const float* wr1=(const float*)d_in[27]; const float* br1=(const float*)d_in[28];
    const float* wr2=(const float*)d_in[29]; const float* br2=(const float*)d_in[30];
    const float* wr3=(const float*)d_in[31]; const float* br3=(const float*)d_in[32];
    const float* wf1=(const float*)d_in[33]; const float* bf1=(const float*)d_in[34];
    const float* gbn1=(const float*)d_in[35];const float* bbn1=(const float*)d_in[36];
    const float* wf2=(const float*)d_in[37]; const float* bf2=(const float*)d_in[38];
    const float* gbn2=(const float*)d_in[39];const float* bbn2=(const float*)d_in[40];
    const float* wf3=(const float*)d_in[41]; const float* bf3=(const float*)d_in[42];
    float* outp = (float*)d_out;
    (void)in_sizes; (void)n_in; (void)out_size; (void)ws_size;

    const float BNS = 1.0f / sqrtf(1.0f + 1e-5f);

    // ---- workspace arena (~109 MB peak; R region phase-aliased) ----
    char* basep = (char*)d_ws;
    size_t off = 0;
    auto alloc = [&](size_t nbytes)->char* {
        char* p = basep + off;
        off += (nbytes + 255) & ~(size_t)255;
        return p;
    };
    float* xc     = (float*)alloc((size_t)BB*384*4);
    int* rowptr2  = (int*)  alloc((size_t)2*(NN+1)*4);
    int* cnt2     = (int*)  alloc((size_t)2*NN*4);
    int* srcs2    = (int*)  alloc((size_t)2*EE*4);
    // zero-region 1: g + bps + bpe (contiguous)
    char* zg      = alloc(0);
    float* g      = (float*)alloc((size_t)2*BB*1024*4);   // [2B,1024] pooled (raw f32)
    int* bps      = (int*)  alloc((size_t)2*BB*4);
    int* bpe      = (int*)  alloc((size_t)2*BB*4);
    size_t zg_len = (size_t)((char*)(basep+off) - zg);
    float* b1c    = (float*)alloc((size_t)1024*4);
    float* b2c    = (float*)alloc((size_t)4096*4);
    bf16* W1t     = (bf16*) alloc((size_t)1024*96*2);
    bf16* W2t     = (bf16*) alloc((size_t)2*2048*256*2);
    bf16* h1      = (bf16*) alloc((size_t)2*NN*256*2);    // both branches stacked
    // R region (16.8 MB): phase1 xa -> phase2 h2h -> phase3 MLP scratch + cn
    char* R       = alloc((size_t)NN*512*2);
    bf16* xa      = (bf16*)R;                              // [2NN,96]   (6.3 MB)
    bf16* h2h     = (bf16*)R;                              // [NN,512]   (16.8 MB)
    float* gout   = (float*)R;                             // [2B,128]
    float* gh     = (float*)(R + 524288);                  // [2B,512]
    float* c1     = (float*)(R + 524288 + 2097152);        // [B,512]
    float* c2     = c1 + (size_t)BB*512;                   // [B,256]
    float* c3     = c2 + (size_t)BB*256;                   // [B,128]
    float* f1     = c3 + (size_t)BB*128;                   // [B,512]
    float* f2b_   = f1 + (size_t)BB*512;                   // [B,256]
    float* cn     = f2b_ + (size_t)BB*256;                 // [B,954]
    const size_t zmlp_len = 524288 + 2097152 + ((size_t)BB*(512+256+128+512+256))*4; // gout..f2
    bf16* qkvs    = (bf16*) alloc((size_t)NN*2048*2);      // qkvs1 [2NN,1024] / qkvs2 [NN,2048]

    // ---- prep + CSR (both branches in one pass) ----
    (void)hipMemsetAsync(zg,  0, zg_len, stream);           // g, bps, bpe
    (void)hipMemsetAsync(cnt2, 0, (size_t)2*NN*4, stream);
    prep_all_kernel<<<4500,256,0,stream>>>(wq1,wk1,wv1,ws1, bq1,bk1,bv1,bs1,
                                           wq2,wk2,wv2,ws2, bq2,bk2,bv2,bs2q,
                                           W1t,b1c,W2t,b2c);
    hist_kernel<<<2*EE/256,256,0,stream>>>(ei1, ei2, cnt2);
    scan_kernel<<<2,1024,0,stream>>>(cnt2, rowptr2);
    (void)hipMemsetAsync(cnt2, 0, (size_t)2*NN*4, stream);
    scatter_kernel<<<2*EE/256,256,0,stream>>>(ei1, ei2, rowptr2, cnt2, srcs2);
    range_kernel<<<2*NN/256,256,0,stream>>>(bt1, bt2, bps, bpe);

    // ---- layer 1 (both branches stacked): [2NN,96] x [96,1024] -> attn ----
    cvt_x_kernel<<<(2*NN*96)/256,256,0,stream>>>(x1, x2, xa);
    mfma_gemm<<<dim3(1024/128, 2*NN/128),256,0,stream>>>(xa,96, W1t,96, b1c, qkvs,1024, 96);
    attn_kernel<128,1><<<2*NN*2/4,256,0,stream>>>(qkvs,1024, 0,256,512,768, 2, h1,256, rowptr2, srcs2);

    // ---- layer 2: per (branch, head) GEMM + attn + pool ----
    for (int br=0; br<2; br++){
        for (int h=0; h<2; h++){
            mfma_gemm<<<dim3(2048/128, NN/128),256,0,stream>>>(
                h1 + (size_t)br*NN*256, 256, W2t + (size_t)h*2048*256, 256,
                b2c + h*2048, qkvs, 2048, 256);
            attn_kernel<512,0><<<NN/4,256,0,stream>>>(qkvs,2048, 0,512,1024,1536, 1,
                                                      h2h,512, rowptr2 + br*(NN+1), srcs2 + br*EE);
            pool_kernel<<<BB,256,0,stream>>>(h2h, bps + br*BB, bpe + br*BB, g, br*BB, h*512);
        }
    }

    // ---- MLP chains: split-K atomic GEMMs, bias/act folded into consumers ----
    (void)hipMemsetAsync(gout, 0, zmlp_len, stream);   // gout, gh, c1, c2, c3, f1, f2 (h2h dead)
    // graph head (both branches stacked, M=2B=1024)
    skgemm<0><<<dim3(8,16,8),256,0,stream>>>(g,1024,    wg1,512, nullptr,nullptr,nullptr,1.f, gh,512,   1024,512,1024,128);
    skgemm<2><<<dim3(2,16,8),256,0,stream>>>(gh,512,    wg2,128, bg1,    nullptr,nullptr,1.f, gout,128, 1024,128,512, 64);
    l2n_gout_kernel<<<2*BB,128,0,stream>>>(gout, bg2, xc);
    // cell branch
    l2n_kernel<<<BB,256,0,stream>>>(cell, cn, 954, 954, 954);
    skgemm<0><<<dim3(8,8,8),256,0,stream>>>(cn,954,     wr1,512, nullptr,nullptr,nullptr,1.f, c1,512,   512,512,954,120);
    skgemm<2><<<dim3(4,8,8),256,0,stream>>>(c1,512,     wr2,256, br1,    nullptr,nullptr,1.f, c2,256,   512,256,512, 64);
    skgemm<2><<<dim3(2,8,8),256,0,stream>>>(c2,256,     wr3,128, br2,    nullptr,nullptr,1.f, c3,128,   512,128,256, 32);
    l2n_xc_kernel<<<BB,384,0,stream>>>(xc, c3, br3);
    // head MLP
    skgemm<0><<<dim3(8,8,8),256,0,stream>>>(xc,384,     wf1,512, nullptr,nullptr,nullptr,1.f, f1,512,   512,512,384, 48);
    skgemm<3><<<dim3(4,8,8),256,0,stream>>>(f1,512,     wf2,256, bf1,    gbn1,   bbn1,   BNS, f2b_,256, 512,256,512, 64);
    final_kernel<<<BB,64,0,stream>>>(f2b_, bf2, gbn2, bbn2, BNS, wf3, bf3, outp);
}

// Round 8
// 694.382 us; speedup vs baseline: 1.1650x; 1.1650x over previous
//
#include <hip/hip_runtime.h>
#include <hip/hip_bf16.h>
#include <math.h>
#include <stdint.h>

typedef __hip_bfloat16 bf16;

#define NN 16384
#define EE 65536
#define BB 512

typedef __attribute__((ext_vector_type(8))) short short8;
typedef __attribute__((ext_vector_type(4))) float floatx4;

__device__ __forceinline__ float lrelu_f(float x){ return x >= 0.f ? x : 0.01f*x; }

__device__ __forceinline__ float b2f(short s){
    unsigned int u = ((unsigned int)(unsigned short)s) << 16;
    float f; __builtin_memcpy(&f, &u, 4); return f;
}
__device__ __forceinline__ short f2b(float f){
    bf16 b = (bf16)f;
    short s; __builtin_memcpy(&s, &b, 2); return s;
}

// async 16B global->LDS. LDS dest is wave-uniform base; lane i lands at base+16*i.
__device__ __forceinline__ void gl2lds16(const void* g, void* l){
    __builtin_amdgcn_global_load_lds(
        (__attribute__((address_space(1))) unsigned int*)(uintptr_t)g,
        (__attribute__((address_space(3))) unsigned int*)(uintptr_t)l, 16, 0, 0);
}

// ================= MFMA bf16 GEMM: C[m,n] = A[m,:K] @ W[:,n] + bias[n] =================
// A: bf16 [M, lda] row-major. Bt: bf16 [N, ldb] N-MAJOR k-contiguous. C: bf16 [M, ldc].
// M,N multiples of 128; K mult of 32. Epilogue: LDS swizzle -> dwordx4 stores.
__global__ __launch_bounds__(256)
void mfma_gemm(const bf16* __restrict__ A, int lda,
               const bf16* __restrict__ Bt, int ldb,
               const float* __restrict__ bias,
               bf16* __restrict__ C, int ldc, int K)
{
    __shared__ bf16 As[128*32];     // As[r][k]
    __shared__ bf16 Bs[128*32];     // Bs[n][k]
    __shared__ bf16 epi[4*64*40];   // per-wave 64x32 epilogue tile, row stride 40
    const int tid  = threadIdx.x;
    const int wave = tid >> 6;
    const int lane = tid & 63;
    const int wm = (wave & 1) * 64;
    const int wn = (wave >> 1) * 64;
    const int m0 = blockIdx.y * 128;
    const int n0 = blockIdx.x * 128;

    const int srow = lane >> 2;
    const int scol = (lane & 3) * 8;
    const int arow = lane & 15;
    const int aq   = (lane >> 4) * 8;

    floatx4 acc[4][4];
    #pragma unroll
    for (int i=0;i<4;i++)
        #pragma unroll
        for (int j=0;j<4;j++) acc[i][j] = (floatx4){0.f,0.f,0.f,0.f};

    for (int k0 = 0; k0 < K; k0 += 32) {
        #pragma unroll
        for (int i = 0; i < 2; i++) {
            const int chunk = wave*2 + i;
            const int r = chunk*16 + srow;
            gl2lds16(A  + (size_t)(m0 + r)*lda + k0 + scol, As + chunk*512);
            gl2lds16(Bt + (size_t)(n0 + r)*ldb + k0 + scol, Bs + chunk*512);
        }
        __syncthreads();
        short8 af[4], bf_[4];
        #pragma unroll
        for (int i=0;i<4;i++) af[i]  = *(const short8*)(As + (wm + i*16 + arow)*32 + aq);
        #pragma unroll
        for (int j=0;j<4;j++) bf_[j] = *(const short8*)(Bs + (wn + j*16 + arow)*32 + aq);
        #pragma unroll
        for (int i=0;i<4;i++)
            #pragma unroll
            for (int j=0;j<4;j++)
                acc[i][j] = __builtin_amdgcn_mfma_f32_16x16x32_bf16(af[i], bf_[j], acc[i][j], 0,0,0);
        __syncthreads();
    }
    const int crow = (lane >> 4) * 4;
    const int ccol = lane & 15;
    const int erow = lane >> 2;
    const int ecol = (lane & 3) * 8;
    bf16* ep = epi + wave * (64*40);
    #pragma unroll
    for (int j2 = 0; j2 < 2; j2++){
        if (j2) __syncthreads();
        #pragma unroll
        for (int jj = 0; jj < 2; jj++){
            const int j = j2*2 + jj;
            const float bsv = bias[n0 + wn + j*16 + ccol];
            #pragma unroll
            for (int i = 0; i < 4; i++)
                #pragma unroll
                for (int r = 0; r < 4; r++)
                    ep[(i*16 + crow + r)*40 + jj*16 + ccol] = (bf16)(acc[i][j][r] + bsv);
        }
        __syncthreads();
        #pragma unroll
        for (int q = 0; q < 4; q++){
            const int rr = q*16 + erow;
            short8 vv = *(const short8*)(ep + rr*40 + ecol);
            *(short8*)(C + (size_t)(m0 + wm + rr)*ldc + n0 + wn + j2*32 + ecol) = vv;
        }
    }
}

// ================= combined weight/bias prep (1 dispatch) =================
__global__ void prep_all_kernel(const float* __restrict__ wq1, const float* __restrict__ wk1,
                                const float* __restrict__ wv1, const float* __restrict__ ws1,
                                const float* __restrict__ bq1, const float* __restrict__ bk1,
                                const float* __restrict__ bv1, const float* __restrict__ bs1,
                                const float* __restrict__ wq2, const float* __restrict__ wk2,
                                const float* __restrict__ wv2, const float* __restrict__ ws2,
                                const float* __restrict__ bq2, const float* __restrict__ bk2,
                                const float* __restrict__ bv2, const float* __restrict__ bs2v,
                                bf16* __restrict__ W1t, float* __restrict__ b1c,
                                bf16* __restrict__ W2t, float* __restrict__ b2c)
{
    int i = blockIdx.x*256 + threadIdx.x;
    if (i < 98304){                      // W1t: [1024][96]
        int n = i / 96, k = i - n*96;
        const float* w = (n<256)?wq1:(n<512)?wk1:(n<768)?wv1:ws1;
        W1t[i] = (k < 78) ? (bf16)w[(size_t)k*256 + (n & 255)] : (bf16)0.f;
        return;
    }
    i -= 98304;
    if (i < 1024){                       // b1c
        const float* b = (i<256)?bq1:(i<512)?bk1:(i<768)?bv1:bs1;
        b1c[i] = b[i & 255];
        return;
    }
    i -= 1024;
    if (i < 1048576){                    // W2t: [2][2048][256]
        int k = i & 255;
        int j = (i >> 8) & 2047;
        int h = i >> 19;
        const float* w = (j<512)?wq2:(j<1024)?wk2:(j<1536)?wv2:ws2;
        W2t[i] = (bf16)w[(size_t)k*1024 + h*512 + (j & 511)];
        return;
    }
    i -= 1048576;
    if (i < 4096){                       // b2c
        int j = i & 2047, h = i >> 11;
        const float* b = (j<512)?bq2:(j<1024)?bk2:(j<1536)?bv2:bs2v;
        b2c[i] = b[h*512 + (j & 511)];
    }
}

__global__ void cvt_x_kernel(const float* __restrict__ x1, const float* __restrict__ x2,
                             bf16* __restrict__ xa){
    int i = blockIdx.x*256 + threadIdx.x;          // 2*NN*96
    int r = i / 96, c = i - r*96;
    const float* x = (r >= NN) ? x2 : x1;
    int lr = r & (NN-1);
    xa[i] = (c < 78) ? (bf16)x[(size_t)lr*78 + c] : (bf16)0.f;
}

// ================= CSR build (both branches, stacked) =================
__global__ void hist_kernel(const int* __restrict__ ei1, const int* __restrict__ ei2,
                            int* __restrict__ cnt){
    int eg = blockIdx.x*256 + threadIdx.x;     // 0..2EE
    int br = eg >> 16, e = eg & (EE-1);
    const int* ei = br ? ei2 : ei1;
    atomicAdd(&cnt[br*NN + ei[EE + e]], 1);
}

__global__ __launch_bounds__(1024)
void scan_kernel(const int* __restrict__ hist, int* __restrict__ rowptr){
    const int br = blockIdx.x;
    hist   += br*NN;
    rowptr += br*(NN+1);
    __shared__ int sums[1024];
    const int t = threadIdx.x;
    const int base = t*16;
    int loc[16]; int s = 0;
    #pragma unroll
    for (int i=0;i<16;i++){ loc[i]=s; s += hist[base+i]; }
    sums[t] = s; __syncthreads();
    for (int o=1;o<1024;o<<=1){
        int v = (t>=o) ? sums[t-o] : 0;
        __syncthreads();
        sums[t] += v;
        __syncthreads();
    }
    int pref = (t>0) ? sums[t-1] : 0;
    #pragma unroll
    for (int i=0;i<16;i++) rowptr[base+i] = pref + loc[i];
    if (t==1023) rowptr[NN] = sums[1023];
}

__global__ void scatter_kernel(const int* __restrict__ ei1, const int* __restrict__ ei2,
                               const int* __restrict__ rowptr,
                               int* __restrict__ cnt, int* __restrict__ srcs){
    int eg = blockIdx.x*256 + threadIdx.x;
    int br = eg >> 16, e = eg & (EE-1);
    const int* ei = br ? ei2 : ei1;
    int d = ei[EE + e];
    int pos = rowptr[br*(NN+1) + d] + atomicAdd(&cnt[br*NN + d], 1);
    srcs[br*EE + pos] = ei[e];
}

__global__ void range_kernel(const int* __restrict__ bt1, const int* __restrict__ bt2,
                             int* __restrict__ bps, int* __restrict__ bpe){
    int ng = blockIdx.x*256 + threadIdx.x;     // 0..2NN
    int br = ng >> 14, n = ng & (NN-1);
    const int* bt = br ? bt2 : bt1;
    int b = bt[n];
    if (n==0     || bt[n-1]!=b) bps[br*BB + b] = n;
    if (n==NN-1  || bt[n+1]!=b) bpe[br*BB + b] = n+1;
}

// ================= attention: one wave per (dst node, head), chunked online softmax ====
template<int D, int STACKED>
__global__ __launch_bounds__(256)
void attn_kernel(const bf16* __restrict__ qkvs, int ld, int qo, int ko, int vo, int so, int H,
                 bf16* __restrict__ hout, int ldo,
                 const int* __restrict__ rowptr, const int* __restrict__ srcs)
{
    constexpr int PER = D / 64;
    typedef __attribute__((ext_vector_type(PER))) short shortP;
    const int lane = threadIdx.x & 63;
    const int gw = blockIdx.x * 4 + (threadIdx.x >> 6);
    const int n = gw / H;                 // global node id (stacked: 0..2NN)
    const int h = gw - n*H;
    int nl = n, brNN = 0;
    if (STACKED){
        int br = n >> 14;
        brNN = br*NN; nl = n - brNN;
        rowptr += br*(NN+1); srcs += br*EE;
    }
    const float qscale = rsqrtf((float)D) * 1.44269504f;
    const int hd = h*D + lane*PER;

    const shortP qv = *(const shortP*)(qkvs + (size_t)n*ld + qo + hd);
    float qr[PER];
    #pragma unroll
    for (int i=0;i<PER;i++) qr[i] = b2f(qv[i]) * qscale;

    const int e0 = rowptr[nl], e1 = rowptr[nl+1];
    float m = -INFINITY, z = 0.f;
    float acc[PER];
    #pragma unroll
    for (int i=0;i<PER;i++) acc[i] = 0.f;

    for (int base = e0; base < e1; base += 4){
        const int cnt = min(4, e1 - base);
        int sl = srcs[min(base + (lane & 3), e1 - 1)];
        int src[4];
        #pragma unroll
        for (int j=0;j<4;j++) src[j] = __shfl(sl, j, 64);

        shortP kv[4], vv[4];
        #pragma unroll
        for (int j=0;j<4;j++){
            if (j < cnt){
                const bf16* rp = qkvs + (size_t)(brNN + src[j])*ld;
                kv[j] = *(const shortP*)(rp + ko + hd);
                vv[j] = *(const shortP*)(rp + vo + hd);
            }
        }
        float dt[4];
        #pragma unroll
        for (int j=0;j<4;j++){
            float d = 0.f;
            if (j < cnt){
                #pragma unroll
                for (int i=0;i<PER;i++) d += qr[i]*b2f(kv[j][i]);
            }
            dt[j] = d;
        }
        #pragma unroll
        for (int o=32;o;o>>=1){
            #pragma unroll
            for (int j=0;j<4;j++) dt[j] += __shfl_xor(dt[j], o, 64);
        }
        float cm = -INFINITY;
        #pragma unroll
        for (int j=0;j<4;j++) if (j < cnt) cm = fmaxf(cm, dt[j]);
        const float mn = fmaxf(m, cm);
        const float cs = exp2f(m - mn);
        z *= cs;
        #pragma unroll
        for (int i=0;i<PER;i++) acc[i] *= cs;
        #pragma unroll
        for (int j=0;j<4;j++){
            if (j < cnt){
                const float w = exp2f(dt[j] - mn);
                z += w;
                #pragma unroll
                for (int i=0;i<PER;i++) acc[i] += w*b2f(vv[j][i]);
            }
        }
        m = mn;
    }
    const float invz = 1.0f/(z + 1e-16f);
    const shortP sv = *(const shortP*)(qkvs + (size_t)n*ld + so + hd);
    shortP ov;
    #pragma unroll
    for (int i=0;i<PER;i++) ov[i] = f2b(lrelu_f(b2f(sv[i]) + acc[i]*invz));
    *(shortP*)(hout + (size_t)n*ldo + hd) = ov;
}

// ================= segment-max pool (512 cols, one block per graph) =================
__global__ __launch_bounds__(256)
void pool_kernel(const bf16* __restrict__ h,
                 const int* __restrict__ bps, const int* __restrict__ bpe,
                 float* __restrict__ g, int grow0, int gc0)
{
    typedef __attribute__((ext_vector_type(2))) short short2v;
    const int c = threadIdx.x * 2;
    const int b = blockIdx.x;
    float m0 = -INFINITY, m1 = -INFINITY;
    for (int n = bps[b]; n < bpe[b]; n++){
        const short2v hv = *(const short2v*)(h + (size_t)n*512 + c);
        m0 = fmaxf(m0, b2f(hv[0]));
        m1 = fmaxf(m1, b2f(hv[1]));
    }
    float* gp = g + (size_t)(grow0 + b)*1024 + gc0 + c;
    gp[0] = (m0 == -INFINITY) ? 0.f : m0;
    gp[1] = (m1 == -INFINITY) ? 0.f : m1;
}

// ================= fused MLP tail: dense step helper =================
// C[r][j] = act( sum_k A[r][k]*W[k][j] + bias[j] ), A/C in LDS, W/bias global.
// N>=256: CPT=N/256 adjacent cols/thread, all R rows. N==128: 2 row-groups.
// ACT: 0 none, 1 lrelu, 2 BN+lrelu: lrelu((v+bias)*bns*gam+bet)
template<int R, int N, int ACT>
__device__ __forceinline__ void dense_step(
    const float* __restrict__ W, const float* __restrict__ bias,
    const float* __restrict__ gam, const float* __restrict__ bet, float bns,
    const float* A, int lda, float* C, int ldc, int K, int tid)
{
    constexpr int CPT = (N >= 256) ? N/256 : 1;
    constexpr int G   = (N >= 256) ? 1 : 256/N;
    constexpr int RG  = R / G;
    const int jt  = (N >= 256) ? tid*CPT : (tid & (N-1));
    const int grp = (N >= 256) ? 0 : (tid / N);
    const float* Ab = A + grp*RG*lda;

    float acc[RG][CPT];
    #pragma unroll
    for (int r=0;r<RG;r++)
        #pragma unroll
        for (int c=0;c<CPT;c++) acc[r][c] = 0.f;

    int k = 0;
    for (; k + 4 <= K; k += 4){
        float w[4][CPT];
        #pragma unroll
        for (int u=0;u<4;u++)
            #pragma unroll
            for (int c=0;c<CPT;c++) w[u][c] = W[(size_t)(k+u)*N + jt + c];
        #pragma unroll
        for (int r=0;r<RG;r++){
            const floatx4 av = *(const floatx4*)(Ab + r*lda + k);
            #pragma unroll
            for (int u=0;u<4;u++)
                #pragma unroll
                for (int c=0;c<CPT;c++) acc[r][c] += av[u]*w[u][c];
        }
    }
    for (; k < K; k++){
        float w[CPT];
        #pragma unroll
        for (int c=0;c<CPT;c++) w[c] = W[(size_t)k*N + jt + c];
        #pragma unroll
        for (int r=0;r<RG;r++){
            const float a = Ab[r*lda + k];
            #pragma unroll
            for (int c=0;c<CPT;c++) acc[r][c] += a*w[c];
        }
    }
    #pragma unroll
    for (int r=0;r<RG;r++)
        #pragma unroll
        for (int c=0;c<CPT;c++){
            const int j = jt + c;
            float v = acc[r][c] + bias[j];
            if (ACT==1) v = lrelu_f(v);
            if (ACT==2) v = lrelu_f(v*bns*gam[j] + bet[j]);
            C[(grp*RG + r)*ldc + j] = v;
        }
}

// ================= fused tail: graph-head + cell branch + head MLP, 2 graphs/block ====
__global__ __launch_bounds__(256)
void tail_kernel(const float* __restrict__ g,            // [2*BB][1024]
                 const float* __restrict__ cell,         // [BB][954]
                 const float* __restrict__ wg1, const float* __restrict__ bg1,
                 const float* __restrict__ wg2, const float* __restrict__ bg2,
                 const float* __restrict__ wr1, const float* __restrict__ br1,
                 const float* __restrict__ wr2, const float* __restrict__ br2,
                 const float* __restrict__ wr3, const float* __restrict__ br3,
                 const float* __restrict__ wf1, const float* __restrict__ bf1,
                 const float* __restrict__ gbn1, const float* __restrict__ bbn1,
                 const float* __restrict__ wf2, const float* __restrict__ bf2,
                 const float* __restrict__ gbn2, const float* __restrict__ bbn2,
                 const float* __restrict__ wf3, const float* __restrict__ bf3,
                 float bns, float* __restrict__ outp)
{
    __shared__ float Sg[4][1024];    // rows: lg*2 + br
    __shared__ float Sgh[4][512];
    __shared__ float Sgout[4][128];
    __shared__ float Scell[2][960];
    __shared__ float Sc1[2][512];
    __shared__ float Sc2[2][256];
    __shared__ float Sc3[2][128];
    __shared__ float Sxc[2][384];
    __shared__ float Sf1[2][512];
    __shared__ float Sf2[2][256];
    __shared__ float inv4[4], invc[2], invx[2];

    const int tid = threadIdx.x;
    const int wv  = tid >> 6;
    const int ln  = tid & 63;
    const int b0  = blockIdx.x * 2;

    // load g rows (r = lg*2 + br -> g[br*BB + b0+lg]) and cell rows
    #pragma unroll
    for (int i=0;i<16;i++){
        int idx = tid + i*256;           // 4096
        int r = idx >> 10, c = idx & 1023;
        int lg = r >> 1, br = r & 1;
        Sg[r][c] = g[(size_t)(br*BB + b0 + lg)*1024 + c];
    }
    for (int idx = tid; idx < 2*954; idx += 256){
        int r = (idx >= 954) ? 1 : 0;
        int c = idx - r*954;
        Scell[r][c] = cell[(size_t)(b0 + r)*954 + c];
    }
    __syncthreads();

    // cell l2n
    if (wv < 2){
        float s = 0.f;
        for (int c = ln; c < 954; c += 64){ float v = Scell[wv][c]; s += v*v; }
        #pragma unroll
        for (int o=32;o;o>>=1) s += __shfl_xor(s, o, 64);
        if (ln == 0) invc[wv] = 1.0f / fmaxf(sqrtf(s), 1e-12f);
    }
    __syncthreads();
    #pragma unroll
    for (int r=0;r<2;r++)
        for (int c = tid; c < 954; c += 256) Scell[r][c] *= invc[r];
    __syncthreads();

    // graph head: gh = lrelu(g@wg1+bg1); gout = gh@wg2 + bg2
    dense_step<4,512,1>(wg1, bg1, nullptr, nullptr, 1.f, &Sg[0][0],   1024, &Sgh[0][0],  512, 1024, tid);
    __syncthreads();
    dense_step<4,128,0>(wg2, bg2, nullptr, nullptr, 1.f, &Sgh[0][0],  512,  &Sgout[0][0],128, 512,  tid);
    // cell: c1 = lrelu(cn@wr1+br1); c2 = lrelu(c1@wr2+br2); c3 = c2@wr3+br3
    __syncthreads();
    dense_step<2,512,1>(wr1, br1, nullptr, nullptr, 1.f, &Scell[0][0], 960, &Sc1[0][0],  512, 954,  tid);
    __syncthreads();
    dense_step<2,256,1>(wr2, br2, nullptr, nullptr, 1.f, &Sc1[0][0],   512, &Sc2[0][0],  256, 512,  tid);
    __syncthreads();
    dense_step<2,128,0>(wr3, br3, nullptr, nullptr, 1.f, &Sc2[0][0],   256, &Sc3[0][0],  128, 256,  tid);
    __syncthreads();

    // l2n per gout row (4 rows x 128)
    if (wv < 4){
        float a = Sgout[wv][ln], bq = Sgout[wv][ln+64];
        float s = a*a + bq*bq;
        #pragma unroll
        for (int o=32;o;o>>=1) s += __shfl_xor(s, o, 64);
        if (ln == 0) inv4[wv] = 1.0f / fmaxf(sqrtf(s), 1e-12f);
    }
    __syncthreads();

    // build xc rows (2 x 384) then l2n
    #pragma unroll
    for (int lg=0; lg<2; lg++){
        for (int j = tid; j < 384; j += 256){
            float v;
            if (j < 128)      v = Sgout[lg*2+0][j]       * inv4[lg*2+0];
            else if (j < 256) v = Sgout[lg*2+1][j-128]   * inv4[lg*2+1];
            else              v = Sc3[lg][j-256];
            Sxc[lg][j] = v;
        }
    }
    __syncthreads();
    if (wv < 2){
        float s = 0.f;
        #pragma unroll
        for (int i=0;i<6;i++){ float v = Sxc[wv][ln + i*64]; s += v*v; }
        #pragma unroll
        for (int o=32;o;o>>=1) s += __shfl_xor(s, o, 64);
        if (ln == 0) invx[wv] = 1.0f / fmaxf(sqrtf(s), 1e-12f);
    }
    __syncthreads();
    #pragma unroll
    for (int lg=0; lg<2; lg++)
        for (int j = tid; j < 384; j += 256) Sxc[lg][j] *= invx[lg];
    __syncthreads();

    // head MLP: f1 = lrelu(BN1(xc@wf1+bf1)); f2 = lrelu(BN2(f1@wf2+bf2))
    dense_step<2,512,2>(wf1, bf1, gbn1, bbn1, bns, &Sxc[0][0], 384, &Sf1[0][0], 512, 384, tid);
    __syncthreads();
    dense_step<2,256,2>(wf2, bf2, gbn2, bbn2, bns, &Sf1[0][0], 512, &Sf2[0][0], 256, 512, tid);
    __syncthreads();

    // final dot + sigmoid
    if (wv < 2){
        float s = 0.f;
        #pragma unroll
        for (int i=0;i<4;i++){ int c = ln + i*64; s += Sf2[wv][c]*wf3[c]; }
        #pragma unroll
        for (int o=32;o;o>>=1) s += __shfl_xor(s, o, 64);
        if (ln == 0) outp[b0 + wv] = 1.0f/(1.0f + expf(-(s + bf3[0])));
    }
}

extern "C" void kernel_launch(void* const* d_in, const int* in_sizes, int n_in,
                              void* d_out, int out_size, void* d_ws, size_t ws_size,
                              hipStream_t stream)
{
    const float* x1  = (const float*)d_in[0];
    const int*   ei1 = (const int*)  d_in[1];
    const int*   bt1 = (const int*)  d_in[2];
    const float* x2  = (const float*)d_in[3];
    const int*   ei2 = (const int*)  d_in[4];
    const int*   bt2 = (const int*)  d_in[5];
    const float* cell= (const float*)d_in[6];
    const float* wq1=(const float*)d_in[7];  const float* bq1=(const float*)d_in[8];
    const float* wk1=(const float*)d_in[9];  const float* bk1=(const float*)d_in[10];
    const float* wv1=(const float*)d_in[11]; const float* bv1=(const float*)d_in[12];
    const float* ws1=(const float*)d_in[13]; const float* bs1=(const float*)d_in[14];
    const float* wq2=(const float*)d_in[15]; const float* bq2=(const float*)d_in[16];
    const float* wk2=(const float*)d_in[17]; const float* bk2=(const float*)d_in[18];
    const float* wv2=(const float*)d_in[19]; const float* bv2=(const float*)d_in[20];
    const float* ws2=(const float*)d_in[21]; const float* bs2q=(const float*)d_in[22];
    const float* wg1=(const float*)d_in[23]; const float* bg1=(const float*)d_in[24];
    const float* wg2=(const float*)d_in[25]; const float* bg2=(const float*)d_in[26];
    const float* wr1=(const float*)d_in[27]; const float* br1=(const float*)d_in[28];
    const float* wr2=(const float*)d_in[29]; const float* br2=(const float*)d_in[30];
    const float* wr3=(const float*)d_in[31]; const float* br3=(const float*)d_in[32];
    const float* wf1=(const float*)d_in[33]; const float* bf1=(const float*)d_in[34];
    const float* gbn1=(const float*)d_in[35];const float* bbn1=(const float*)d_in[36];
    const float* wf2=(const float*)d_in[37]; const float* bf2=(const float*)d_in[38];
    const float* gbn2=(const float*)d_in[39];const float* bbn2=(const float*)d_in[40];
    const float* wf3=(const float*)d_in[41]; const float* bf3=(const float*)d_in[42];
    float* outp = (float*)d_out;
    (void)in_sizes; (void)n_in; (void)out_size; (void)ws_size;

    const float BNS = 1.0f / sqrtf(1.0f + 1e-5f);

    // ---- workspace arena (R region phase-aliased xa -> h2h) ----
    char* basep = (char*)d_ws;
    size_t off = 0;
    auto alloc = [&](size_t nbytes)->char* {
        char* p = basep + off;
        off += (nbytes + 255) & ~(size_t)255;
        return p;
    };
    int* rowptr2  = (int*)  alloc((size_t)2*(NN+1)*4);
    int* cnt2     = (int*)  alloc((size_t)2*NN*4);
    int* srcs2    = (int*)  alloc((size_t)2*EE*4);
    float* g      = (float*)alloc((size_t)2*BB*1024*4);   // [2B,1024] pooled (raw f32)
    int* bps      = (int*)  alloc((size_t)2*BB*4);
    int* bpe      = (int*)  alloc((size_t)2*BB*4);
    float* b1c    = (float*)alloc((size_t)1024*4);
    float* b2c    = (float*)alloc((size_t)4096*4);
    bf16* W1t     = (bf16*) alloc((size_t)1024*96*2);
    bf16* W2t     = (bf16*) alloc((size_t)2*2048*256*2);
    bf16* h1      = (bf16*) alloc((size_t)2*NN*256*2);    // both branches stacked
    char* R       = alloc((size_t)NN*512*2);              // xa [2NN,96] -> h2h [NN,512]
    bf16* xa      = (bf16*)R;
    bf16* h2h     = (bf16*)R;
    bf16* qkvs    = (bf16*) alloc((size_t)NN*2048*2);     // qkvs1 [2NN,1024] / qkvs2 [NN,2048]

    // ---- prep + CSR (both branches in one pass) ----
    (void)hipMemsetAsync(bps, 0, (size_t)4*BB*4, stream);   // bps+bpe adjacent
    (void)hipMemsetAsync(cnt2, 0, (size_t)2*NN*4, stream);
    prep_all_kernel<<<4500,256,0,stream>>>(wq1,wk1,wv1,ws1, bq1,bk1,bv1,bs1,
                                           wq2,wk2,wv2,ws2, bq2,bk2,bv2,bs2q,
                                           W1t,b1c,W2t,b2c);
    hist_kernel<<<2*EE/256,256,0,stream>>>(ei1, ei2, cnt2);
    scan_kernel<<<2,1024,0,stream>>>(cnt2, rowptr2);
    (void)hipMemsetAsync(cnt2, 0, (size_t)2*NN*4, stream);
    scatter_kernel<<<2*EE/256,256,0,stream>>>(ei1, ei2, rowptr2, cnt2, srcs2);
    range_kernel<<<2*NN/256,256,0,stream>>>(bt1, bt2, bps, bpe);

    // ---- layer 1 (both branches stacked): [2NN,96] x [96,1024] -> attn ----
    cvt_x_kernel<<<(2*NN*96)/256,256,0,stream>>>(x1, x2, xa);
    mfma_gemm<<<dim3(1024/128, 2*NN/128),256,0,stream>>>(xa,96, W1t,96, b1c, qkvs,1024, 96);
    attn_kernel<128,1><<<2*NN*2/4,256,0,stream>>>(qkvs,1024, 0,256,512,768, 2, h1,256, rowptr2, srcs2);

    // ---- layer 2: per (branch, head) GEMM + attn + pool ----
    for (int br=0; br<2; br++){
        for (int h=0; h<2; h++){
            mfma_gemm<<<dim3(2048/128, NN/128),256,0,stream>>>(
                h1 + (size_t)br*NN*256, 256, W2t + (size_t)h*2048*256, 256,
                b2c + h*2048, qkvs, 2048, 256);
            attn_kernel<512,0><<<NN/4,256,0,stream>>>(qkvs,2048, 0,512,1024,1536, 1,
                                                      h2h,512, rowptr2 + br*(NN+1), srcs2 + br*EE);
            pool_kernel<<<BB,256,0,stream>>>(h2h, bps + br*BB, bpe + br*BB, g, br*BB, h*512);
        }
    }

    // ---- fused tail: graph-head + cell + head MLP + sigmoid, one dispatch ----
    tail_kernel<<<BB/2,256,0,stream>>>(g, cell,
                                       wg1,bg1, wg2,bg2, wr1,br1, wr2,br2, wr3,br3,
                                       wf1,bf1, gbn1,bbn1, wf2,bf2, gbn2,bbn2, wf3,bf3,
                                       BNS, outp);
}

// Round 9
// 662.848 us; speedup vs baseline: 1.2204x; 1.0476x over previous
//
#include <hip/hip_runtime.h>
#include <hip/hip_bf16.h>
#include <math.h>
#include <stdint.h>

typedef __hip_bfloat16 bf16;

#define NN 16384
#define EE 65536
#define BB 512

typedef __attribute__((ext_vector_type(8))) short short8;
typedef __attribute__((ext_vector_type(4))) float floatx4;

__device__ __forceinline__ float lrelu_f(float x){ return x >= 0.f ? x : 0.01f*x; }

__device__ __forceinline__ float b2f(short s){
    unsigned int u = ((unsigned int)(unsigned short)s) << 16;
    float f; __builtin_memcpy(&f, &u, 4); return f;
}
__device__ __forceinline__ short f2b(float f){
    bf16 b = (bf16)f;
    short s; __builtin_memcpy(&s, &b, 2); return s;
}

// async 16B global->LDS. LDS dest is wave-uniform base; lane i lands at base+16*i.
__device__ __forceinline__ void gl2lds16(const void* g, void* l){
    __builtin_amdgcn_global_load_lds(
        (__attribute__((address_space(1))) unsigned int*)(uintptr_t)g,
        (__attribute__((address_space(3))) unsigned int*)(uintptr_t)l, 16, 0, 0);
}

// ================= MFMA bf16 GEMM: C[m,n] = A[m,:K] @ W[:,n] + bias[n] =================
__global__ __launch_bounds__(256)
void mfma_gemm(const bf16* __restrict__ A, int lda,
               const bf16* __restrict__ Bt, int ldb,
               const float* __restrict__ bias,
               bf16* __restrict__ C, int ldc, int K)
{
    __shared__ bf16 As[128*32];     // As[r][k]
    __shared__ bf16 Bs[128*32];     // Bs[n][k]
    __shared__ bf16 epi[4*64*40];   // per-wave 64x32 epilogue tile, row stride 40
    const int tid  = threadIdx.x;
    const int wave = tid >> 6;
    const int lane = tid & 63;
    const int wm = (wave & 1) * 64;
    const int wn = (wave >> 1) * 64;
    const int m0 = blockIdx.y * 128;
    const int n0 = blockIdx.x * 128;

    const int srow = lane >> 2;
    const int scol = (lane & 3) * 8;
    const int arow = lane & 15;
    const int aq   = (lane >> 4) * 8;

    floatx4 acc[4][4];
    #pragma unroll
    for (int i=0;i<4;i++)
        #pragma unroll
        for (int j=0;j<4;j++) acc[i][j] = (floatx4){0.f,0.f,0.f,0.f};

    for (int k0 = 0; k0 < K; k0 += 32) {
        #pragma unroll
        for (int i = 0; i < 2; i++) {
            const int chunk = wave*2 + i;
            const int r = chunk*16 + srow;
            gl2lds16(A  + (size_t)(m0 + r)*lda + k0 + scol, As + chunk*512);
            gl2lds16(Bt + (size_t)(n0 + r)*ldb + k0 + scol, Bs + chunk*512);
        }
        __syncthreads();
        short8 af[4], bf_[4];
        #pragma unroll
        for (int i=0;i<4;i++) af[i]  = *(const short8*)(As + (wm + i*16 + arow)*32 + aq);
        #pragma unroll
        for (int j=0;j<4;j++) bf_[j] = *(const short8*)(Bs + (wn + j*16 + arow)*32 + aq);
        #pragma unroll
        for (int i=0;i<4;i++)
            #pragma unroll
            for (int j=0;j<4;j++)
                acc[i][j] = __builtin_amdgcn_mfma_f32_16x16x32_bf16(af[i], bf_[j], acc[i][j], 0,0,0);
        __syncthreads();
    }
    const int crow = (lane >> 4) * 4;
    const int ccol = lane & 15;
    const int erow = lane >> 2;
    const int ecol = (lane & 3) * 8;
    bf16* ep = epi + wave * (64*40);
    #pragma unroll
    for (int j2 = 0; j2 < 2; j2++){
        if (j2) __syncthreads();
        #pragma unroll
        for (int jj = 0; jj < 2; jj++){
            const int j = j2*2 + jj;
            const float bsv = bias[n0 + wn + j*16 + ccol];
            #pragma unroll
            for (int i = 0; i < 4; i++)
                #pragma unroll
                for (int r = 0; r < 4; r++)
                    ep[(i*16 + crow + r)*40 + jj*16 + ccol] = (bf16)(acc[i][j][r] + bsv);
        }
        __syncthreads();
        #pragma unroll
        for (int q = 0; q < 4; q++){
            const int rr = q*16 + erow;
            short8 vv = *(const short8*)(ep + rr*40 + ecol);
            *(short8*)(C + (size_t)(m0 + wm + rr)*ldc + n0 + wn + j2*32 + ecol) = vv;
        }
    }
}

// ================= combined weight/bias prep (1 dispatch) =================
__global__ void prep_all_kernel(const float* __restrict__ wq1, const float* __restrict__ wk1,
                                const float* __restrict__ wv1, const float* __restrict__ ws1,
                                const float* __restrict__ bq1, const float* __restrict__ bk1,
                                const float* __restrict__ bv1, const float* __restrict__ bs1,
                                const float* __restrict__ wq2, const float* __restrict__ wk2,
                                const float* __restrict__ wv2, const float* __restrict__ ws2,
                                const float* __restrict__ bq2, const float* __restrict__ bk2,
                                const float* __restrict__ bv2, const float* __restrict__ bs2v,
                                bf16* __restrict__ W1t, float* __restrict__ b1c,
                                bf16* __restrict__ W2t, float* __restrict__ b2c)
{
    int i = blockIdx.x*256 + threadIdx.x;
    if (i < 98304){                      // W1t: [1024][96]
        int n = i / 96, k = i - n*96;
        const float* w = (n<256)?wq1:(n<512)?wk1:(n<768)?wv1:ws1;
        W1t[i] = (k < 78) ? (bf16)w[(size_t)k*256 + (n & 255)] : (bf16)0.f;
        return;
    }
    i -= 98304;
    if (i < 1024){                       // b1c
        const float* b = (i<256)?bq1:(i<512)?bk1:(i<768)?bv1:bs1;
        b1c[i] = b[i & 255];
        return;
    }
    i -= 1024;
    if (i < 1048576){                    // W2t: [2][2048][256]
        int k = i & 255;
        int j = (i >> 8) & 2047;
        int h = i >> 19;
        const float* w = (j<512)?wq2:(j<1024)?wk2:(j<1536)?wv2:ws2;
        W2t[i] = (bf16)w[(size_t)k*1024 + h*512 + (j & 511)];
        return;
    }
    i -= 1048576;
    if (i < 4096){                       // b2c
        int j = i & 2047, h = i >> 11;
        const float* b = (j<512)?bq2:(j<1024)?bk2:(j<1536)?bv2:bs2v;
        b2c[i] = b[h*512 + (j & 511)];
    }
}

__global__ void cvt_x_kernel(const float* __restrict__ x1, const float* __restrict__ x2,
                             bf16* __restrict__ xa){
    int i = blockIdx.x*256 + threadIdx.x;          // 2*NN*96
    int r = i / 96, c = i - r*96;
    const float* x = (r >= NN) ? x2 : x1;
    int lr = r & (NN-1);
    xa[i] = (c < 78) ? (bf16)x[(size_t)lr*78 + c] : (bf16)0.f;
}

// ================= CSR build (both branches, stacked) =================
__global__ void hist_kernel(const int* __restrict__ ei1, const int* __restrict__ ei2,
                            int* __restrict__ cnt){
    int eg = blockIdx.x*256 + threadIdx.x;     // 0..2EE
    int br = eg >> 16, e = eg & (EE-1);
    const int* ei = br ? ei2 : ei1;
    atomicAdd(&cnt[br*NN + ei[EE + e]], 1);
}

__global__ __launch_bounds__(1024)
void scan_kernel(const int* __restrict__ hist, int* __restrict__ rowptr){
    const int br = blockIdx.x;
    hist   += br*NN;
    rowptr += br*(NN+1);
    __shared__ int sums[1024];
    const int t = threadIdx.x;
    const int base = t*16;
    int loc[16]; int s = 0;
    #pragma unroll
    for (int i=0;i<16;i++){ loc[i]=s; s += hist[base+i]; }
    sums[t] = s; __syncthreads();
    for (int o=1;o<1024;o<<=1){
        int v = (t>=o) ? sums[t-o] : 0;
        __syncthreads();
        sums[t] += v;
        __syncthreads();
    }
    int pref = (t>0) ? sums[t-1] : 0;
    #pragma unroll
    for (int i=0;i<16;i++) rowptr[base+i] = pref + loc[i];
    if (t==1023) rowptr[NN] = sums[1023];
}

__global__ void scatter_kernel(const int* __restrict__ ei1, const int* __restrict__ ei2,
                               const int* __restrict__ rowptr,
                               int* __restrict__ cnt, int* __restrict__ srcs){
    int eg = blockIdx.x*256 + threadIdx.x;
    int br = eg >> 16, e = eg & (EE-1);
    const int* ei = br ? ei2 : ei1;
    int d = ei[EE + e];
    int pos = rowptr[br*(NN+1) + d] + atomicAdd(&cnt[br*NN + d], 1);
    srcs[br*EE + pos] = ei[e];
}

__global__ void range_kernel(const int* __restrict__ bt1, const int* __restrict__ bt2,
                             int* __restrict__ bps, int* __restrict__ bpe){
    int ng = blockIdx.x*256 + threadIdx.x;     // 0..2NN
    int br = ng >> 14, n = ng & (NN-1);
    const int* bt = br ? bt2 : bt1;
    int b = bt[n];
    if (n==0     || bt[n-1]!=b) bps[br*BB + b] = n;
    if (n==NN-1  || bt[n+1]!=b) bpe[br*BB + b] = n+1;
}

// ================= attention: one wave per (dst node, head), chunked online softmax ====
template<int D, int STACKED>
__global__ __launch_bounds__(256)
void attn_kernel(const bf16* __restrict__ qkvs, int ld, int qo, int ko, int vo, int so, int H,
                 bf16* __restrict__ hout, int ldo,
                 const int* __restrict__ rowptr, const int* __restrict__ srcs)
{
    constexpr int PER = D / 64;
    typedef __attribute__((ext_vector_type(PER))) short shortP;
    const int lane = threadIdx.x & 63;
    const int gw = blockIdx.x * 4 + (threadIdx.x >> 6);
    const int n = gw / H;                 // global node id (stacked: 0..2NN)
    const int h = gw - n*H;
    int nl = n, brNN = 0;
    if (STACKED){
        int br = n >> 14;
        brNN = br*NN; nl = n - brNN;
        rowptr += br*(NN+1); srcs += br*EE;
    }
    const float qscale = rsqrtf((float)D) * 1.44269504f;
    const int hd = h*D + lane*PER;

    const shortP qv = *(const shortP*)(qkvs + (size_t)n*ld + qo + hd);
    float qr[PER];
    #pragma unroll
    for (int i=0;i<PER;i++) qr[i] = b2f(qv[i]) * qscale;

    const int e0 = rowptr[nl], e1 = rowptr[nl+1];
    float m = -INFINITY, z = 0.f;
    float acc[PER];
    #pragma unroll
    for (int i=0;i<PER;i++) acc[i] = 0.f;

    for (int base = e0; base < e1; base += 4){
        const int cnt = min(4, e1 - base);
        int sl = srcs[min(base + (lane & 3), e1 - 1)];
        int src[4];
        #pragma unroll
        for (int j=0;j<4;j++) src[j] = __shfl(sl, j, 64);

        shortP kv[4], vv[4];
        #pragma unroll
        for (int j=0;j<4;j++){
            if (j < cnt){
                const bf16* rp = qkvs + (size_t)(brNN + src[j])*ld;
                kv[j] = *(const shortP*)(rp + ko + hd);
                vv[j] = *(const shortP*)(rp + vo + hd);
            }
        }
        float dt[4];
        #pragma unroll
        for (int j=0;j<4;j++){
            float d = 0.f;
            if (j < cnt){
                #pragma unroll
                for (int i=0;i<PER;i++) d += qr[i]*b2f(kv[j][i]);
            }
            dt[j] = d;
        }
        #pragma unroll
        for (int o=32;o;o>>=1){
            #pragma unroll
            for (int j=0;j<4;j++) dt[j] += __shfl_xor(dt[j], o, 64);
        }
        float cm = -INFINITY;
        #pragma unroll
        for (int j=0;j<4;j++) if (j < cnt) cm = fmaxf(cm, dt[j]);
        const float mn = fmaxf(m, cm);
        const float cs = exp2f(m - mn);
        z *= cs;
        #pragma unroll
        for (int i=0;i<PER;i++) acc[i] *= cs;
        #pragma unroll
        for (int j=0;j<4;j++){
            if (j < cnt){
                const float w = exp2f(dt[j] - mn);
                z += w;
                #pragma unroll
                for (int i=0;i<PER;i++) acc[i] += w*b2f(vv[j][i]);
            }
        }
        m = mn;
    }
    const float invz = 1.0f/(z + 1e-16f);
    const shortP sv = *(const shortP*)(qkvs + (size_t)n*ld + so + hd);
    shortP ov;
    #pragma unroll
    for (int i=0;i<PER;i++) ov[i] = f2b(lrelu_f(b2f(sv[i]) + acc[i]*invz));
    *(shortP*)(hout + (size_t)n*ldo + hd) = ov;
}

// ================= segment-max pool (512 cols, one block per graph) =================
__global__ __launch_bounds__(256)
void pool_kernel(const bf16* __restrict__ h,
                 const int* __restrict__ bps, const int* __restrict__ bpe,
                 float* __restrict__ g, int grow0, int gc0)
{
    typedef __attribute__((ext_vector_type(2))) short short2v;
    const int c = threadIdx.x * 2;
    const int b = blockIdx.x;
    float m0 = -INFINITY, m1 = -INFINITY;
    for (int n = bps[b]; n < bpe[b]; n++){
        const short2v hv = *(const short2v*)(h + (size_t)n*512 + c);
        m0 = fmaxf(m0, b2f(hv[0]));
        m1 = fmaxf(m1, b2f(hv[1]));
    }
    float* gp = g + (size_t)(grow0 + b)*1024 + gc0 + c;
    gp[0] = (m0 == -INFINITY) ? 0.f : m0;
    gp[1] = (m1 == -INFINITY) ? 0.f : m1;
}

// ================= fused MLP tail (1024 threads): split-K dense step =================
// CT=min(N,256) col-threads x KG=1024/CT k-groups. Partials in Spart, combine adds
// bias + activation. ACT: 0 none, 1 lrelu, 2 BN+lrelu.
template<int R, int N, int ACT>
__device__ __forceinline__ void dense_split(
    const float* __restrict__ W, const float* __restrict__ bias,
    const float* __restrict__ gam, const float* __restrict__ bet, float bns,
    const float* A, int lda, float* C, int ldc, int K, int tid, float* Spart)
{
    constexpr int CT  = (N >= 256) ? 256 : N;
    constexpr int CPT = N / CT;
    constexpr int KG  = 1024 / CT;
    const int ct = tid % CT;
    const int kg = tid / CT;
    const int jt = ct * CPT;
    const int Kc = ((K + KG - 1) / KG + 3) & ~3;
    const int kb = kg * Kc;
    const int ke = min(K, kb + Kc);

    float acc[R][CPT];
    #pragma unroll
    for (int r=0;r<R;r++)
        #pragma unroll
        for (int c=0;c<CPT;c++) acc[r][c] = 0.f;

    int k = kb;
    for (; k + 4 <= ke; k += 4){
        float w[4][CPT];
        #pragma unroll
        for (int u=0;u<4;u++)
            #pragma unroll
            for (int c=0;c<CPT;c++) w[u][c] = W[(size_t)(k+u)*N + jt + c];
        #pragma unroll
        for (int r=0;r<R;r++){
            const floatx4 av = *(const floatx4*)(A + r*lda + k);
            #pragma unroll
            for (int u=0;u<4;u++)
                #pragma unroll
                for (int c=0;c<CPT;c++) acc[r][c] += av[u]*w[u][c];
        }
    }
    for (; k < ke; k++){
        float w[CPT];
        #pragma unroll
        for (int c=0;c<CPT;c++) w[c] = W[(size_t)k*N + jt + c];
        #pragma unroll
        for (int r=0;r<R;r++){
            const float a = A[r*lda + k];
            #pragma unroll
            for (int c=0;c<CPT;c++) acc[r][c] += a*w[c];
        }
    }
    #pragma unroll
    for (int r=0;r<R;r++)
        #pragma unroll
        for (int c=0;c<CPT;c++)
            Spart[(kg*R + r)*N + jt + c] = acc[r][c];
    __syncthreads();
    for (int idx = tid; idx < R*N; idx += 1024){
        int r = idx / N, j = idx - r*N;
        float v = 0.f;
        #pragma unroll
        for (int g=0; g<KG; g++) v += Spart[(g*R + r)*N + j];
        v += bias[j];
        if (ACT==1) v = lrelu_f(v);
        if (ACT==2) v = lrelu_f(v*bns*gam[j] + bet[j]);
        C[r*ldc + j] = v;
    }
    __syncthreads();
}

// ================= fused tail: graph-head + cell branch + head MLP, 2 graphs/block ====
__global__ __launch_bounds__(1024)
void tail_kernel(const float* __restrict__ g,            // [2*BB][1024]
                 const float* __restrict__ cell,         // [BB][954]
                 const float* __restrict__ wg1, const float* __restrict__ bg1,
                 const float* __restrict__ wg2, const float* __restrict__ bg2,
                 const float* __restrict__ wr1, const float* __restrict__ br1,
                 const float* __restrict__ wr2, const float* __restrict__ br2,
                 const float* __restrict__ wr3, const float* __restrict__ br3,
                 const float* __restrict__ wf1, const float* __restrict__ bf1,
                 const float* __restrict__ gbn1, const float* __restrict__ bbn1,
                 const float* __restrict__ wf2, const float* __restrict__ bf2,
                 const float* __restrict__ gbn2, const float* __restrict__ bbn2,
                 const float* __restrict__ wf3, const float* __restrict__ bf3,
                 float bns, float* __restrict__ outp)
{
    __shared__ float Sg[4][1024];    // rows: lg*2 + br
    __shared__ float Sgh[4][512];
    __shared__ float Sgout[4][128];
    __shared__ float Scell[2][960];
    __shared__ float Sc1[2][512];
    __shared__ float Sc2[2][256];
    __shared__ float Sc3[2][128];
    __shared__ float Sxc[2][384];
    __shared__ float Sf1[2][512];
    __shared__ float Sf2[2][256];
    __shared__ float Spart[8192];    // split-K partials (max KG*R*N = 4*4*512)
    __shared__ float inv4[4], invc[2], invx[2];

    const int tid = threadIdx.x;
    const int wv  = tid >> 6;
    const int ln  = tid & 63;
    const int b0  = blockIdx.x * 2;

    // load g rows (r = lg*2 + br -> g[br*BB + b0+lg]) and cell rows
    #pragma unroll
    for (int i=0;i<4;i++){
        int idx = tid + i*1024;          // 4096
        int r = idx >> 10, c = idx & 1023;
        int lg = r >> 1, br = r & 1;
        Sg[r][c] = g[(size_t)(br*BB + b0 + lg)*1024 + c];
    }
    for (int idx = tid; idx < 2*954; idx += 1024){
        int r = (idx >= 954) ? 1 : 0;
        int c = idx - r*954;
        Scell[r][c] = cell[(size_t)(b0 + r)*954 + c];
    }
    __syncthreads();

    // cell l2n (waves 0-1)
    if (wv < 2){
        float s = 0.f;
        for (int c = ln; c < 954; c += 64){ float v = Scell[wv][c]; s += v*v; }
        #pragma unroll
        for (int o=32;o;o>>=1) s += __shfl_xor(s, o, 64);
        if (ln == 0) invc[wv] = 1.0f / fmaxf(sqrtf(s), 1e-12f);
    }
    __syncthreads();
    #pragma unroll
    for (int r=0;r<2;r++)
        for (int c = tid; c < 954; c += 1024) Scell[r][c] *= invc[r];
    __syncthreads();

    // graph head: gh = lrelu(g@wg1+bg1); gout = gh@wg2 + bg2
    dense_split<4,512,1>(wg1, bg1, nullptr, nullptr, 1.f, &Sg[0][0],   1024, &Sgh[0][0],  512, 1024, tid, Spart);
    dense_split<4,128,0>(wg2, bg2, nullptr, nullptr, 1.f, &Sgh[0][0],  512,  &Sgout[0][0],128, 512,  tid, Spart);
    // cell: c1 = lrelu(cn@wr1+br1); c2 = lrelu(c1@wr2+br2); c3 = c2@wr3+br3
    dense_split<2,512,1>(wr1, br1, nullptr, nullptr, 1.f, &Scell[0][0], 960, &Sc1[0][0],  512, 954,  tid, Spart);
    dense_split<2,256,1>(wr2, br2, nullptr, nullptr, 1.f, &Sc1[0][0],   512, &Sc2[0][0],  256, 512,  tid, Spart);
    dense_split<2,128,0>(wr3, br3, nullptr, nullptr, 1.f, &Sc2[0][0],   256, &Sc3[0][0],  128, 256,  tid, Spart);

    // l2n per gout row (4 rows x 128)
    if (wv < 4){
        float a = Sgout[wv][ln], bq = Sgout[wv][ln+64];
        float s = a*a + bq*bq;
        #pragma unroll
        for (int o=32;o;o>>=1) s += __shfl_xor(s, o, 64);
        if (ln == 0) inv4[wv] = 1.0f / fmaxf(sqrtf(s), 1e-12f);
    }
    __syncthreads();

    // build xc rows (2 x 384)
    if (tid < 768){
        int lg = tid / 384, j = tid - lg*384;
        float v;
        if (j < 128)      v = Sgout[lg*2+0][j]     * inv4[lg*2+0];
        else if (j < 256) v = Sgout[lg*2+1][j-128] * inv4[lg*2+1];
        else              v = Sc3[lg][j-256];
        Sxc[lg][j] = v;
    }
    __syncthreads();
    if (wv < 2){
        float s = 0.f;
        #pragma unroll
        for (int i=0;i<6;i++){ float v = Sxc[wv][ln + i*64]; s += v*v; }
        #pragma unroll
        for (int o=32;o;o>>=1) s += __shfl_xor(s, o, 64);
        if (ln == 0) invx[wv] = 1.0f / fmaxf(sqrtf(s), 1e-12f);
    }
    __syncthreads();
    if (tid < 768){
        int lg = tid / 384, j = tid - lg*384;
        Sxc[lg][j] *= invx[lg];
    }
    __syncthreads();

    // head MLP: f1 = lrelu(BN1(xc@wf1+bf1)); f2 = lrelu(BN2(f1@wf2+bf2))
    dense_split<2,512,2>(wf1, bf1, gbn1, bbn1, bns, &Sxc[0][0], 384, &Sf1[0][0], 512, 384, tid, Spart);
    dense_split<2,256,2>(wf2, bf2, gbn2, bbn2, bns, &Sf1[0][0], 512, &Sf2[0][0], 256, 512, tid, Spart);

    // final dot + sigmoid
    if (wv < 2){
        float s = 0.f;
        #pragma unroll
        for (int i=0;i<4;i++){ int c = ln + i*64; s += Sf2[wv][c]*wf3[c]; }
        #pragma unroll
        for (int o=32;o;o>>=1) s += __shfl_xor(s, o, 64);
        if (ln == 0) outp[b0 + wv] = 1.0f/(1.0f + expf(-(s + bf3[0])));
    }
}

extern "C" void kernel_launch(void* const* d_in, const int* in_sizes, int n_in,
                              void* d_out, int out_size, void* d_ws, size_t ws_size,
                              hipStream_t stream)
{
    const float* x1  = (const float*)d_in[0];
    const int*   ei1 = (const int*)  d_in[1];
    const int*   bt1 = (const int*)  d_in[2];
    const float* x2  = (const float*)d_in[3];
    const int*   ei2 = (const int*)  d_in[4];
    const int*   bt2 = (const int*)  d_in[5];
    const float* cell= (const float*)d_in[6];
    const float* wq1=(const float*)d_in[7];  const float* bq1=(const float*)d_in[8];
    const float* wk1=(const float*)d_in[9];  const float* bk1=(const float*)d_in[10];
    const float* wv1=(const float*)d_in[11]; const float* bv1=(const float*)d_in[12];
    const float* ws1=(const float*)d_in[13]; const float* bs1=(const float*)d_in[14];
    const float* wq2=(const float*)d_in[15]; const float* bq2=(const float*)d_in[16];
    const float* wk2=(const float*)d_in[17]; const float* bk2=(const float*)d_in[18];
    const float* wv2=(const float*)d_in[19]; const float* bv2=(const float*)d_in[20];
    const float* ws2=(const float*)d_in[21]; const float* bs2q=(const float*)d_in[22];
    const float* wg1=(const float*)d_in[23]; const float* bg1=(const float*)d_in[24];
    const float* wg2=(const float*)d_in[25]; const float* bg2=(const float*)d_in[26];
    const float* wr1=(const float*)d_in[27]; const float* br1=(const float*)d_in[28];
    const float* wr2=(const float*)d_in[29]; const float* br2=(const float*)d_in[30];
    const float* wr3=(const float*)d_in[31]; const float* br3=(const float*)d_in[32];
    const float* wf1=(const float*)d_in[33]; const float* bf1=(const float*)d_in[34];
    const float* gbn1=(const float*)d_in[35];const float* bbn1=(const float*)d_in[36];
    const float* wf2=(const float*)d_in[37]; const float* bf2=(const float*)d_in[38];
    const float* gbn2=(const float*)d_in[39];const float* bbn2=(const float*)d_in[40];
    const float* wf3=(const float*)d_in[41]; const float* bf3=(const float*)d_in[42];
    float* outp = (float*)d_out;
    (void)in_sizes; (void)n_in; (void)out_size; (void)ws_size;

    const float BNS = 1.0f / sqrtf(1.0f + 1e-5f);

    // ---- workspace arena (R region phase-aliased xa -> h2h) ----
    char* basep = (char*)d_ws;
    size_t off = 0;
    auto alloc = [&](size_t nbytes)->char* {
        char* p = basep + off;
        off += (nbytes + 255) & ~(size_t)255;
        return p;
    };
    int* rowptr2  = (int*)  alloc((size_t)2*(NN+1)*4);
    int* cnt2     = (int*)  alloc((size_t)2*NN*4);
    int* srcs2    = (int*)  alloc((size_t)2*EE*4);
    float* g      = (float*)alloc((size_t)2*BB*1024*4);   // [2B,1024] pooled (raw f32)
    int* bps      = (int*)  alloc((size_t)2*BB*4);
    int* bpe      = (int*)  alloc((size_t)2*BB*4);
    float* b1c    = (float*)alloc((size_t)1024*4);
    float* b2c    = (float*)alloc((size_t)4096*4);
    bf16* W1t     = (bf16*) alloc((size_t)1024*96*2);
    bf16* W2t     = (bf16*) alloc((size_t)2*2048*256*2);
    bf16* h1      = (bf16*) alloc((size_t)2*NN*256*2);    // both branches stacked
    char* R       = alloc((size_t)NN*512*2);              // xa [2NN,96] -> h2h [NN,512]
    bf16* xa      = (bf16*)R;
    bf16* h2h     = (bf16*)R;
    bf16* qkvs    = (bf16*) alloc((size_t)NN*2048*2);     // qkvs1 [2NN,1024] / qkvs2 [NN,2048]

    // ---- prep + CSR (both branches in one pass) ----
    (void)hipMemsetAsync(bps, 0, (size_t)4*BB*4, stream);   // bps+bpe adjacent
    (void)hipMemsetAsync(cnt2, 0, (size_t)2*NN*4, stream);
    prep_all_kernel<<<4500,256,0,stream>>>(wq1,wk1,wv1,ws1, bq1,bk1,bv1,bs1,
                                           wq2,wk2,wv2,ws2, bq2,bk2,bv2,bs2q,
                                           W1t,b1c,W2t,b2c);
    hist_kernel<<<2*EE/256,256,0,stream>>>(ei1, ei2, cnt2);
    scan_kernel<<<2,1024,0,stream>>>(cnt2, rowptr2);
    (void)hipMemsetAsync(cnt2, 0, (size_t)2*NN*4, stream);
    scatter_kernel<<<2*EE/256,256,0,stream>>>(ei1, ei2, rowptr2, cnt2, srcs2);
    range_kernel<<<2*NN/256,256,0,stream>>>(bt1, bt2, bps, bpe);

    // ---- layer 1 (both branches stacked): [2NN,96] x [96,1024] -> attn ----
    cvt_x_kernel<<<(2*NN*96)/256,256,0,stream>>>(x1, x2, xa);
    mfma_gemm<<<dim3(1024/128, 2*NN/128),256,0,stream>>>(xa,96, W1t,96, b1c, qkvs,1024, 96);
    attn_kernel<128,1><<<2*NN*2/4,256,0,stream>>>(qkvs,1024, 0,256,512,768, 2, h1,256, rowptr2, srcs2);

    // ---- layer 2: per (branch, head) GEMM + attn + pool ----
    for (int br=0; br<2; br++){
        for (int h=0; h<2; h++){
            mfma_gemm<<<dim3(2048/128, NN/128),256,0,stream>>>(
                h1 + (size_t)br*NN*256, 256, W2t + (size_t)h*2048*256, 256,
                b2c + h*2048, qkvs, 2048, 256);
            attn_kernel<512,0><<<NN/4,256,0,stream>>>(qkvs,2048, 0,512,1024,1536, 1,
                                                      h2h,512, rowptr2 + br*(NN+1), srcs2 + br*EE);
            pool_kernel<<<BB,256,0,stream>>>(h2h, bps + br*BB, bpe + br*BB, g, br*BB, h*512);
        }
    }

    // ---- fused tail: graph-head + cell + head MLP + sigmoid, one dispatch ----
    tail_kernel<<<BB/2,1024,0,stream>>>(g, cell,
                                        wg1,bg1, wg2,bg2, wr1,br1, wr2,br2, wr3,br3,
                                        wf1,bf1, gbn1,bbn1, wf2,bf2, gbn2,bbn2, wf3,bf3,
                                        BNS, outp);
}

// Round 10
// 627.369 us; speedup vs baseline: 1.2894x; 1.0566x over previous
//
#include <hip/hip_runtime.h>
#include <hip/hip_bf16.h>
#include <math.h>
#include <stdint.h>

typedef __hip_bfloat16 bf16;

#define NN 16384
#define EE 65536
#define BB 512

typedef __attribute__((ext_vector_type(8))) short short8;
typedef __attribute__((ext_vector_type(4))) short short4v;
typedef __attribute__((ext_vector_type(4))) float floatx4;

__device__ __forceinline__ float lrelu_f(float x){ return x >= 0.f ? x : 0.01f*x; }

__device__ __forceinline__ float b2f(short s){
    unsigned int u = ((unsigned int)(unsigned short)s) << 16;
    float f; __builtin_memcpy(&f, &u, 4); return f;
}
__device__ __forceinline__ short f2b(float f){
    bf16 b = (bf16)f;
    short s; __builtin_memcpy(&s, &b, 2); return s;
}

// async 16B global->LDS. LDS dest is wave-uniform base; lane i lands at base+16*i.
__device__ __forceinline__ void gl2lds16(const void* g, void* l){
    __builtin_amdgcn_global_load_lds(
        (__attribute__((address_space(1))) unsigned int*)(uintptr_t)g,
        (__attribute__((address_space(3))) unsigned int*)(uintptr_t)l, 16, 0, 0);
}

// ================= MFMA bf16 GEMM: C[m,n] = A[m,:K] @ W[:,n] + bias[n] =================
__global__ __launch_bounds__(256)
void mfma_gemm(const bf16* __restrict__ A, int lda,
               const bf16* __restrict__ Bt, int ldb,
               const float* __restrict__ bias,
               bf16* __restrict__ C, int ldc, int K)
{
    __shared__ bf16 As[128*32];     // As[r][k]
    __shared__ bf16 Bs[128*32];     // Bs[n][k]
    __shared__ bf16 epi[4*64*40];   // per-wave 64x32 epilogue tile, row stride 40
    const int tid  = threadIdx.x;
    const int wave = tid >> 6;
    const int lane = tid & 63;
    const int wm = (wave & 1) * 64;
    const int wn = (wave >> 1) * 64;
    const int m0 = blockIdx.y * 128;
    const int n0 = blockIdx.x * 128;

    const int srow = lane >> 2;
    const int scol = (lane & 3) * 8;
    const int arow = lane & 15;
    const int aq   = (lane >> 4) * 8;

    floatx4 acc[4][4];
    #pragma unroll
    for (int i=0;i<4;i++)
        #pragma unroll
        for (int j=0;j<4;j++) acc[i][j] = (floatx4){0.f,0.f,0.f,0.f};

    for (int k0 = 0; k0 < K; k0 += 32) {
        #pragma unroll
        for (int i = 0; i < 2; i++) {
            const int chunk = wave*2 + i;
            const int r = chunk*16 + srow;
            gl2lds16(A  + (size_t)(m0 + r)*lda + k0 + scol, As + chunk*512);
            gl2lds16(Bt + (size_t)(n0 + r)*ldb + k0 + scol, Bs + chunk*512);
        }
        __syncthreads();
        short8 af[4], bf_[4];
        #pragma unroll
        for (int i=0;i<4;i++) af[i]  = *(const short8*)(As + (wm + i*16 + arow)*32 + aq);
        #pragma unroll
        for (int j=0;j<4;j++) bf_[j] = *(const short8*)(Bs + (wn + j*16 + arow)*32 + aq);
        #pragma unroll
        for (int i=0;i<4;i++)
            #pragma unroll
            for (int j=0;j<4;j++)
                acc[i][j] = __builtin_amdgcn_mfma_f32_16x16x32_bf16(af[i], bf_[j], acc[i][j], 0,0,0);
        __syncthreads();
    }
    const int crow = (lane >> 4) * 4;
    const int ccol = lane & 15;
    const int erow = lane >> 2;
    const int ecol = (lane & 3) * 8;
    bf16* ep = epi + wave * (64*40);
    #pragma unroll
    for (int j2 = 0; j2 < 2; j2++){
        if (j2) __syncthreads();
        #pragma unroll
        for (int jj = 0; jj < 2; jj++){
            const int j = j2*2 + jj;
            const float bsv = bias[n0 + wn + j*16 + ccol];
            #pragma unroll
            for (int i = 0; i < 4; i++)
                #pragma unroll
                for (int r = 0; r < 4; r++)
                    ep[(i*16 + crow + r)*40 + jj*16 + ccol] = (bf16)(acc[i][j][r] + bsv);
        }
        __syncthreads();
        #pragma unroll
        for (int q = 0; q < 4; q++){
            const int rr = q*16 + erow;
            short8 vv = *(const short8*)(ep + rr*40 + ecol);
            *(short8*)(C + (size_t)(m0 + wm + rr)*ldc + n0 + wn + j2*32 + ecol) = vv;
        }
    }
}

// ================= combined weight/bias prep (1 dispatch) =================
__global__ void prep_all_kernel(const float* __restrict__ wq1, const float* __restrict__ wk1,
                                const float* __restrict__ wv1, const float* __restrict__ ws1,
                                const float* __restrict__ bq1, const float* __restrict__ bk1,
                                const float* __restrict__ bv1, const float* __restrict__ bs1,
                                const float* __restrict__ wq2, const float* __restrict__ wk2,
                                const float* __restrict__ wv2, const float* __restrict__ ws2,
                                const float* __restrict__ bq2, const float* __restrict__ bk2,
                                const float* __restrict__ bv2, const float* __restrict__ bs2v,
                                bf16* __restrict__ W1t, float* __restrict__ b1c,
                                bf16* __restrict__ W2t, float* __restrict__ b2c)
{
    int i = blockIdx.x*256 + threadIdx.x;
    if (i < 98304){                      // W1t: [1024][96]
        int n = i / 96, k = i - n*96;
        const float* w = (n<256)?wq1:(n<512)?wk1:(n<768)?wv1:ws1;
        W1t[i] = (k < 78) ? (bf16)w[(size_t)k*256 + (n & 255)] : (bf16)0.f;
        return;
    }
    i -= 98304;
    if (i < 1024){                       // b1c
        const float* b = (i<256)?bq1:(i<512)?bk1:(i<768)?bv1:bs1;
        b1c[i] = b[i & 255];
        return;
    }
    i -= 1024;
    if (i < 1048576){                    // W2t: [2][2048][256]
        int k = i & 255;
        int j = (i >> 8) & 2047;
        int h = i >> 19;
        const float* w = (j<512)?wq2:(j<1024)?wk2:(j<1536)?wv2:ws2;
        W2t[i] = (bf16)w[(size_t)k*1024 + h*512 + (j & 511)];
        return;
    }
    i -= 1048576;
    if (i < 4096){                       // b2c
        int j = i & 2047, h = i >> 11;
        const float* b = (j<512)?bq2:(j<1024)?bk2:(j<1536)?bv2:bs2v;
        b2c[i] = b[h*512 + (j & 511)];
    }
}

// ---- tail weights: bf16 packed [K/4][N][4] (u = k%4). Offsets in Wtp arena ----
#define OG1 0         // wg1 1024x512 -> 256x512x4
#define OG2 524288    // wg2 512x128  -> 128x128x4
#define OR1 589824    // wr1 954x512  -> 240x512x4 (pad)
#define OR2 1081344   // wr2 512x256  -> 128x256x4
#define OR3 1212416   // wr3 256x128  -> 64x128x4
#define OF1 1245184   // wf1 384x512  -> 96x512x4
#define OF2 1441792   // wf2 512x256  -> 128x256x4
#define TAILW_TOTAL 1572864

__global__ void prep_tail_kernel(const float* __restrict__ wg1, const float* __restrict__ wg2,
                                 const float* __restrict__ wr1, const float* __restrict__ wr2,
                                 const float* __restrict__ wr3, const float* __restrict__ wf1,
                                 const float* __restrict__ wf2, bf16* __restrict__ Wtp)
{
    int i = blockIdx.x*256 + threadIdx.x;
    if (i >= TAILW_TOTAL) return;
    const float* W; int N, K, base;
    if      (i < OG2){ W = wg1; N = 512; K = 1024; base = OG1; }
    else if (i < OR1){ W = wg2; N = 128; K = 512;  base = OG2; }
    else if (i < OR2){ W = wr1; N = 512; K = 954;  base = OR1; }
    else if (i < OR3){ W = wr2; N = 256; K = 512;  base = OR2; }
    else if (i < OF1){ W = wr3; N = 128; K = 256;  base = OR3; }
    else if (i < OF2){ W = wf1; N = 512; K = 384;  base = OF1; }
    else             { W = wf2; N = 256; K = 512;  base = OF2; }
    int loc = i - base;
    int u = loc & 3;
    int j = (loc >> 2) % N;
    int k4 = (loc >> 2) / N;
    int k = k4*4 + u;
    Wtp[i] = (k < K) ? (bf16)W[(size_t)k*N + j] : (bf16)0.f;
}

__global__ void cvt_x_kernel(const float* __restrict__ x1, const float* __restrict__ x2,
                             bf16* __restrict__ xa){
    int i = blockIdx.x*256 + threadIdx.x;          // 2*NN*96
    int r = i / 96, c = i - r*96;
    const float* x = (r >= NN) ? x2 : x1;
    int lr = r & (NN-1);
    xa[i] = (c < 78) ? (bf16)x[(size_t)lr*78 + c] : (bf16)0.f;
}

// ================= CSR build (both branches, stacked) =================
__global__ void hist_kernel(const int* __restrict__ ei1, const int* __restrict__ ei2,
                            int* __restrict__ cnt){
    int eg = blockIdx.x*256 + threadIdx.x;     // 0..2EE
    int br = eg >> 16, e = eg & (EE-1);
    const int* ei = br ? ei2 : ei1;
    atomicAdd(&cnt[br*NN + ei[EE + e]], 1);
}

__global__ __launch_bounds__(1024)
void scan_kernel(const int* __restrict__ hist, int* __restrict__ rowptr){
    const int br = blockIdx.x;
    hist   += br*NN;
    rowptr += br*(NN+1);
    __shared__ int sums[1024];
    const int t = threadIdx.x;
    const int base = t*16;
    int loc[16]; int s = 0;
    #pragma unroll
    for (int i=0;i<16;i++){ loc[i]=s; s += hist[base+i]; }
    sums[t] = s; __syncthreads();
    for (int o=1;o<1024;o<<=1){
        int v = (t>=o) ? sums[t-o] : 0;
        __syncthreads();
        sums[t] += v;
        __syncthreads();
    }
    int pref = (t>0) ? sums[t-1] : 0;
    #pragma unroll
    for (int i=0;i<16;i++) rowptr[base+i] = pref + loc[i];
    if (t==1023) rowptr[NN] = sums[1023];
}

__global__ void scatter_kernel(const int* __restrict__ ei1, const int* __restrict__ ei2,
                               const int* __restrict__ rowptr,
                               int* __restrict__ cnt, int* __restrict__ srcs){
    int eg = blockIdx.x*256 + threadIdx.x;
    int br = eg >> 16, e = eg & (EE-1);
    const int* ei = br ? ei2 : ei1;
    int d = ei[EE + e];
    int pos = rowptr[br*(NN+1) + d] + atomicAdd(&cnt[br*NN + d], 1);
    srcs[br*EE + pos] = ei[e];
}

__global__ void range_kernel(const int* __restrict__ bt1, const int* __restrict__ bt2,
                             int* __restrict__ bps, int* __restrict__ bpe){
    int ng = blockIdx.x*256 + threadIdx.x;     // 0..2NN
    int br = ng >> 14, n = ng & (NN-1);
    const int* bt = br ? bt2 : bt1;
    int b = bt[n];
    if (n==0     || bt[n-1]!=b) bps[br*BB + b] = n;
    if (n==NN-1  || bt[n+1]!=b) bpe[br*BB + b] = n+1;
}

// ================= attention: one wave per (dst node, head), chunked online softmax ====
template<int D, int STACKED>
__global__ __launch_bounds__(256)
void attn_kernel(const bf16* __restrict__ qkvs, int ld, int qo, int ko, int vo, int so, int H,
                 bf16* __restrict__ hout, int ldo,
                 const int* __restrict__ rowptr, const int* __restrict__ srcs)
{
    constexpr int PER = D / 64;
    typedef __attribute__((ext_vector_type(PER))) short shortP;
    const int lane = threadIdx.x & 63;
    const int gw = blockIdx.x * 4 + (threadIdx.x >> 6);
    const int n = gw / H;                 // global node id (stacked: 0..2NN)
    const int h = gw - n*H;
    int nl = n, brNN = 0;
    if (STACKED){
        int br = n >> 14;
        brNN = br*NN; nl = n - brNN;
        rowptr += br*(NN+1); srcs += br*EE;
    }
    const float qscale = rsqrtf((float)D) * 1.44269504f;
    const int hd = h*D + lane*PER;

    const shortP qv = *(const shortP*)(qkvs + (size_t)n*ld + qo + hd);
    float qr[PER];
    #pragma unroll
    for (int i=0;i<PER;i++) qr[i] = b2f(qv[i]) * qscale;

    const int e0 = rowptr[nl], e1 = rowptr[nl+1];
    float m = -INFINITY, z = 0.f;
    float acc[PER];
    #pragma unroll
    for (int i=0;i<PER;i++) acc[i] = 0.f;

    for (int base = e0; base < e1; base += 4){
        const int cnt = min(4, e1 - base);
        int sl = srcs[min(base + (lane & 3), e1 - 1)];
        int src[4];
        #pragma unroll
        for (int j=0;j<4;j++) src[j] = __shfl(sl, j, 64);

        shortP kv[4], vv[4];
        #pragma unroll
        for (int j=0;j<4;j++){
            if (j < cnt){
                const bf16* rp = qkvs + (size_t)(brNN + src[j])*ld;
                kv[j] = *(const shortP*)(rp + ko + hd);
                vv[j] = *(const shortP*)(rp + vo + hd);
            }
        }
        float dt[4];
        #pragma unroll
        for (int j=0;j<4;j++){
            float d = 0.f;
            if (j < cnt){
                #pragma unroll
                for (int i=0;i<PER;i++) d += qr[i]*b2f(kv[j][i]);
            }
            dt[j] = d;
        }
        #pragma unroll
        for (int o=32;o;o>>=1){
            #pragma unroll
            for (int j=0;j<4;j++) dt[j] += __shfl_xor(dt[j], o, 64);
        }
        float cm = -INFINITY;
        #pragma unroll
        for (int j=0;j<4;j++) if (j < cnt) cm = fmaxf(cm, dt[j]);
        const float mn = fmaxf(m, cm);
        const float cs = exp2f(m - mn);
        z *= cs;
        #pragma unroll
        for (int i=0;i<PER;i++) acc[i] *= cs;
        #pragma unroll
        for (int j=0;j<4;j++){
            if (j < cnt){
                const float w = exp2f(dt[j] - mn);
                z += w;
                #pragma unroll
                for (int i=0;i<PER;i++) acc[i] += w*b2f(vv[j][i]);
            }
        }
        m = mn;
    }
    const float invz = 1.0f/(z + 1e-16f);
    const shortP sv = *(const shortP*)(qkvs + (size_t)n*ld + so + hd);
    shortP ov;
    #pragma unroll
    for (int i=0;i<PER;i++) ov[i] = f2b(lrelu_f(b2f(sv[i]) + acc[i]*invz));
    *(shortP*)(hout + (size_t)n*ldo + hd) = ov;
}

// ================= segment-max pool (512 cols, one block per graph) =================
__global__ __launch_bounds__(256)
void pool_kernel(const bf16* __restrict__ h,
                 const int* __restrict__ bps, const int* __restrict__ bpe,
                 float* __restrict__ g, int grow0, int gc0)
{
    typedef __attribute__((ext_vector_type(2))) short short2v;
    const int c = threadIdx.x * 2;
    const int b = blockIdx.x;
    float m0 = -INFINITY, m1 = -INFINITY;
    for (int n = bps[b]; n < bpe[b]; n++){
        const short2v hv = *(const short2v*)(h + (size_t)n*512 + c);
        m0 = fmaxf(m0, b2f(hv[0]));
        m1 = fmaxf(m1, b2f(hv[1]));
    }
    float* gp = g + (size_t)(grow0 + b)*1024 + gc0 + c;
    gp[0] = (m0 == -INFINITY) ? 0.f : m0;
    gp[1] = (m1 == -INFINITY) ? 0.f : m1;
}

// ================= fused MLP tail (1024 threads): split-K dense step, bf16 weights ====
// Wp packed [K/4][N][4]; CT=min(N,256) col-threads x KG=1024/CT k-groups.
// ACT: 0 none, 1 lrelu, 2 BN+lrelu.
template<int R, int N, int ACT>
__device__ __forceinline__ void dense_split(
    const bf16* __restrict__ Wp, const float* __restrict__ bias,
    const float* __restrict__ gam, const float* __restrict__ bet, float bns,
    const float* A, int lda, float* C, int ldc, int K, int tid, float* Spart)
{
    constexpr int CT  = (N >= 256) ? 256 : N;
    constexpr int CPT = N / CT;
    constexpr int KG  = 1024 / CT;
    const int ct = tid % CT;
    const int kg = tid / CT;
    const int jt = ct * CPT;
    const int Kc = ((K + KG - 1) / KG + 3) & ~3;
    const int kb = kg * Kc;
    const int ke = min(K, kb + Kc);

    float acc[R][CPT];
    #pragma unroll
    for (int r=0;r<R;r++)
        #pragma unroll
        for (int c=0;c<CPT;c++) acc[r][c] = 0.f;

    int k = kb;
    for (; k + 4 <= ke; k += 4){
        float w[4][CPT];
        if (CPT == 2){
            // 16B: cols jt,jt+1 x k..k+3
            short8 wv8 = *(const short8*)(Wp + ((size_t)(k>>2)*N + jt)*4);
            #pragma unroll
            for (int u=0;u<4;u++){ w[u][0] = b2f(wv8[u]); w[u][1] = b2f(wv8[4+u]); }
        } else {
            // 8B: col jt x k..k+3
            short4v wv4 = *(const short4v*)(Wp + ((size_t)(k>>2)*N + jt)*4);
            #pragma unroll
            for (int u=0;u<4;u++) w[u][0] = b2f(wv4[u]);
        }
        #pragma unroll
        for (int r=0;r<R;r++){
            const floatx4 av = *(const floatx4*)(A + r*lda + k);
            #pragma unroll
            for (int u=0;u<4;u++)
                #pragma unroll
                for (int c=0;c<CPT;c++) acc[r][c] += av[u]*w[u][c];
        }
    }
    for (; k < ke; k++){
        float w[CPT];
        #pragma unroll
        for (int c=0;c<CPT;c++) w[c] = b2f(Wp[((size_t)(k>>2)*N + jt + c)*4 + (k&3)]);
        #pragma unroll
        for (int r=0;r<R;r++){
            const float a = A[r*lda + k];
            #pragma unroll
            for (int c=0;c<CPT;c++) acc[r][c] += a*w[c];
        }
    }
    #pragma unroll
    for (int r=0;r<R;r++)
        #pragma unroll
        for (int c=0;c<CPT;c++)
            Spart[(kg*R + r)*N + jt + c] = acc[r][c];
    __syncthreads();
    for (int idx = tid; idx < R*N; idx += 1024){
        int r = idx / N, j = idx - r*N;
        float v = 0.f;
        #pragma unroll
        for (int g=0; g<KG; g++) v += Spart[(g*R + r)*N + j];
        v += bias[j];
        if (ACT==1) v = lrelu_f(v);
        if (ACT==2) v = lrelu_f(v*bns*gam[j] + bet[j]);
        C[r*ldc + j] = v;
    }
    __syncthreads();
}

// ================= fused tail: graph-head + cell branch + head MLP, 2 graphs/block ====
__global__ __launch_bounds__(1024)
void tail_kernel(const float* __restrict__ g,            // [2*BB][1024]
                 const float* __restrict__ cell,         // [BB][954]
                 const bf16*  __restrict__ Wtp,          // packed tail weights
                 const float* __restrict__ bg1, const float* __restrict__ bg2,
                 const float* __restrict__ br1, const float* __restrict__ br2,
                 const float* __restrict__ br3,
                 const float* __restrict__ bf1,
                 const float* __restrict__ gbn1, const float* __restrict__ bbn1,
                 const float* __restrict__ bf2,
                 const float* __restrict__ gbn2, const float* __restrict__ bbn2,
                 const float* __restrict__ wf3, const float* __restrict__ bf3,
                 float bns, float* __restrict__ outp)
{
    __shared__ float Sg[4][1024];    // rows: lg*2 + br
    __shared__ float Sgh[4][512];
    __shared__ float Sgout[4][128];
    __shared__ float Scell[2][960];
    __shared__ float Sc1[2][512];
    __shared__ float Sc2[2][256];
    __shared__ float Sc3[2][128];
    __shared__ float Sxc[2][384];
    __shared__ float Sf1[2][512];
    __shared__ float Sf2[2][256];
    __shared__ float Spart[8192];    // split-K partials (max KG*R*N = 4*4*512)
    __shared__ float inv4[4], invc[2], invx[2];

    const int tid = threadIdx.x;
    const int wv  = tid >> 6;
    const int ln  = tid & 63;
    const int b0  = blockIdx.x * 2;

    // load g rows (r = lg*2 + br -> g[br*BB + b0+lg]) and cell rows
    #pragma unroll
    for (int i=0;i<4;i++){
        int idx = tid + i*1024;          // 4096
        int r = idx >> 10, c = idx & 1023;
        int lg = r >> 1, br = r & 1;
        Sg[r][c] = g[(size_t)(br*BB + b0 + lg)*1024 + c];
    }
    for (int idx = tid; idx < 2*954; idx += 1024){
        int r = (idx >= 954) ? 1 : 0;
        int c = idx - r*954;
        Scell[r][c] = cell[(size_t)(b0 + r)*954 + c];
    }
    __syncthreads();

    // cell l2n (waves 0-1)
    if (wv < 2){
        float s = 0.f;
        for (int c = ln; c < 954; c += 64){ float v = Scell[wv][c]; s += v*v; }
        #pragma unroll
        for (int o=32;o;o>>=1) s += __shfl_xor(s, o, 64);
        if (ln == 0) invc[wv] = 1.0f / fmaxf(sqrtf(s), 1e-12f);
    }
    __syncthreads();
    #pragma unroll
    for (int r=0;r<2;r++)
        for (int c = tid; c < 954; c += 1024) Scell[r][c] *= invc[r];
    __syncthreads();

    // graph head: gh = lrelu(g@wg1+bg1); gout = gh@wg2 + bg2
    dense_split<4,512,1>(Wtp+OG1, bg1, nullptr, nullptr, 1.f, &Sg[0][0],   1024, &Sgh[0][0],  512, 1024, tid, Spart);
    dense_split<4,128,0>(Wtp+OG2, bg2, nullptr, nullptr, 1.f, &Sgh[0][0],  512,  &Sgout[0][0],128, 512,  tid, Spart);
    // cell: c1 = lrelu(cn@wr1+br1); c2 = lrelu(c1@wr2+br2); c3 = c2@wr3+br3
    dense_split<2,512,1>(Wtp+OR1, br1, nullptr, nullptr, 1.f, &Scell[0][0], 960, &Sc1[0][0],  512, 954,  tid, Spart);
    dense_split<2,256,1>(Wtp+OR2, br2, nullptr, nullptr, 1.f, &Sc1[0][0],   512, &Sc2[0][0],  256, 512,  tid, Spart);
    dense_split<2,128,0>(Wtp+OR3, br3, nullptr, nullptr, 1.f, &Sc2[0][0],   256, &Sc3[0][0],  128, 256,  tid, Spart);

    // l2n per gout row (4 rows x 128)
    if (wv < 4){
        float a = Sgout[wv][ln], bq = Sgout[wv][ln+64];
        float s = a*a + bq*bq;
        #pragma unroll
        for (int o=32;o;o>>=1) s += __shfl_xor(s, o, 64);
        if (ln == 0) inv4[wv] = 1.0f / fmaxf(sqrtf(s), 1e-12f);
    }
    __syncthreads();

    // build xc rows (2 x 384)
    if (tid < 768){
        int lg = tid / 384, j = tid - lg*384;
        float v;
        if (j < 128)      v = Sgout[lg*2+0][j]     * inv4[lg*2+0];
        else if (j < 256) v = Sgout[lg*2+1][j-128] * inv4[lg*2+1];
        else              v = Sc3[lg][j-256];
        Sxc[lg][j] = v;
    }
    __syncthreads();
    if (wv < 2){
        float s = 0.f;
        #pragma unroll
        for (int i=0;i<6;i++){ float v = Sxc[wv][ln + i*64]; s += v*v; }
        #pragma unroll
        for (int o=32;o;o>>=1) s += __shfl_xor(s, o, 64);
        if (ln == 0) invx[wv] = 1.0f / fmaxf(sqrtf(s), 1e-12f);
    }
    __syncthreads();
    if (tid < 768){
        int lg = tid / 384, j = tid - lg*384;
        Sxc[lg][j] *= invx[lg];
    }
    __syncthreads();

    // head MLP: f1 = lrelu(BN1(xc@wf1+bf1)); f2 = lrelu(BN2(f1@wf2+bf2))
    dense_split<2,512,2>(Wtp+OF1, bf1, gbn1, bbn1, bns, &Sxc[0][0], 384, &Sf1[0][0], 512, 384, tid, Spart);
    dense_split<2,256,2>(Wtp+OF2, bf2, gbn2, bbn2, bns, &Sf1[0][0], 512, &Sf2[0][0], 256, 512, tid, Spart);

    // final dot + sigmoid
    if (wv < 2){
        float s = 0.f;
        #pragma unroll
        for (int i=0;i<4;i++){ int c = ln + i*64; s += Sf2[wv][c]*wf3[c]; }
        #pragma unroll
        for (int o=32;o;o>>=1) s += __shfl_xor(s, o, 64);
        if (ln == 0) outp[b0 + wv] = 1.0f/(1.0f + expf(-(s + bf3[0])));
    }
}

extern "C" void kernel_launch(void* const* d_in, const int* in_sizes, int n_in,
                              void* d_out, int out_size, void* d_ws, size_t ws_size,
                              hipStream_t stream)
{
    const float* x1  = (const float*)d_in[0];
    const int*   ei1 = (const int*)  d_in[1];
    const int*   bt1 = (const int*)  d_in[2];
    const float* x2  = (const float*)d_in[3];
    const int*   ei2 = (const int*)  d_in[4];
    const int*   bt2 = (const int*)  d_in[5];
    const float* cell= (const float*)d_in[6];
    const float* wq1=(const float*)d_in[7];  const float* bq1=(const float*)d_in[8];
    const float* wk1=(const float*)d_in[9];  const float* bk1=(const float*)d_in[10];
    const float* wv1=(const float*)d_in[11]; const float* bv1=(const float*)d_in[12];
    const float* ws1=(const float*)d_in[13]; const float* bs1=(const float*)d_in[14];
    const float* wq2=(const float*)d_in[15]; const float* bq2=(const float*)d_in[16];
    const float* wk2=(const float*)d_in[17]; const float* bk2=(const float*)d_in[18];
    const float* wv2=(const float*)d_in[19]; const float* bv2=(const float*)d_in[20];
    const float* ws2=(const float*)d_in[21]; const float* bs2q=(const float*)d_in[22];
    const float* wg1=(const float*)d_in[23]; const float* bg1=(const float*)d_in[24];
    const float* wg2=(const float*)d_in[25]; const float* bg2=(const float*)d_in[26];
    const float* wr1=(const float*)d_in[27]; const float* br1=(const float*)d_in[28];
    const float* wr2=(const float*)d_in[29]; const float* br2=(const float*)d_in[30];
    const float* wr3=(const float*)d_in[31]; const float* br3=(const float*)d_in[32];
    const float* wf1=(const float*)d_in[33]; const float* bf1=(const float*)d_in[34];
    const float* gbn1=(const float*)d_in[35];const float* bbn1=(const float*)d_in[36];
    const float* wf2=(const float*)d_in[37]; const float* bf2=(const float*)d_in[38];
    const float* gbn2=(const float*)d_in[39];const float* bbn2=(const float*)d_in[40];
    const float* wf3=(const float*)d_in[41]; const float* bf3=(const float*)d_in[42];
    float* outp = (float*)d_out;
    (void)in_sizes; (void)n_in; (void)out_size; (void)ws_size;

    const float BNS = 1.0f / sqrtf(1.0f + 1e-5f);

    // ---- workspace arena (R region phase-aliased xa -> h2h) ----
    char* basep = (char*)d_ws;
    size_t off = 0;
    auto alloc = [&](size_t nbytes)->char* {
        char* p = basep + off;
        off += (nbytes + 255) & ~(size_t)255;
        return p;
    };
    int* rowptr2  = (int*)  alloc((size_t)2*(NN+1)*4);
    int* cnt2     = (int*)  alloc((size_t)2*NN*4);
    int* srcs2    = (int*)  alloc((size_t)2*EE*4);
    float* g      = (float*)alloc((size_t)2*BB*1024*4);   // [2B,1024] pooled (raw f32)
    int* bps      = (int*)  alloc((size_t)2*BB*4);
    int* bpe      = (int*)  alloc((size_t)2*BB*4);
    float* b1c    = (float*)alloc((size_t)1024*4);
    float* b2c    = (float*)alloc((size_t)4096*4);
    bf16* W1t     = (bf16*) alloc((size_t)1024*96*2);
    bf16* W2t     = (bf16*) alloc((size_t)2*2048*256*2);
    bf16* Wtp     = (bf16*) alloc((size_t)TAILW_TOTAL*2);
    bf16* h1      = (bf16*) alloc((size_t)2*NN*256*2);    // both branches stacked
    char* R       = alloc((size_t)NN*512*2);              // xa [2NN,96] -> h2h [NN,512]
    bf16* xa      = (bf16*)R;
    bf16* h2h     = (bf16*)R;
    bf16* qkvs    = (bf16*) alloc((size_t)NN*2048*2);     // qkvs1 [2NN,1024] / qkvs2 [NN,2048]

    // ---- prep + CSR (both branches in one pass) ----
    (void)hipMemsetAsync(bps, 0, (size_t)4*BB*4, stream);   // bps+bpe adjacent
    (void)hipMemsetAsync(cnt2, 0, (size_t)2*NN*4, stream);
    prep_all_kernel<<<4500,256,0,stream>>>(wq1,wk1,wv1,ws1, bq1,bk1,bv1,bs1,
                                           wq2,wk2,wv2,ws2, bq2,bk2,bv2,bs2q,
                                           W1t,b1c,W2t,b2c);
    prep_tail_kernel<<<(TAILW_TOTAL+255)/256,256,0,stream>>>(wg1,wg2,wr1,wr2,wr3,wf1,wf2, Wtp);
    hist_kernel<<<2*EE/256,256,0,stream>>>(ei1, ei2, cnt2);
    scan_kernel<<<2,1024,0,stream>>>(cnt2, rowptr2);
    (void)hipMemsetAsync(cnt2, 0, (size_t)2*NN*4, stream);
    scatter_kernel<<<2*EE/256,256,0,stream>>>(ei1, ei2, rowptr2, cnt2, srcs2);
    range_kernel<<<2*NN/256,256,0,stream>>>(bt1, bt2, bps, bpe);

    // ---- layer 1 (both branches stacked): [2NN,96] x [96,1024] -> attn ----
    cvt_x_kernel<<<(2*NN*96)/256,256,0,stream>>>(x1, x2, xa);
    mfma_gemm<<<dim3(1024/128, 2*NN/128),256,0,stream>>>(xa,96, W1t,96, b1c, qkvs,1024, 96);
    attn_kernel<128,1><<<2*NN*2/4,256,0,stream>>>(qkvs,1024, 0,256,512,768, 2, h1,256, rowptr2, srcs2);

    // ---- layer 2: per (branch, head) GEMM + attn + pool ----
    for (int br=0; br<2; br++){
        for (int h=0; h<2; h++){
            mfma_gemm<<<dim3(2048/128, NN/128),256,0,stream>>>(
                h1 + (size_t)br*NN*256, 256, W2t + (size_t)h*2048*256, 256,
                b2c + h*2048, qkvs, 2048, 256);
            attn_kernel<512,0><<<NN/4,256,0,stream>>>(qkvs,2048, 0,512,1024,1536, 1,
                                                      h2h,512, rowptr2 + br*(NN+1), srcs2 + br*EE);
            pool_kernel<<<BB,256,0,stream>>>(h2h, bps + br*BB, bpe + br*BB, g, br*BB, h*512);
        }
    }

    // ---- fused tail: graph-head + cell + head MLP + sigmoid, one dispatch ----
    tail_kernel<<<BB/2,1024,0,stream>>>(g, cell, Wtp,
                                        bg1,bg2, br1,br2,br3,
                                        bf1,gbn1,bbn1, bf2,gbn2,bbn2, wf3,bf3,
                                        BNS, outp);
}

// Round 11
// 625.053 us; speedup vs baseline: 1.2942x; 1.0037x over previous
//
#include <hip/hip_runtime.h>
#include <hip/hip_bf16.h>
#include <math.h>
#include <stdint.h>

typedef __hip_bfloat16 bf16;

#define NN 16384
#define EE 65536
#define BB 512

typedef __attribute__((ext_vector_type(8))) short short8;
typedef __attribute__((ext_vector_type(4))) short short4v;
typedef __attribute__((ext_vector_type(4))) float floatx4;

__device__ __forceinline__ float lrelu_f(float x){ return x >= 0.f ? x : 0.01f*x; }

__device__ __forceinline__ float b2f(short s){
    unsigned int u = ((unsigned int)(unsigned short)s) << 16;
    float f; __builtin_memcpy(&f, &u, 4); return f;
}
__device__ __forceinline__ short f2b(float f){
    bf16 b = (bf16)f;
    short s; __builtin_memcpy(&s, &b, 2); return s;
}

// async 16B global->LDS. LDS dest is wave-uniform base; lane i lands at base+16*i.
__device__ __forceinline__ void gl2lds16(const void* g, void* l){
    __builtin_amdgcn_global_load_lds(
        (__attribute__((address_space(1))) unsigned int*)(uintptr_t)g,
        (__attribute__((address_space(3))) unsigned int*)(uintptr_t)l, 16, 0, 0);
}

// ================= MFMA bf16 GEMM: C[m,n] = A[m,:K] @ W[:,n] + bias[n] =================
// LDS: staging (As+Bs 16K) and epilogue (20K) share one 20.5K arena (staging dead at
// epilogue; K-loop ends with __syncthreads). 36.8K->20.5K per block => more blocks/CU.
__global__ __launch_bounds__(256)
void mfma_gemm(const bf16* __restrict__ A, int lda,
               const bf16* __restrict__ Bt, int ldb,
               const float* __restrict__ bias,
               bf16* __restrict__ C, int ldc, int K)
{
    __shared__ __align__(16) char smem[20480];
    bf16* As  = (bf16*)smem;            // [128*32]
    bf16* Bs  = (bf16*)(smem + 8192);   // [128*32]
    bf16* epi = (bf16*)smem;            // [4*64*40] epilogue (aliases As/Bs)
    const int tid  = threadIdx.x;
    const int wave = tid >> 6;
    const int lane = tid & 63;
    const int wm = (wave & 1) * 64;
    const int wn = (wave >> 1) * 64;
    const int m0 = blockIdx.y * 128;
    const int n0 = blockIdx.x * 128;

    const int srow = lane >> 2;
    const int scol = (lane & 3) * 8;
    const int arow = lane & 15;
    const int aq   = (lane >> 4) * 8;

    floatx4 acc[4][4];
    #pragma unroll
    for (int i=0;i<4;i++)
        #pragma unroll
        for (int j=0;j<4;j++) acc[i][j] = (floatx4){0.f,0.f,0.f,0.f};

    for (int k0 = 0; k0 < K; k0 += 32) {
        #pragma unroll
        for (int i = 0; i < 2; i++) {
            const int chunk = wave*2 + i;
            const int r = chunk*16 + srow;
            gl2lds16(A  + (size_t)(m0 + r)*lda + k0 + scol, As + chunk*512);
            gl2lds16(Bt + (size_t)(n0 + r)*ldb + k0 + scol, Bs + chunk*512);
        }
        __syncthreads();
        short8 af[4], bf_[4];
        #pragma unroll
        for (int i=0;i<4;i++) af[i]  = *(const short8*)(As + (wm + i*16 + arow)*32 + aq);
        #pragma unroll
        for (int j=0;j<4;j++) bf_[j] = *(const short8*)(Bs + (wn + j*16 + arow)*32 + aq);
        #pragma unroll
        for (int i=0;i<4;i++)
            #pragma unroll
            for (int j=0;j<4;j++)
                acc[i][j] = __builtin_amdgcn_mfma_f32_16x16x32_bf16(af[i], bf_[j], acc[i][j], 0,0,0);
        __syncthreads();
    }
    const int crow = (lane >> 4) * 4;
    const int ccol = lane & 15;
    const int erow = lane >> 2;
    const int ecol = (lane & 3) * 8;
    bf16* ep = epi + wave * (64*40);
    #pragma unroll
    for (int j2 = 0; j2 < 2; j2++){
        if (j2) __syncthreads();
        #pragma unroll
        for (int jj = 0; jj < 2; jj++){
            const int j = j2*2 + jj;
            const float bsv = bias[n0 + wn + j*16 + ccol];
            #pragma unroll
            for (int i = 0; i < 4; i++)
                #pragma unroll
                for (int r = 0; r < 4; r++)
                    ep[(i*16 + crow + r)*40 + jj*16 + ccol] = (bf16)(acc[i][j][r] + bsv);
        }
        __syncthreads();
        #pragma unroll
        for (int q = 0; q < 4; q++){
            const int rr = q*16 + erow;
            short8 vv = *(const short8*)(ep + rr*40 + ecol);
            *(short8*)(C + (size_t)(m0 + wm + rr)*ldc + n0 + wn + j2*32 + ecol) = vv;
        }
    }
}

// ================= combined weight/bias prep (1 dispatch) =================
__global__ void prep_all_kernel(const float* __restrict__ wq1, const float* __restrict__ wk1,
                                const float* __restrict__ wv1, const float* __restrict__ ws1,
                                const float* __restrict__ bq1, const float* __restrict__ bk1,
                                const float* __restrict__ bv1, const float* __restrict__ bs1,
                                const float* __restrict__ wq2, const float* __restrict__ wk2,
                                const float* __restrict__ wv2, const float* __restrict__ ws2,
                                const float* __restrict__ bq2, const float* __restrict__ bk2,
                                const float* __restrict__ bv2, const float* __restrict__ bs2v,
                                bf16* __restrict__ W1t, float* __restrict__ b1c,
                                bf16* __restrict__ W2t, float* __restrict__ b2c)
{
    int i = blockIdx.x*256 + threadIdx.x;
    if (i < 98304){                      // W1t: [1024][96]
        int n = i / 96, k = i - n*96;
        const float* w = (n<256)?wq1:(n<512)?wk1:(n<768)?wv1:ws1;
        W1t[i] = (k < 78) ? (bf16)w[(size_t)k*256 + (n & 255)] : (bf16)0.f;
        return;
    }
    i -= 98304;
    if (i < 1024){                       // b1c
        const float* b = (i<256)?bq1:(i<512)?bk1:(i<768)?bv1:bs1;
        b1c[i] = b[i & 255];
        return;
    }
    i -= 1024;
    if (i < 1048576){                    // W2t: [2][2048][256]
        int k = i & 255;
        int j = (i >> 8) & 2047;
        int h = i >> 19;
        const float* w = (j<512)?wq2:(j<1024)?wk2:(j<1536)?wv2:ws2;
        W2t[i] = (bf16)w[(size_t)k*1024 + h*512 + (j & 511)];
        return;
    }
    i -= 1048576;
    if (i < 4096){                       // b2c
        int j = i & 2047, h = i >> 11;
        const float* b = (j<512)?bq2:(j<1024)?bk2:(j<1536)?bv2:bs2v;
        b2c[i] = b[h*512 + (j & 511)];
    }
}

// ---- tail weights: bf16 packed [K/4][N][4] (u = k%4). Offsets in Wtp arena ----
#define OG1 0         // wg1 1024x512 -> 256x512x4
#define OG2 524288    // wg2 512x128  -> 128x128x4
#define OR1 589824    // wr1 954x512  -> 240x512x4 (pad)
#define OR2 1081344   // wr2 512x256  -> 128x256x4
#define OR3 1212416   // wr3 256x128  -> 64x128x4
#define OF1 1245184   // wf1 384x512  -> 96x512x4
#define OF2 1441792   // wf2 512x256  -> 128x256x4
#define TAILW_TOTAL 1572864

__global__ void prep_tail_kernel(const float* __restrict__ wg1, const float* __restrict__ wg2,
                                 const float* __restrict__ wr1, const float* __restrict__ wr2,
                                 const float* __restrict__ wr3, const float* __restrict__ wf1,
                                 const float* __restrict__ wf2, bf16* __restrict__ Wtp)
{
    int i = blockIdx.x*256 + threadIdx.x;
    if (i >= TAILW_TOTAL) return;
    const float* W; int N, K, base;
    if      (i < OG2){ W = wg1; N = 512; K = 1024; base = OG1; }
    else if (i < OR1){ W = wg2; N = 128; K = 512;  base = OG2; }
    else if (i < OR2){ W = wr1; N = 512; K = 954;  base = OR1; }
    else if (i < OR3){ W = wr2; N = 256; K = 512;  base = OR2; }
    else if (i < OF1){ W = wr3; N = 128; K = 256;  base = OR3; }
    else if (i < OF2){ W = wf1; N = 512; K = 384;  base = OF1; }
    else             { W = wf2; N = 256; K = 512;  base = OF2; }
    int loc = i - base;
    int u = loc & 3;
    int j = (loc >> 2) % N;
    int k4 = (loc >> 2) / N;
    int k = k4*4 + u;
    Wtp[i] = (k < K) ? (bf16)W[(size_t)k*N + j] : (bf16)0.f;
}

__global__ void cvt_x_kernel(const float* __restrict__ x1, const float* __restrict__ x2,
                             bf16* __restrict__ xa){
    int i = blockIdx.x*256 + threadIdx.x;          // 2*NN*96
    int r = i / 96, c = i - r*96;
    const float* x = (r >= NN) ? x2 : x1;
    int lr = r & (NN-1);
    xa[i] = (c < 78) ? (bf16)x[(size_t)lr*78 + c] : (bf16)0.f;
}

// ================= CSR build (both branches, stacked) =================
__global__ void hist_kernel(const int* __restrict__ ei1, const int* __restrict__ ei2,
                            int* __restrict__ cnt){
    int eg = blockIdx.x*256 + threadIdx.x;     // 0..2EE
    int br = eg >> 16, e = eg & (EE-1);
    const int* ei = br ? ei2 : ei1;
    atomicAdd(&cnt[br*NN + ei[EE + e]], 1);
}

__global__ __launch_bounds__(1024)
void scan_kernel(const int* __restrict__ hist, int* __restrict__ rowptr){
    const int br = blockIdx.x;
    hist   += br*NN;
    rowptr += br*(NN+1);
    __shared__ int sums[1024];
    const int t = threadIdx.x;
    const int base = t*16;
    int loc[16]; int s = 0;
    #pragma unroll
    for (int i=0;i<16;i++){ loc[i]=s; s += hist[base+i]; }
    sums[t] = s; __syncthreads();
    for (int o=1;o<1024;o<<=1){
        int v = (t>=o) ? sums[t-o] : 0;
        __syncthreads();
        sums[t] += v;
        __syncthreads();
    }
    int pref = (t>0) ? sums[t-1] : 0;
    #pragma unroll
    for (int i=0;i<16;i++) rowptr[base+i] = pref + loc[i];
    if (t==1023) rowptr[NN] = sums[1023];
}

__global__ void scatter_kernel(const int* __restrict__ ei1, const int* __restrict__ ei2,
                               const int* __restrict__ rowptr,
                               int* __restrict__ cnt, int* __restrict__ srcs){
    int eg = blockIdx.x*256 + threadIdx.x;
    int br = eg >> 16, e = eg & (EE-1);
    const int* ei = br ? ei2 : ei1;
    int d = ei[EE + e];
    int pos = rowptr[br*(NN+1) + d] + atomicAdd(&cnt[br*NN + d], 1);
    srcs[br*EE + pos] = ei[e];
}

__global__ void range_kernel(const int* __restrict__ bt1, const int* __restrict__ bt2,
                             int* __restrict__ bps, int* __restrict__ bpe){
    int ng = blockIdx.x*256 + threadIdx.x;     // 0..2NN
    int br = ng >> 14, n = ng & (NN-1);
    const int* bt = br ? bt2 : bt1;
    int b = bt[n];
    if (n==0     || bt[n-1]!=b) bps[br*BB + b] = n;
    if (n==NN-1  || bt[n+1]!=b) bpe[br*BB + b] = n+1;
}

// ================= attention: one wave per (dst node, head), chunked online softmax ====
template<int D, int STACKED>
__global__ __launch_bounds__(256)
void attn_kernel(const bf16* __restrict__ qkvs, int ld, int qo, int ko, int vo, int so, int H,
                 bf16* __restrict__ hout, int ldo,
                 const int* __restrict__ rowptr, const int* __restrict__ srcs)
{
    constexpr int PER = D / 64;
    typedef __attribute__((ext_vector_type(PER))) short shortP;
    const int lane = threadIdx.x & 63;
    const int gw = blockIdx.x * 4 + (threadIdx.x >> 6);
    const int n = gw / H;                 // global node id (stacked: 0..2NN)
    const int h = gw - n*H;
    int nl = n, brNN = 0;
    if (STACKED){
        int br = n >> 14;
        brNN = br*NN; nl = n - brNN;
        rowptr += br*(NN+1); srcs += br*EE;
    }
    const float qscale = rsqrtf((float)D) * 1.44269504f;
    const int hd = h*D + lane*PER;

    const shortP qv = *(const shortP*)(qkvs + (size_t)n*ld + qo + hd);
    float qr[PER];
    #pragma unroll
    for (int i=0;i<PER;i++) qr[i] = b2f(qv[i]) * qscale;

    const int e0 = rowptr[nl], e1 = rowptr[nl+1];
    float m = -INFINITY, z = 0.f;
    float acc[PER];
    #pragma unroll
    for (int i=0;i<PER;i++) acc[i] = 0.f;

    for (int base = e0; base < e1; base += 4){
        const int cnt = min(4, e1 - base);
        int sl = srcs[min(base + (lane & 3), e1 - 1)];
        int src[4];
        #pragma unroll
        for (int j=0;j<4;j++) src[j] = __shfl(sl, j, 64);

        shortP kv[4], vv[4];
        #pragma unroll
        for (int j=0;j<4;j++){
            if (j < cnt){
                const bf16* rp = qkvs + (size_t)(brNN + src[j])*ld;
                kv[j] = *(const shortP*)(rp + ko + hd);
                vv[j] = *(const shortP*)(rp + vo + hd);
            }
        }
        float dt[4];
        #pragma unroll
        for (int j=0;j<4;j++){
            float d = 0.f;
            if (j < cnt){
                #pragma unroll
                for (int i=0;i<PER;i++) d += qr[i]*b2f(kv[j][i]);
            }
            dt[j] = d;
        }
        #pragma unroll
        for (int o=32;o;o>>=1){
            #pragma unroll
            for (int j=0;j<4;j++) dt[j] += __shfl_xor(dt[j], o, 64);
        }
        float cm = -INFINITY;
        #pragma unroll
        for (int j=0;j<4;j++) if (j < cnt) cm = fmaxf(cm, dt[j]);
        const float mn = fmaxf(m, cm);
        const float cs = exp2f(m - mn);
        z *= cs;
        #pragma unroll
        for (int i=0;i<PER;i++) acc[i] *= cs;
        #pragma unroll
        for (int j=0;j<4;j++){
            if (j < cnt){
                const float w = exp2f(dt[j] - mn);
                z += w;
                #pragma unroll
                for (int i=0;i<PER;i++) acc[i] += w*b2f(vv[j][i]);
            }
        }
        m = mn;
    }
    const float invz = 1.0f/(z + 1e-16f);
    const shortP sv = *(const shortP*)(qkvs + (size_t)n*ld + so + hd);
    shortP ov;
    #pragma unroll
    for (int i=0;i<PER;i++) ov[i] = f2b(lrelu_f(b2f(sv[i]) + acc[i]*invz));
    *(shortP*)(hout + (size_t)n*ldo + hd) = ov;
}

// ================= segment-max pool (512 cols, one block per graph) =================
__global__ __launch_bounds__(256)
void pool_kernel(const bf16* __restrict__ h,
                 const int* __restrict__ bps, const int* __restrict__ bpe,
                 float* __restrict__ g, int grow0, int gc0)
{
    typedef __attribute__((ext_vector_type(2))) short short2v;
    const int c = threadIdx.x * 2;
    const int b = blockIdx.x;
    float m0 = -INFINITY, m1 = -INFINITY;
    for (int n = bps[b]; n < bpe[b]; n++){
        const short2v hv = *(const short2v*)(h + (size_t)n*512 + c);
        m0 = fmaxf(m0, b2f(hv[0]));
        m1 = fmaxf(m1, b2f(hv[1]));
    }
    float* gp = g + (size_t)(grow0 + b)*1024 + gc0 + c;
    gp[0] = (m0 == -INFINITY) ? 0.f : m0;
    gp[1] = (m1 == -INFINITY) ? 0.f : m1;
}

// ================= fused MLP tail (1024 threads): split-K dense step, bf16 weights ====
// Wp packed [K/4][N][4]; weights zero-padded to 4-aligned K (prep). Software-pipelined:
// next iteration's 16B/8B weight vector is prefetched before consuming the current one,
// overlapping the ~250cyc L2 latency with FMAs (R10: VALUBusy 45% = exposed W latency).
template<int R, int N, int ACT>
__device__ __forceinline__ void dense_split(
    const bf16* __restrict__ Wp, const float* __restrict__ bias,
    const float* __restrict__ gam, const float* __restrict__ bet, float bns,
    const float* A, int lda, float* C, int ldc, int K, int tid, float* Spart)
{
    constexpr int CT  = (N >= 256) ? 256 : N;
    constexpr int CPT = N / CT;
    constexpr int KG  = 1024 / CT;
    const int ct = tid % CT;
    const int kg = tid / CT;
    const int jt = ct * CPT;
    const int Kc = ((K + KG - 1) / KG + 3) & ~3;
    const int kb = kg * Kc;
    const int Kpad = (K + 3) & ~3;
    const int ke = min(Kpad, kb + Kc);   // 4-aligned (zero-padded weights cover K..Kpad)

    float acc[R][CPT];
    #pragma unroll
    for (int r=0;r<R;r++)
        #pragma unroll
        for (int c=0;c<CPT;c++) acc[r][c] = 0.f;

    if (kb < ke){
        short8  wn8; short4v wn4;
        if (CPT == 2) wn8 = *(const short8*)(Wp + ((size_t)(kb>>2)*N + jt)*4);
        else          wn4 = *(const short4v*)(Wp + ((size_t)(kb>>2)*N + jt)*4);
        for (int k = kb; k < ke; k += 4){
            short8 w8; short4v w4;
            if (CPT == 2) w8 = wn8; else w4 = wn4;
            const int kn = (k + 4 < ke) ? k + 4 : kb;   // dummy last prefetch
            if (CPT == 2) wn8 = *(const short8*)(Wp + ((size_t)(kn>>2)*N + jt)*4);
            else          wn4 = *(const short4v*)(Wp + ((size_t)(kn>>2)*N + jt)*4);
            float w[4][CPT];
            if (CPT == 2){
                #pragma unroll
                for (int u=0;u<4;u++){ w[u][0] = b2f(w8[u]); w[u][1] = b2f(w8[4+u]); }
            } else {
                #pragma unroll
                for (int u=0;u<4;u++) w[u][0] = b2f(w4[u]);
            }
            #pragma unroll
            for (int r=0;r<R;r++){
                const floatx4 av = *(const floatx4*)(A + r*lda + k);
                #pragma unroll
                for (int u=0;u<4;u++)
                    #pragma unroll
                    for (int c=0;c<CPT;c++) acc[r][c] += av[u]*w[u][c];
            }
        }
    }
    #pragma unroll
    for (int r=0;r<R;r++)
        #pragma unroll
        for (int c=0;c<CPT;c++)
            Spart[(kg*R + r)*N + jt + c] = acc[r][c];
    __syncthreads();
    for (int idx = tid; idx < R*N; idx += 1024){
        int r = idx / N, j = idx - r*N;
        float v = 0.f;
        #pragma unroll
        for (int g=0; g<KG; g++) v += Spart[(g*R + r)*N + j];
        v += bias[j];
        if (ACT==1) v = lrelu_f(v);
        if (ACT==2) v = lrelu_f(v*bns*gam[j] + bet[j]);
        C[r*ldc + j] = v;
    }
    __syncthreads();
}

// ================= fused tail: graph-head + cell branch + head MLP, 2 graphs/block ====
__global__ __launch_bounds__(1024)
void tail_kernel(const float* __restrict__ g,            // [2*BB][1024]
                 const float* __restrict__ cell,         // [BB][954]
                 const bf16*  __restrict__ Wtp,          // packed tail weights
                 const float* __restrict__ bg1, const float* __restrict__ bg2,
                 const float* __restrict__ br1, const float* __restrict__ br2,
                 const float* __restrict__ br3,
                 const float* __restrict__ bf1,
                 const float* __restrict__ gbn1, const float* __restrict__ bbn1,
                 const float* __restrict__ bf2,
                 const float* __restrict__ gbn2, const float* __restrict__ bbn2,
                 const float* __restrict__ wf3, const float* __restrict__ bf3,
                 float bns, float* __restrict__ outp)
{
    __shared__ float Sg[4][1024];    // rows: lg*2 + br
    __shared__ float Sgh[4][512];
    __shared__ float Sgout[4][128];
    __shared__ float Scell[2][960];
    __shared__ float Sc1[2][512];
    __shared__ float Sc2[2][256];
    __shared__ float Sc3[2][128];
    __shared__ float Sxc[2][384];
    __shared__ float Sf1[2][512];
    __shared__ float Sf2[2][256];
    __shared__ float Spart[8192];    // split-K partials (max KG*R*N = 4*4*512)
    __shared__ float inv4[4], invc[2], invx[2];

    const int tid = threadIdx.x;
    const int wv  = tid >> 6;
    const int ln  = tid & 63;
    const int b0  = blockIdx.x * 2;

    // load g rows (vectorized) and cell rows
    {
        int idx = tid*4;                 // 0..4092
        int r = idx >> 10, c = idx & 1023;
        int lg = r >> 1, br = r & 1;
        *(floatx4*)&Sg[r][c] = *(const floatx4*)(g + (size_t)(br*BB + b0 + lg)*1024 + c);
    }
    for (int idx = tid; idx < 2*954; idx += 1024){
        int r = (idx >= 954) ? 1 : 0;
        int c = idx - r*954;
        Scell[r][c] = cell[(size_t)(b0 + r)*954 + c];
    }
    if (tid < 12){ int r = tid/6; Scell[r][954 + tid%6] = 0.f; }  // zero pad (k-loop reads to 955)
    __syncthreads();

    // cell l2n (waves 0-1)
    if (wv < 2){
        float s = 0.f;
        for (int c = ln; c < 954; c += 64){ float v = Scell[wv][c]; s += v*v; }
        #pragma unroll
        for (int o=32;o;o>>=1) s += __shfl_xor(s, o, 64);
        if (ln == 0) invc[wv] = 1.0f / fmaxf(sqrtf(s), 1e-12f);
    }
    __syncthreads();
    #pragma unroll
    for (int r=0;r<2;r++)
        for (int c = tid; c < 954; c += 1024) Scell[r][c] *= invc[r];
    __syncthreads();

    // graph head: gh = lrelu(g@wg1+bg1); gout = gh@wg2 + bg2
    dense_split<4,512,1>(Wtp+OG1, bg1, nullptr, nullptr, 1.f, &Sg[0][0],   1024, &Sgh[0][0],  512, 1024, tid, Spart);
    dense_split<4,128,0>(Wtp+OG2, bg2, nullptr, nullptr, 1.f, &Sgh[0][0],  512,  &Sgout[0][0],128, 512,  tid, Spart);
    // cell: c1 = lrelu(cn@wr1+br1); c2 = lrelu(c1@wr2+br2); c3 = c2@wr3+br3
    dense_split<2,512,1>(Wtp+OR1, br1, nullptr, nullptr, 1.f, &Scell[0][0], 960, &Sc1[0][0],  512, 954,  tid, Spart);
    dense_split<2,256,1>(Wtp+OR2, br2, nullptr, nullptr, 1.f, &Sc1[0][0],   512, &Sc2[0][0],  256, 512,  tid, Spart);
    dense_split<2,128,0>(Wtp+OR3, br3, nullptr, nullptr, 1.f, &Sc2[0][0],   256, &Sc3[0][0],  128, 256,  tid, Spart);

    // l2n per gout row (4 rows x 128)
    if (wv < 4){
        float a = Sgout[wv][ln], bq = Sgout[wv][ln+64];
        float s = a*a + bq*bq;
        #pragma unroll
        for (int o=32;o;o>>=1) s += __shfl_xor(s, o, 64);
        if (ln == 0) inv4[wv] = 1.0f / fmaxf(sqrtf(s), 1e-12f);
    }
    __syncthreads();

    // build xc rows (2 x 384)
    if (tid < 768){
        int lg = tid / 384, j = tid - lg*384;
        float v;
        if (j < 128)      v = Sgout[lg*2+0][j]     * inv4[lg*2+0];
        else if (j < 256) v = Sgout[lg*2+1][j-128] * inv4[lg*2+1];
        else              v = Sc3[lg][j-256];
        Sxc[lg][j] = v;
    }
    __syncthreads();
    if (wv < 2){
        float s = 0.f;
        #pragma unroll
        for (int i=0;i<6;i++){ float v = Sxc[wv][ln + i*64]; s += v*v; }
        #pragma unroll
        for (int o=32;o;o>>=1) s += __shfl_xor(s, o, 64);
        if (ln == 0) invx[wv] = 1.0f / fmaxf(sqrtf(s), 1e-12f);
    }
    __syncthreads();
    if (tid < 768){
        int lg = tid / 384, j = tid - lg*384;
        Sxc[lg][j] *= invx[lg];
    }
    __syncthreads();

    // head MLP: f1 = lrelu(BN1(xc@wf1+bf1)); f2 = lrelu(BN2(f1@wf2+bf2))
    dense_split<2,512,2>(Wtp+OF1, bf1, gbn1, bbn1, bns, &Sxc[0][0], 384, &Sf1[0][0], 512, 384, tid, Spart);
    dense_split<2,256,2>(Wtp+OF2, bf2, gbn2, bbn2, bns, &Sf1[0][0], 512, &Sf2[0][0], 256, 512, tid, Spart);

    // final dot + sigmoid
    if (wv < 2){
        float s = 0.f;
        #pragma unroll
        for (int i=0;i<4;i++){ int c = ln + i*64; s += Sf2[wv][c]*wf3[c]; }
        #pragma unroll
        for (int o=32;o;o>>=1) s += __shfl_xor(s, o, 64);
        if (ln == 0) outp[b0 + wv] = 1.0f/(1.0f + expf(-(s + bf3[0])));
    }
}

extern "C" void kernel_launch(void* const* d_in, const int* in_sizes, int n_in,
                              void* d_out, int out_size, void* d_ws, size_t ws_size,
                              hipStream_t stream)
{
    const float* x1  = (const float*)d_in[0];
    const int*   ei1 = (const int*)  d_in[1];
    const int*   bt1 = (const int*)  d_in[2];
    const float* x2  = (const float*)d_in[3];
    const int*   ei2 = (const int*)  d_in[4];
    const int*   bt2 = (const int*)  d_in[5];
    const float* cell= (const float*)d_in[6];
    const float* wq1=(const float*)d_in[7];  const float* bq1=(const float*)d_in[8];
    const float* wk1=(const float*)d_in[9];  const float* bk1=(const float*)d_in[10];
    const float* wv1=(const float*)d_in[11]; const float* bv1=(const float*)d_in[12];
    const float* ws1=(const float*)d_in[13]; const float* bs1=(const float*)d_in[14];
    const float* wq2=(const float*)d_in[15]; const float* bq2=(const float*)d_in[16];
    const float* wk2=(const float*)d_in[17]; const float* bk2=(const float*)d_in[18];
    const float* wv2=(const float*)d_in[19]; const float* bv2=(const float*)d_in[20];
    const float* ws2=(const float*)d_in[21]; const float* bs2q=(const float*)d_in[22];
    const float* wg1=(const float*)d_in[23]; const float* bg1=(const float*)d_in[24];
    const float* wg2=(const float*)d_in[25]; const float* bg2=(const float*)d_in[26];
    const float* wr1=(const float*)d_in[27]; const float* br1=(const float*)d_in[28];
    const float* wr2=(const float*)d_in[29]; const float* br2=(const float*)d_in[30];
    const float* wr3=(const float*)d_in[31]; const float* br3=(const float*)d_in[32];
    const float* wf1=(const float*)d_in[33]; const float* bf1=(const float*)d_in[34];
    const float* gbn1=(const float*)d_in[35];const float* bbn1=(const float*)d_in[36];
    const float* wf2=(const float*)d_in[37]; const float* bf2=(const float*)d_in[38];
    const float* gbn2=(const float*)d_in[39];const float* bbn2=(const float*)d_in[40];
    const float* wf3=(const float*)d_in[41]; const float* bf3=(const float*)d_in[42];
    float* outp = (float*)d_out;
    (void)in_sizes; (void)n_in; (void)out_size; (void)ws_size;

    const float BNS = 1.0f / sqrtf(1.0f + 1e-5f);

    // ---- workspace arena (R region phase-aliased xa -> h2h) ----
    char* basep = (char*)d_ws;
    size_t off = 0;
    auto alloc = [&](size_t nbytes)->char* {
        char* p = basep + off;
        off += (nbytes + 255) & ~(size_t)255;
        return p;
    };
    int* rowptr2  = (int*)  alloc((size_t)2*(NN+1)*4);
    int* cnt2     = (int*)  alloc((size_t)2*NN*4);
    int* srcs2    = (int*)  alloc((size_t)2*EE*4);
    float* g      = (float*)alloc((size_t)2*BB*1024*4);   // [2B,1024] pooled (raw f32)
    int* bps      = (int*)  alloc((size_t)2*BB*4);
    int* bpe      = (int*)  alloc((size_t)2*BB*4);
    float* b1c    = (float*)alloc((size_t)1024*4);
    float* b2c    = (float*)alloc((size_t)4096*4);
    bf16* W1t     = (bf16*) alloc((size_t)1024*96*2);
    bf16* W2t     = (bf16*) alloc((size_t)2*2048*256*2);
    bf16* Wtp     = (bf16*) alloc((size_t)TAILW_TOTAL*2);
    bf16* h1      = (bf16*) alloc((size_t)2*NN*256*2);    // both branches stacked
    char* R       = alloc((size_t)NN*512*2);              // xa [2NN,96] -> h2h [NN,512]
    bf16* xa      = (bf16*)R;
    bf16* h2h     = (bf16*)R;
    bf16* qkvs    = (bf16*) alloc((size_t)NN*2048*2);     // qkvs1 [2NN,1024] / qkvs2 [NN,2048]

    // ---- prep + CSR (both branches in one pass) ----
    (void)hipMemsetAsync(bps, 0, (size_t)4*BB*4, stream);   // bps+bpe adjacent
    (void)hipMemsetAsync(cnt2, 0, (size_t)2*NN*4, stream);
    prep_all_kernel<<<4500,256,0,stream>>>(wq1,wk1,wv1,ws1, bq1,bk1,bv1,bs1,
                                           wq2,wk2,wv2,ws2, bq2,bk2,bv2,bs2q,
                                           W1t,b1c,W2t,b2c);
    prep_tail_kernel<<<(TAILW_TOTAL+255)/256,256,0,stream>>>(wg1,wg2,wr1,wr2,wr3,wf1,wf2, Wtp);
    hist_kernel<<<2*EE/256,256,0,stream>>>(ei1, ei2, cnt2);
    scan_kernel<<<2,1024,0,stream>>>(cnt2, rowptr2);
    (void)hipMemsetAsync(cnt2, 0, (size_t)2*NN*4, stream);
    scatter_kernel<<<2*EE/256,256,0,stream>>>(ei1, ei2, rowptr2, cnt2, srcs2);
    range_kernel<<<2*NN/256,256,0,stream>>>(bt1, bt2, bps, bpe);

    // ---- layer 1 (both branches stacked): [2NN,96] x [96,1024] -> attn ----
    cvt_x_kernel<<<(2*NN*96)/256,256,0,stream>>>(x1, x2, xa);
    mfma_gemm<<<dim3(1024/128, 2*NN/128),256,0,stream>>>(xa,96, W1t,96, b1c, qkvs,1024, 96);
    attn_kernel<128,1><<<2*NN*2/4,256,0,stream>>>(qkvs,1024, 0,256,512,768, 2, h1,256, rowptr2, srcs2);

    // ---- layer 2: per (branch, head) GEMM + attn + pool ----
    for (int br=0; br<2; br++){
        for (int h=0; h<2; h++){
            mfma_gemm<<<dim3(2048/128, NN/128),256,0,stream>>>(
                h1 + (size_t)br*NN*256, 256, W2t + (size_t)h*2048*256, 256,
                b2c + h*2048, qkvs, 2048, 256);
            attn_kernel<512,0><<<NN/4,256,0,stream>>>(qkvs,2048, 0,512,1024,1536, 1,
                                                      h2h,512, rowptr2 + br*(NN+1), srcs2 + br*EE);
            pool_kernel<<<BB,256,0,stream>>>(h2h, bps + br*BB, bpe + br*BB, g, br*BB, h*512);
        }
    }

    // ---- fused tail: graph-head + cell + head MLP + sigmoid, one dispatch ----
    tail_kernel<<<BB/2,1024,0,stream>>>(g, cell, Wtp,
                                        bg1,bg2, br1,br2,br3,
                                        bf1,gbn1,bbn1, bf2,gbn2,bbn2, wf3,bf3,
                                        BNS, outp);
}

// Round 12
// 615.562 us; speedup vs baseline: 1.3142x; 1.0154x over previous
//
#include <hip/hip_runtime.h>
#include <hip/hip_bf16.h>
#include <hip/hip_fp8.h>
#include <math.h>
#include <stdint.h>

typedef __hip_bfloat16 bf16;

#define NN 16384
#define EE 65536
#define BB 512

typedef __attribute__((ext_vector_type(8))) short short8;
typedef __attribute__((ext_vector_type(4))) short short4v;
typedef __attribute__((ext_vector_type(4))) float floatx4;
typedef __attribute__((ext_vector_type(8))) unsigned char uchar8;

__device__ __forceinline__ float lrelu_f(float x){ return x >= 0.f ? x : 0.01f*x; }

__device__ __forceinline__ float b2f(short s){
    unsigned int u = ((unsigned int)(unsigned short)s) << 16;
    float f; __builtin_memcpy(&f, &u, 4); return f;
}
__device__ __forceinline__ short f2b(float f){
    bf16 b = (bf16)f;
    short s; __builtin_memcpy(&s, &b, 2); return s;
}
__device__ __forceinline__ unsigned char f2fp8(float f){
    __hip_fp8_e4m3 t(f);
    return (unsigned char)t.__x;
}
__device__ __forceinline__ float fp82f(unsigned char c){
    __hip_fp8_e4m3 t; t.__x = (__hip_fp8_storage_t)c;
    return (float)t;
}

// async 16B global->LDS. LDS dest is wave-uniform base; lane i lands at base+16*i.
__device__ __forceinline__ void gl2lds16(const void* g, void* l){
    __builtin_amdgcn_global_load_lds(
        (__attribute__((address_space(1))) unsigned int*)(uintptr_t)g,
        (__attribute__((address_space(3))) unsigned int*)(uintptr_t)l, 16, 0, 0);
}

// ================= MFMA bf16 GEMM: C[m,n] = A[m,:K] @ W[:,n] + bias[n] =================
// Blocks with n0 < nsplit store bf16 to C (ldc); blocks with n0 >= nsplit convert to
// fp8-e4m3 and store to C2 (ldc2) at col n-nsplit. LDS: staging and epilogue aliased.
__global__ __launch_bounds__(256)
void mfma_gemm(const bf16* __restrict__ A, int lda,
               const bf16* __restrict__ Bt, int ldb,
               const float* __restrict__ bias,
               bf16* __restrict__ C, int ldc,
               unsigned char* __restrict__ C2, int ldc2, int nsplit, int K)
{
    __shared__ __align__(16) char smem[20480];
    bf16* As  = (bf16*)smem;            // [128*32]
    bf16* Bs  = (bf16*)(smem + 8192);   // [128*32]
    bf16* epi = (bf16*)smem;            // [4*64*40] epilogue (aliases As/Bs)
    const int tid  = threadIdx.x;
    const int wave = tid >> 6;
    const int lane = tid & 63;
    const int wm = (wave & 1) * 64;
    const int wn = (wave >> 1) * 64;
    const int m0 = blockIdx.y * 128;
    const int n0 = blockIdx.x * 128;
    const bool isf8 = (n0 >= nsplit);

    const int srow = lane >> 2;
    const int scol = (lane & 3) * 8;
    const int arow = lane & 15;
    const int aq   = (lane >> 4) * 8;

    floatx4 acc[4][4];
    #pragma unroll
    for (int i=0;i<4;i++)
        #pragma unroll
        for (int j=0;j<4;j++) acc[i][j] = (floatx4){0.f,0.f,0.f,0.f};

    for (int k0 = 0; k0 < K; k0 += 32) {
        #pragma unroll
        for (int i = 0; i < 2; i++) {
            const int chunk = wave*2 + i;
            const int r = chunk*16 + srow;
            gl2lds16(A  + (size_t)(m0 + r)*lda + k0 + scol, As + chunk*512);
            gl2lds16(Bt + (size_t)(n0 + r)*ldb + k0 + scol, Bs + chunk*512);
        }
        __syncthreads();
        short8 af[4], bf_[4];
        #pragma unroll
        for (int i=0;i<4;i++) af[i]  = *(const short8*)(As + (wm + i*16 + arow)*32 + aq);
        #pragma unroll
        for (int j=0;j<4;j++) bf_[j] = *(const short8*)(Bs + (wn + j*16 + arow)*32 + aq);
        #pragma unroll
        for (int i=0;i<4;i++)
            #pragma unroll
            for (int j=0;j<4;j++)
                acc[i][j] = __builtin_amdgcn_mfma_f32_16x16x32_bf16(af[i], bf_[j], acc[i][j], 0,0,0);
        __syncthreads();
    }
    const int crow = (lane >> 4) * 4;
    const int ccol = lane & 15;
    const int erow = lane >> 2;
    const int ecol = (lane & 3) * 8;
    bf16* ep = epi + wave * (64*40);
    #pragma unroll
    for (int j2 = 0; j2 < 2; j2++){
        if (j2) __syncthreads();
        #pragma unroll
        for (int jj = 0; jj < 2; jj++){
            const int j = j2*2 + jj;
            const float bsv = bias[n0 + wn + j*16 + ccol];
            #pragma unroll
            for (int i = 0; i < 4; i++)
                #pragma unroll
                for (int r = 0; r < 4; r++)
                    ep[(i*16 + crow + r)*40 + jj*16 + ccol] = (bf16)(acc[i][j][r] + bsv);
        }
        __syncthreads();
        #pragma unroll
        for (int q = 0; q < 4; q++){
            const int rr = q*16 + erow;
            short8 vv = *(const short8*)(ep + rr*40 + ecol);
            if (!isf8){
                *(short8*)(C + (size_t)(m0 + wm + rr)*ldc + n0 + wn + j2*32 + ecol) = vv;
            } else {
                uchar8 ob;
                #pragma unroll
                for (int i=0;i<8;i++) ob[i] = f2fp8(b2f(vv[i]));
                *(uchar8*)(C2 + (size_t)(m0 + wm + rr)*ldc2 + (n0 - nsplit) + wn + j2*32 + ecol) = ob;
            }
        }
    }
}

// ================= combined weight/bias prep (1 dispatch) =================
// W2t reordered per head to q|s|k|v (fp8 k/v cols contiguous in the upper half).
__global__ void prep_all_kernel(const float* __restrict__ wq1, const float* __restrict__ wk1,
                                const float* __restrict__ wv1, const float* __restrict__ ws1,
                                const float* __restrict__ bq1, const float* __restrict__ bk1,
                                const float* __restrict__ bv1, const float* __restrict__ bs1,
                                const float* __restrict__ wq2, const float* __restrict__ wk2,
                                const float* __restrict__ wv2, const float* __restrict__ ws2,
                                const float* __restrict__ bq2, const float* __restrict__ bk2,
                                const float* __restrict__ bv2, const float* __restrict__ bs2v,
                                bf16* __restrict__ W1t, float* __restrict__ b1c,
                                bf16* __restrict__ W2t, float* __restrict__ b2c)
{
    int i = blockIdx.x*256 + threadIdx.x;
    if (i < 98304){                      // W1t: [1024][96] (q|k|v|s)
        int n = i / 96, k = i - n*96;
        const float* w = (n<256)?wq1:(n<512)?wk1:(n<768)?wv1:ws1;
        W1t[i] = (k < 78) ? (bf16)w[(size_t)k*256 + (n & 255)] : (bf16)0.f;
        return;
    }
    i -= 98304;
    if (i < 1024){                       // b1c
        const float* b = (i<256)?bq1:(i<512)?bk1:(i<768)?bv1:bs1;
        b1c[i] = b[i & 255];
        return;
    }
    i -= 1024;
    if (i < 1048576){                    // W2t: [2][2048][256], order q|s|k|v
        int k = i & 255;
        int j = (i >> 8) & 2047;
        int h = i >> 19;
        const float* w = (j<512)?wq2:(j<1024)?ws2:(j<1536)?wk2:wv2;
        int col = h*512 + (j & 511);
        W2t[i] = (bf16)w[(size_t)k*1024 + col];
        return;
    }
    i -= 1048576;
    if (i < 4096){                       // b2c (q|s|k|v)
        int j = i & 2047, h = i >> 11;
        const float* b = (j<512)?bq2:(j<1024)?bs2v:(j<1536)?bk2:bv2;
        b2c[i] = b[h*512 + (j & 511)];
    }
}

// ---- tail weights: bf16 packed [K/4][N][4] (u = k%4). Offsets in Wtp arena ----
#define OG1 0         // wg1 1024x512 -> 256x512x4
#define OG2 524288    // wg2 512x128  -> 128x128x4
#define OR1 589824    // wr1 954x512  -> 240x512x4 (pad)
#define OR2 1081344   // wr2 512x256  -> 128x256x4
#define OR3 1212416   // wr3 256x128  -> 64x128x4
#define OF1 1245184   // wf1 384x512  -> 96x512x4
#define OF2 1441792   // wf2 512x256  -> 128x256x4
#define TAILW_TOTAL 1572864

__global__ void prep_tail_kernel(const float* __restrict__ wg1, const float* __restrict__ wg2,
                                 const float* __restrict__ wr1, const float* __restrict__ wr2,
                                 const float* __restrict__ wr3, const float* __restrict__ wf1,
                                 const float* __restrict__ wf2, bf16* __restrict__ Wtp)
{
    int i = blockIdx.x*256 + threadIdx.x;
    if (i >= TAILW_TOTAL) return;
    const float* W; int N, K, base;
    if      (i < OG2){ W = wg1; N = 512; K = 1024; base = OG1; }
    else if (i < OR1){ W = wg2; N = 128; K = 512;  base = OG2; }
    else if (i < OR2){ W = wr1; N = 512; K = 954;  base = OR1; }
    else if (i < OR3){ W = wr2; N = 256; K = 512;  base = OR2; }
    else if (i < OF1){ W = wr3; N = 128; K = 256;  base = OR3; }
    else if (i < OF2){ W = wf1; N = 512; K = 384;  base = OF1; }
    else             { W = wf2; N = 256; K = 512;  base = OF2; }
    int loc = i - base;
    int u = loc & 3;
    int j = (loc >> 2) % N;
    int k4 = (loc >> 2) / N;
    int k = k4*4 + u;
    Wtp[i] = (k < K) ? (bf16)W[(size_t)k*N + j] : (bf16)0.f;
}

__global__ void cvt_x_kernel(const float* __restrict__ x1, const float* __restrict__ x2,
                             bf16* __restrict__ xa){
    int i = blockIdx.x*256 + threadIdx.x;          // 2*NN*96
    int r = i / 96, c = i - r*96;
    const float* x = (r >= NN) ? x2 : x1;
    int lr = r & (NN-1);
    xa[i] = (c < 78) ? (bf16)x[(size_t)lr*78 + c] : (bf16)0.f;
}

// ================= CSR build (both branches, stacked) =================
__global__ void hist_kernel(const int* __restrict__ ei1, const int* __restrict__ ei2,
                            int* __restrict__ cnt){
    int eg = blockIdx.x*256 + threadIdx.x;     // 0..2EE
    int br = eg >> 16, e = eg & (EE-1);
    const int* ei = br ? ei2 : ei1;
    atomicAdd(&cnt[br*NN + ei[EE + e]], 1);
}

__global__ __launch_bounds__(1024)
void scan_kernel(const int* __restrict__ hist, int* __restrict__ rowptr){
    const int br = blockIdx.x;
    hist   += br*NN;
    rowptr += br*(NN+1);
    __shared__ int sums[1024];
    const int t = threadIdx.x;
    const int base = t*16;
    int loc[16]; int s = 0;
    #pragma unroll
    for (int i=0;i<16;i++){ loc[i]=s; s += hist[base+i]; }
    sums[t] = s; __syncthreads();
    for (int o=1;o<1024;o<<=1){
        int v = (t>=o) ? sums[t-o] : 0;
        __syncthreads();
        sums[t] += v;
        __syncthreads();
    }
    int pref = (t>0) ? sums[t-1] : 0;
    #pragma unroll
    for (int i=0;i<16;i++) rowptr[base+i] = pref + loc[i];
    if (t==1023) rowptr[NN] = sums[1023];
}

__global__ void scatter_kernel(const int* __restrict__ ei1, const int* __restrict__ ei2,
                               const int* __restrict__ rowptr,
                               int* __restrict__ cnt, int* __restrict__ srcs){
    int eg = blockIdx.x*256 + threadIdx.x;
    int br = eg >> 16, e = eg & (EE-1);
    const int* ei = br ? ei2 : ei1;
    int d = ei[EE + e];
    int pos = rowptr[br*(NN+1) + d] + atomicAdd(&cnt[br*NN + d], 1);
    srcs[br*EE + pos] = ei[e];
}

__global__ void range_kernel(const int* __restrict__ bt1, const int* __restrict__ bt2,
                             int* __restrict__ bps, int* __restrict__ bpe){
    int ng = blockIdx.x*256 + threadIdx.x;     // 0..2NN
    int br = ng >> 14, n = ng & (NN-1);
    const int* bt = br ? bt2 : bt1;
    int b = bt[n];
    if (n==0     || bt[n-1]!=b) bps[br*BB + b] = n;
    if (n==NN-1  || bt[n+1]!=b) bpe[br*BB + b] = n+1;
}

// ================= attention layer-1 (bf16 qkvs, stacked branches) =================
template<int D>
__global__ __launch_bounds__(256)
void attn_kernel(const bf16* __restrict__ qkvs, int ld, int qo, int ko, int vo, int so, int H,
                 bf16* __restrict__ hout, int ldo,
                 const int* __restrict__ rowptr, const int* __restrict__ srcs)
{
    constexpr int PER = D / 64;
    typedef __attribute__((ext_vector_type(PER))) short shortP;
    const int lane = threadIdx.x & 63;
    const int gw = blockIdx.x * 4 + (threadIdx.x >> 6);
    const int n = gw / H;                 // global node id (stacked: 0..2NN)
    const int h = gw - n*H;
    int br = n >> 14;
    int brNN = br*NN, nl = n - brNN;
    rowptr += br*(NN+1); srcs += br*EE;
    const float qscale = rsqrtf((float)D) * 1.44269504f;
    const int hd = h*D + lane*PER;

    const shortP qv = *(const shortP*)(qkvs + (size_t)n*ld + qo + hd);
    float qr[PER];
    #pragma unroll
    for (int i=0;i<PER;i++) qr[i] = b2f(qv[i]) * qscale;

    const int e0 = rowptr[nl], e1 = rowptr[nl+1];
    float m = -INFINITY, z = 0.f;
    float acc[PER];
    #pragma unroll
    for (int i=0;i<PER;i++) acc[i] = 0.f;

    for (int base = e0; base < e1; base += 4){
        const int cnt = min(4, e1 - base);
        int sl = srcs[min(base + (lane & 3), e1 - 1)];
        int src[4];
        #pragma unroll
        for (int j=0;j<4;j++) src[j] = __shfl(sl, j, 64);

        shortP kv[4], vv[4];
        #pragma unroll
        for (int j=0;j<4;j++){
            if (j < cnt){
                const bf16* rp = qkvs + (size_t)(brNN + src[j])*ld;
                kv[j] = *(const shortP*)(rp + ko + hd);
                vv[j] = *(const shortP*)(rp + vo + hd);
            }
        }
        float dt[4];
        #pragma unroll
        for (int j=0;j<4;j++){
            float d = 0.f;
            if (j < cnt){
                #pragma unroll
                for (int i=0;i<PER;i++) d += qr[i]*b2f(kv[j][i]);
            }
            dt[j] = d;
        }
        #pragma unroll
        for (int o=32;o;o>>=1){
            #pragma unroll
            for (int j=0;j<4;j++) dt[j] += __shfl_xor(dt[j], o, 64);
        }
        float cm = -INFINITY;
        #pragma unroll
        for (int j=0;j<4;j++) if (j < cnt) cm = fmaxf(cm, dt[j]);
        const float mn = fmaxf(m, cm);
        const float cs = exp2f(m - mn);
        z *= cs;
        #pragma unroll
        for (int i=0;i<PER;i++) acc[i] *= cs;
        #pragma unroll
        for (int j=0;j<4;j++){
            if (j < cnt){
                const float w = exp2f(dt[j] - mn);
                z += w;
                #pragma unroll
                for (int i=0;i<PER;i++) acc[i] += w*b2f(vv[j][i]);
            }
        }
        m = mn;
    }
    const float invz = 1.0f/(z + 1e-16f);
    const shortP sv = *(const shortP*)(qkvs + (size_t)n*ld + so + hd);
    shortP ov;
    #pragma unroll
    for (int i=0;i<PER;i++) ov[i] = f2b(lrelu_f(b2f(sv[i]) + acc[i]*invz));
    *(shortP*)(hout + (size_t)n*ldo + hd) = ov;
}

// ================= attention layer-2: q/s bf16 [NN,1024], k/v fp8 [NN,1024] ==========
__global__ __launch_bounds__(256)
void attn512_f8(const bf16* __restrict__ qs, const unsigned char* __restrict__ kv,
                bf16* __restrict__ hout,
                const int* __restrict__ rowptr, const int* __restrict__ srcs)
{
    const int lane = threadIdx.x & 63;
    const int n = blockIdx.x * 4 + (threadIdx.x >> 6);
    const float qscale = rsqrtf(512.f) * 1.44269504f;
    const int hd = lane*8;

    const short8 qv = *(const short8*)(qs + (size_t)n*1024 + hd);
    float qr[8];
    #pragma unroll
    for (int i=0;i<8;i++) qr[i] = b2f(qv[i]) * qscale;

    const int e0 = rowptr[n], e1 = rowptr[n+1];
    float m = -INFINITY, z = 0.f;
    float acc[8];
    #pragma unroll
    for (int i=0;i<8;i++) acc[i] = 0.f;

    for (int base = e0; base < e1; base += 4){
        const int cnt = min(4, e1 - base);
        int sl = srcs[min(base + (lane & 3), e1 - 1)];
        int src[4];
        #pragma unroll
        for (int j=0;j<4;j++) src[j] = __shfl(sl, j, 64);

        uchar8 k8[4], v8[4];
        #pragma unroll
        for (int j=0;j<4;j++){
            if (j < cnt){
                const unsigned char* rp = kv + (size_t)src[j]*1024;
                k8[j] = *(const uchar8*)(rp + hd);
                v8[j] = *(const uchar8*)(rp + 512 + hd);
            }
        }
        float dt[4];
        #pragma unroll
        for (int j=0;j<4;j++){
            float d = 0.f;
            if (j < cnt){
                #pragma unroll
                for (int i=0;i<8;i++) d += qr[i]*fp82f(k8[j][i]);
            }
            dt[j] = d;
        }
        #pragma unroll
        for (int o=32;o;o>>=1){
            #pragma unroll
            for (int j=0;j<4;j++) dt[j] += __shfl_xor(dt[j], o, 64);
        }
        float cm = -INFINITY;
        #pragma unroll
        for (int j=0;j<4;j++) if (j < cnt) cm = fmaxf(cm, dt[j]);
        const float mn = fmaxf(m, cm);
        const float cs = exp2f(m - mn);
        z *= cs;
        #pragma unroll
        for (int i=0;i<8;i++) acc[i] *= cs;
        #pragma unroll
        for (int j=0;j<4;j++){
            if (j < cnt){
                const float w = exp2f(dt[j] - mn);
                z += w;
                #pragma unroll
                for (int i=0;i<8;i++) acc[i] += w*fp82f(v8[j][i]);
            }
        }
        m = mn;
    }
    const float invz = 1.0f/(z + 1e-16f);
    const short8 sv = *(const short8*)(qs + (size_t)n*1024 + 512 + hd);
    short8 ov;
    #pragma unroll
    for (int i=0;i<8;i++) ov[i] = f2b(lrelu_f(b2f(sv[i]) + acc[i]*invz));
    *(short8*)(hout + (size_t)n*512 + hd) = ov;
}

// ================= segment-max pool (512 cols, one block per graph) =================
__global__ __launch_bounds__(256)
void pool_kernel(const bf16* __restrict__ h,
                 const int* __restrict__ bps, const int* __restrict__ bpe,
                 float* __restrict__ g, int grow0, int gc0)
{
    typedef __attribute__((ext_vector_type(2))) short short2v;
    const int c = threadIdx.x * 2;
    const int b = blockIdx.x;
    float m0 = -INFINITY, m1 = -INFINITY;
    for (int n = bps[b]; n < bpe[b]; n++){
        const short2v hv = *(const short2v*)(h + (size_t)n*512 + c);
        m0 = fmaxf(m0, b2f(hv[0]));
        m1 = fmaxf(m1, b2f(hv[1]));
    }
    float* gp = g + (size_t)(grow0 + b)*1024 + gc0 + c;
    gp[0] = (m0 == -INFINITY) ? 0.f : m0;
    gp[1] = (m1 == -INFINITY) ? 0.f : m1;
}

// ================= fused MLP tail (1024 threads): split-K dense step, bf16 weights ====
template<int R, int N, int ACT>
__device__ __forceinline__ void dense_split(
    const bf16* __restrict__ Wp, const float* __restrict__ bias,
    const float* __restrict__ gam, const float* __restrict__ bet, float bns,
    const float* A, int lda, float* C, int ldc, int K, int tid, float* Spart)
{
    constexpr int CT  = (N >= 256) ? 256 : N;
    constexpr int CPT = N / CT;
    constexpr int KG  = 1024 / CT;
    const int ct = tid % CT;
    const int kg = tid / CT;
    const int jt = ct * CPT;
    const int Kc = ((K + KG - 1) / KG + 3) & ~3;
    const int kb = kg * Kc;
    const int Kpad = (K + 3) & ~3;
    const int ke = min(Kpad, kb + Kc);

    float acc[R][CPT];
    #pragma unroll
    for (int r=0;r<R;r++)
        #pragma unroll
        for (int c=0;c<CPT;c++) acc[r][c] = 0.f;

    if (kb < ke){
        short8  wn8; short4v wn4;
        if (CPT == 2) wn8 = *(const short8*)(Wp + ((size_t)(kb>>2)*N + jt)*4);
        else          wn4 = *(const short4v*)(Wp + ((size_t)(kb>>2)*N + jt)*4);
        for (int k = kb; k < ke; k += 4){
            short8 w8; short4v w4;
            if (CPT == 2) w8 = wn8; else w4 = wn4;
            const int kn = (k + 4 < ke) ? k + 4 : kb;
            if (CPT == 2) wn8 = *(const short8*)(Wp + ((size_t)(kn>>2)*N + jt)*4);
            else          wn4 = *(const short4v*)(Wp + ((size_t)(kn>>2)*N + jt)*4);
            float w[4][CPT];
            if (CPT == 2){
                #pragma unroll
                for (int u=0;u<4;u++){ w[u][0] = b2f(w8[u]); w[u][1] = b2f(w8[4+u]); }
            } else {
                #pragma unroll
                for (int u=0;u<4;u++) w[u][0] = b2f(w4[u]);
            }
            #pragma unroll
            for (int r=0;r<R;r++){
                const floatx4 av = *(const floatx4*)(A + r*lda + k);
                #pragma unroll
                for (int u=0;u<4;u++)
                    #pragma unroll
                    for (int c=0;c<CPT;c++) acc[r][c] += av[u]*w[u][c];
            }
        }
    }
    #pragma unroll
    for (int r=0;r<R;r++)
        #pragma unroll
        for (int c=0;c<CPT;c++)
            Spart[(kg*R + r)*N + jt + c] = acc[r][c];
    __syncthreads();
    for (int idx = tid; idx < R*N; idx += 1024){
        int r = idx / N, j = idx - r*N;
        float v = 0.f;
        #pragma unroll
        for (int g=0; g<KG; g++) v += Spart[(g*R + r)*N + j];
        v += bias[j];
        if (ACT==1) v = lrelu_f(v);
        if (ACT==2) v = lrelu_f(v*bns*gam[j] + bet[j]);
        C[r*ldc + j] = v;
    }
    __syncthreads();
}

// ================= fused tail: graph-head + cell branch + head MLP, 2 graphs/block ====
__global__ __launch_bounds__(1024)
void tail_kernel(const float* __restrict__ g,            // [2*BB][1024]
                 const float* __restrict__ cell,         // [BB][954]
                 const bf16*  __restrict__ Wtp,          // packed tail weights
                 const float* __restrict__ bg1, const float* __restrict__ bg2,
                 const float* __restrict__ br1, const float* __restrict__ br2,
                 const float* __restrict__ br3,
                 const float* __restrict__ bf1,
                 const float* __restrict__ gbn1, const float* __restrict__ bbn1,
                 const float* __restrict__ bf2,
                 const float* __restrict__ gbn2, const float* __restrict__ bbn2,
                 const float* __restrict__ wf3, const float* __restrict__ bf3,
                 float bns, float* __restrict__ outp)
{
    __shared__ float Sg[4][1024];    // rows: lg*2 + br
    __shared__ float Sgh[4][512];
    __shared__ float Sgout[4][128];
    __shared__ float Scell[2][960];
    __shared__ float Sc1[2][512];
    __shared__ float Sc2[2][256];
    __shared__ float Sc3[2][128];
    __shared__ float Sxc[2][384];
    __shared__ float Sf1[2][512];
    __shared__ float Sf2[2][256];
    __shared__ float Spart[8192];    // split-K partials (max KG*R*N = 4*4*512)
    __shared__ float inv4[4], invc[2], invx[2];

    const int tid = threadIdx.x;
    const int wv  = tid >> 6;
    const int ln  = tid & 63;
    const int b0  = blockIdx.x * 2;

    {
        int idx = tid*4;                 // 0..4092
        int r = idx >> 10, c = idx & 1023;
        int lg = r >> 1, br = r & 1;
        *(floatx4*)&Sg[r][c] = *(const floatx4*)(g + (size_t)(br*BB + b0 + lg)*1024 + c);
    }
    for (int idx = tid; idx < 2*954; idx += 1024){
        int r = (idx >= 954) ? 1 : 0;
        int c = idx - r*954;
        Scell[r][c] = cell[(size_t)(b0 + r)*954 + c];
    }
    if (tid < 12){ int r = tid/6; Scell[r][954 + tid%6] = 0.f; }
    __syncthreads();

    if (wv < 2){
        float s = 0.f;
        for (int c = ln; c < 954; c += 64){ float v = Scell[wv][c]; s += v*v; }
        #pragma unroll
        for (int o=32;o;o>>=1) s += __shfl_xor(s, o, 64);
        if (ln == 0) invc[wv] = 1.0f / fmaxf(sqrtf(s), 1e-12f);
    }
    __syncthreads();
    #pragma unroll
    for (int r=0;r<2;r++)
        for (int c = tid; c < 954; c += 1024) Scell[r][c] *= invc[r];
    __syncthreads();

    dense_split<4,512,1>(Wtp+OG1, bg1, nullptr, nullptr, 1.f, &Sg[0][0],   1024, &Sgh[0][0],  512, 1024, tid, Spart);
    dense_split<4,128,0>(Wtp+OG2, bg2, nullptr, nullptr, 1.f, &Sgh[0][0],  512,  &Sgout[0][0],128, 512,  tid, Spart);
    dense_split<2,512,1>(Wtp+OR1, br1, nullptr, nullptr, 1.f, &Scell[0][0], 960, &Sc1[0][0],  512, 954,  tid, Spart);
    dense_split<2,256,1>(Wtp+OR2, br2, nullptr, nullptr, 1.f, &Sc1[0][0],   512, &Sc2[0][0],  256, 512,  tid, Spart);
    dense_split<2,128,0>(Wtp+OR3, br3, nullptr, nullptr, 1.f, &Sc2[0][0],   256, &Sc3[0][0],  128, 256,  tid, Spart);

    if (wv < 4){
        float a = Sgout[wv][ln], bq = Sgout[wv][ln+64];
        float s = a*a + bq*bq;
        #pragma unroll
        for (int o=32;o;o>>=1) s += __shfl_xor(s, o, 64);
        if (ln == 0) inv4[wv] = 1.0f / fmaxf(sqrtf(s), 1e-12f);
    }
    __syncthreads();

    if (tid < 768){
        int lg = tid / 384, j = tid - lg*384;
        float v;
        if (j < 128)      v = Sgout[lg*2+0][j]     * inv4[lg*2+0];
        else if (j < 256) v = Sgout[lg*2+1][j-128] * inv4[lg*2+1];
        else              v = Sc3[lg][j-256];
        Sxc[lg][j] = v;
    }
    __syncthreads();
    if (wv < 2){
        float s = 0.f;
        #pragma unroll
        for (int i=0;i<6;i++){ float v = Sxc[wv][ln + i*64]; s += v*v; }
        #pragma unroll
        for (int o=32;o;o>>=1) s += __shfl_xor(s, o, 64);
        if (ln == 0) invx[wv] = 1.0f / fmaxf(sqrtf(s), 1e-12f);
    }
    __syncthreads();
    if (tid < 768){
        int lg = tid / 384, j = tid - lg*384;
        Sxc[lg][j] *= invx[lg];
    }
    __syncthreads();

    dense_split<2,512,2>(Wtp+OF1, bf1, gbn1, bbn1, bns, &Sxc[0][0], 384, &Sf1[0][0], 512, 384, tid, Spart);
    dense_split<2,256,2>(Wtp+OF2, bf2, gbn2, bbn2, bns, &Sf1[0][0], 512, &Sf2[0][0], 256, 512, tid, Spart);

    if (wv < 2){
        float s = 0.f;
        #pragma unroll
        for (int i=0;i<4;i++){ int c = ln + i*64; s += Sf2[wv][c]*wf3[c]; }
        #pragma unroll
        for (int o=32;o;o>>=1) s += __shfl_xor(s, o, 64);
        if (ln == 0) outp[b0 + wv] = 1.0f/(1.0f + expf(-(s + bf3[0])));
    }
}

extern "C" void kernel_launch(void* const* d_in, const int* in_sizes, int n_in,
                              void* d_out, int out_size, void* d_ws, size_t ws_size,
                              hipStream_t stream)
{
    const float* x1  = (const float*)d_in[0];
    const int*   ei1 = (const int*)  d_in[1];
    const int*   bt1 = (const int*)  d_in[2];
    const float* x2  = (const float*)d_in[3];
    const int*   ei2 = (const int*)  d_in[4];
    const int*   bt2 = (const int*)  d_in[5];
    const float* cell= (const float*)d_in[6];
    const float* wq1=(const float*)d_in[7];  const float* bq1=(const float*)d_in[8];
    const float* wk1=(const float*)d_in[9];  const float* bk1=(const float*)d_in[10];
    const float* wv1=(const float*)d_in[11]; const float* bv1=(const float*)d_in[12];
    const float* ws1=(const float*)d_in[13]; const float* bs1=(const float*)d_in[14];
    const float* wq2=(const float*)d_in[15]; const float* bq2=(const float*)d_in[16];
    const float* wk2=(const float*)d_in[17]; const float* bk2=(const float*)d_in[18];
    const float* wv2=(const float*)d_in[19]; const float* bv2=(const float*)d_in[20];
    const float* ws2=(const float*)d_in[21]; const float* bs2q=(const float*)d_in[22];
    const float* wg1=(const float*)d_in[23]; const float* bg1=(const float*)d_in[24];
    const float* wg2=(const float*)d_in[25]; const float* bg2=(const float*)d_in[26];
    const float* wr1=(const float*)d_in[27]; const float* br1=(const float*)d_in[28];
    const float* wr2=(const float*)d_in[29]; const float* br2=(const float*)d_in[30];
    const float* wr3=(const float*)d_in[31]; const float* br3=(const float*)d_in[32];
    const float* wf1=(const float*)d_in[33]; const float* bf1=(const float*)d_in[34];
    const float* gbn1=(const float*)d_in[35];const float* bbn1=(const float*)d_in[36];
    const float* wf2=(const float*)d_in[37]; const float* bf2=(const float*)d_in[38];
    const float* gbn2=(const float*)d_in[39];const float* bbn2=(const float*)d_in[40];
    const float* wf3=(const float*)d_in[41]; const float* bf3=(const float*)d_in[42];
    float* outp = (float*)d_out;
    (void)in_sizes; (void)n_in; (void)out_size; (void)ws_size;

    const float BNS = 1.0f / sqrtf(1.0f + 1e-5f);

    // ---- workspace arena ----
    char* basep = (char*)d_ws;
    size_t off = 0;
    auto alloc = [&](size_t nbytes)->char* {
        char* p = basep + off;
        off += (nbytes + 255) & ~(size_t)255;
        return p;
    };
    int* rowptr2  = (int*)  alloc((size_t)2*(NN+1)*4);
    int* cnt2     = (int*)  alloc((size_t)2*NN*4);
    int* srcs2    = (int*)  alloc((size_t)2*EE*4);
    float* g      = (float*)alloc((size_t)2*BB*1024*4);
    int* bps      = (int*)  alloc((size_t)2*BB*4);
    int* bpe      = (int*)  alloc((size_t)2*BB*4);
    float* b1c    = (float*)alloc((size_t)1024*4);
    float* b2c    = (float*)alloc((size_t)4096*4);
    bf16* W1t     = (bf16*) alloc((size_t)1024*96*2);
    bf16* W2t     = (bf16*) alloc((size_t)2*2048*256*2);
    bf16* Wtp     = (bf16*) alloc((size_t)TAILW_TOTAL*2);
    bf16* h1      = (bf16*) alloc((size_t)2*NN*256*2);
    char* R       = alloc((size_t)NN*512*2);              // xa [2NN,96] -> h2h [NN,512]
    bf16* xa      = (bf16*)R;
    bf16* h2h     = (bf16*)R;
    // 64 MB arena: layer1 qkvs1 [2NN,1024] bf16; layer2 qs [NN,1024] bf16 + kv [NN,1024] u8
    char* QK      = alloc((size_t)2*NN*1024*2);
    bf16* qkvs1   = (bf16*)QK;
    bf16* qs2     = (bf16*)QK;                            // [NN,1024] q|s
    unsigned char* kv2 = (unsigned char*)(QK + (size_t)NN*1024*2);  // [NN,1024] k|v fp8

    // ---- prep + CSR (both branches in one pass) ----
    (void)hipMemsetAsync(bps, 0, (size_t)4*BB*4, stream);
    (void)hipMemsetAsync(cnt2, 0, (size_t)2*NN*4, stream);
    prep_all_kernel<<<4500,256,0,stream>>>(wq1,wk1,wv1,ws1, bq1,bk1,bv1,bs1,
                                           wq2,wk2,wv2,ws2, bq2,bk2,bv2,bs2q,
                                           W1t,b1c,W2t,b2c);
    prep_tail_kernel<<<(TAILW_TOTAL+255)/256,256,0,stream>>>(wg1,wg2,wr1,wr2,wr3,wf1,wf2, Wtp);
    hist_kernel<<<2*EE/256,256,0,stream>>>(ei1, ei2, cnt2);
    scan_kernel<<<2,1024,0,stream>>>(cnt2, rowptr2);
    (void)hipMemsetAsync(cnt2, 0, (size_t)2*NN*4, stream);
    scatter_kernel<<<2*EE/256,256,0,stream>>>(ei1, ei2, rowptr2, cnt2, srcs2);
    range_kernel<<<2*NN/256,256,0,stream>>>(bt1, bt2, bps, bpe);

    // ---- layer 1 (both branches stacked): [2NN,96] x [96,1024] -> attn ----
    cvt_x_kernel<<<(2*NN*96)/256,256,0,stream>>>(x1, x2, xa);
    mfma_gemm<<<dim3(1024/128, 2*NN/128),256,0,stream>>>(xa,96, W1t,96, b1c,
                                                         qkvs1,1024, nullptr,0, 1<<30, 96);
    attn_kernel<128><<<2*NN*2/4,256,0,stream>>>(qkvs1,1024, 0,256,512,768, 2, h1,256, rowptr2, srcs2);

    // ---- layer 2: per (branch, head): GEMM (q|s bf16, k|v fp8) + attn + pool ----
    for (int br=0; br<2; br++){
        for (int h=0; h<2; h++){
            mfma_gemm<<<dim3(2048/128, NN/128),256,0,stream>>>(
                h1 + (size_t)br*NN*256, 256, W2t + (size_t)h*2048*256, 256,
                b2c + h*2048, qs2,1024, kv2,1024, 1024, 256);
            attn512_f8<<<NN/4,256,0,stream>>>(qs2, kv2, h2h,
                                              rowptr2 + br*(NN+1), srcs2 + br*EE);
            pool_kernel<<<BB,256,0,stream>>>(h2h, bps + br*BB, bpe + br*BB, g, br*BB, h*512);
        }
    }

    // ---- fused tail: graph-head + cell + head MLP + sigmoid, one dispatch ----
    tail_kernel<<<BB/2,1024,0,stream>>>(g, cell, Wtp,
                                        bg1,bg2, br1,br2,br3,
                                        bf1,gbn1,bbn1, bf2,gbn2,bbn2, wf3,bf3,
                                        BNS, outp);
}

// Round 13
// 560.371 us; speedup vs baseline: 1.4436x; 1.0985x over previous
//
#include <hip/hip_runtime.h>
#include <hip/hip_bf16.h>
#include <hip/hip_fp8.h>
#include <math.h>
#include <stdint.h>

typedef __hip_bfloat16 bf16;

#define NN 16384
#define EE 65536
#define BB 512

typedef __attribute__((ext_vector_type(8))) short short8;
typedef __attribute__((ext_vector_type(4))) short short4v;
typedef __attribute__((ext_vector_type(4))) float floatx4;
typedef __attribute__((ext_vector_type(8))) unsigned char uchar8;

#define GKEY_NEGINF 0x007FFFFFu   // fkey(-inf)

__device__ __forceinline__ float lrelu_f(float x){ return x >= 0.f ? x : 0.01f*x; }

__device__ __forceinline__ float b2f(short s){
    unsigned int u = ((unsigned int)(unsigned short)s) << 16;
    float f; __builtin_memcpy(&f, &u, 4); return f;
}
__device__ __forceinline__ short f2b(float f){
    bf16 b = (bf16)f;
    short s; __builtin_memcpy(&s, &b, 2); return s;
}
__device__ __forceinline__ unsigned char f2fp8(float f){
    __hip_fp8_e4m3 t(f);
    return (unsigned char)t.__x;
}
__device__ __forceinline__ float fp82f(unsigned char c){
    __hip_fp8_e4m3 t; t.__x = (__hip_fp8_storage_t)c;
    return (float)t;
}
// order-preserving float<->u32 for atomicMax pooling
__device__ __forceinline__ unsigned int fkey(float f){
    unsigned int u; __builtin_memcpy(&u, &f, 4);
    return (u & 0x80000000u) ? ~u : (u | 0x80000000u);
}
__device__ __forceinline__ float fdec(unsigned int k){
    if (k == GKEY_NEGINF) return 0.f;   // empty graph -> where(isfinite)=0
    unsigned int u = (k & 0x80000000u) ? (k ^ 0x80000000u) : ~k;
    float f; __builtin_memcpy(&f, &u, 4); return f;
}

// async 16B global->LDS. LDS dest is wave-uniform base; lane i lands at base+16*i.
__device__ __forceinline__ void gl2lds16(const void* g, void* l){
    __builtin_amdgcn_global_load_lds(
        (__attribute__((address_space(1))) unsigned int*)(uintptr_t)g,
        (__attribute__((address_space(3))) unsigned int*)(uintptr_t)l, 16, 0, 0);
}

// ================= MFMA bf16 GEMM: C[m,n] = A[m,:K] @ W[:,n] + bias[n] =================
// Blocks with n0 < nsplit store bf16 to C (ldc); blocks with n0 >= nsplit convert to
// fp8-e4m3 and store to C2 (ldc2) at col n-nsplit. LDS: staging and epilogue aliased.
__global__ __launch_bounds__(256)
void mfma_gemm(const bf16* __restrict__ A, int lda,
               const bf16* __restrict__ Bt, int ldb,
               const float* __restrict__ bias,
               bf16* __restrict__ C, int ldc,
               unsigned char* __restrict__ C2, int ldc2, int nsplit, int K)
{
    __shared__ __align__(16) char smem[20480];
    bf16* As  = (bf16*)smem;            // [128*32]
    bf16* Bs  = (bf16*)(smem + 8192);   // [128*32]
    bf16* epi = (bf16*)smem;            // [4*64*40] epilogue (aliases As/Bs)
    const int tid  = threadIdx.x;
    const int wave = tid >> 6;
    const int lane = tid & 63;
    const int wm = (wave & 1) * 64;
    const int wn = (wave >> 1) * 64;
    const int m0 = blockIdx.y * 128;
    const int n0 = blockIdx.x * 128;
    const bool isf8 = (n0 >= nsplit);

    const int srow = lane >> 2;
    const int scol = (lane & 3) * 8;
    const int arow = lane & 15;
    const int aq   = (lane >> 4) * 8;

    floatx4 acc[4][4];
    #pragma unroll
    for (int i=0;i<4;i++)
        #pragma unroll
        for (int j=0;j<4;j++) acc[i][j] = (floatx4){0.f,0.f,0.f,0.f};

    for (int k0 = 0; k0 < K; k0 += 32) {
        #pragma unroll
        for (int i = 0; i < 2; i++) {
            const int chunk = wave*2 + i;
            const int r = chunk*16 + srow;
            gl2lds16(A  + (size_t)(m0 + r)*lda + k0 + scol, As + chunk*512);
            gl2lds16(Bt + (size_t)(n0 + r)*ldb + k0 + scol, Bs + chunk*512);
        }
        __syncthreads();
        short8 af[4], bf_[4];
        #pragma unroll
        for (int i=0;i<4;i++) af[i]  = *(const short8*)(As + (wm + i*16 + arow)*32 + aq);
        #pragma unroll
        for (int j=0;j<4;j++) bf_[j] = *(const short8*)(Bs + (wn + j*16 + arow)*32 + aq);
        #pragma unroll
        for (int i=0;i<4;i++)
            #pragma unroll
            for (int j=0;j<4;j++)
                acc[i][j] = __builtin_amdgcn_mfma_f32_16x16x32_bf16(af[i], bf_[j], acc[i][j], 0,0,0);
        __syncthreads();
    }
    const int crow = (lane >> 4) * 4;
    const int ccol = lane & 15;
    const int erow = lane >> 2;
    const int ecol = (lane & 3) * 8;
    bf16* ep = epi + wave * (64*40);
    #pragma unroll
    for (int j2 = 0; j2 < 2; j2++){
        if (j2) __syncthreads();
        #pragma unroll
        for (int jj = 0; jj < 2; jj++){
            const int j = j2*2 + jj;
            const float bsv = bias[n0 + wn + j*16 + ccol];
            #pragma unroll
            for (int i = 0; i < 4; i++)
                #pragma unroll
                for (int r = 0; r < 4; r++)
                    ep[(i*16 + crow + r)*40 + jj*16 + ccol] = (bf16)(acc[i][j][r] + bsv);
        }
        __syncthreads();
        #pragma unroll
        for (int q = 0; q < 4; q++){
            const int rr = q*16 + erow;
            short8 vv = *(const short8*)(ep + rr*40 + ecol);
            if (!isf8){
                *(short8*)(C + (size_t)(m0 + wm + rr)*ldc + n0 + wn + j2*32 + ecol) = vv;
            } else {
                uchar8 ob;
                #pragma unroll
                for (int i=0;i<8;i++) ob[i] = f2fp8(b2f(vv[i]));
                *(uchar8*)(C2 + (size_t)(m0 + wm + rr)*ldc2 + (n0 - nsplit) + wn + j2*32 + ecol) = ob;
            }
        }
    }
}

// ================= combined weight/bias prep (1 dispatch) =================
// W2t reordered per head to q|s|k|v (fp8 k/v cols contiguous in the upper half).
__global__ void prep_all_kernel(const float* __restrict__ wq1, const float* __restrict__ wk1,
                                const float* __restrict__ wv1, const float* __restrict__ ws1,
                                const float* __restrict__ bq1, const float* __restrict__ bk1,
                                const float* __restrict__ bv1, const float* __restrict__ bs1,
                                const float* __restrict__ wq2, const float* __restrict__ wk2,
                                const float* __restrict__ wv2, const float* __restrict__ ws2,
                                const float* __restrict__ bq2, const float* __restrict__ bk2,
                                const float* __restrict__ bv2, const float* __restrict__ bs2v,
                                bf16* __restrict__ W1t, float* __restrict__ b1c,
                                bf16* __restrict__ W2t, float* __restrict__ b2c)
{
    int i = blockIdx.x*256 + threadIdx.x;
    if (i < 98304){                      // W1t: [1024][96] (q|k|v|s)
        int n = i / 96, k = i - n*96;
        const float* w = (n<256)?wq1:(n<512)?wk1:(n<768)?wv1:ws1;
        W1t[i] = (k < 78) ? (bf16)w[(size_t)k*256 + (n & 255)] : (bf16)0.f;
        return;
    }
    i -= 98304;
    if (i < 1024){                       // b1c
        const float* b = (i<256)?bq1:(i<512)?bk1:(i<768)?bv1:bs1;
        b1c[i] = b[i & 255];
        return;
    }
    i -= 1024;
    if (i < 1048576){                    // W2t: [2][2048][256], order q|s|k|v
        int k = i & 255;
        int j = (i >> 8) & 2047;
        int h = i >> 19;
        const float* w = (j<512)?wq2:(j<1024)?ws2:(j<1536)?wk2:wv2;
        int col = h*512 + (j & 511);
        W2t[i] = (bf16)w[(size_t)k*1024 + col];
        return;
    }
    i -= 1048576;
    if (i < 4096){                       // b2c (q|s|k|v)
        int j = i & 2047, h = i >> 11;
        const float* b = (j<512)?bq2:(j<1024)?bs2v:(j<1536)?bk2:bv2;
        b2c[i] = b[h*512 + (j & 511)];
    }
}

// ---- tail weights: bf16 packed [K/4][N][4] (u = k%4). Offsets in Wtp arena ----
#define OG1 0         // wg1 1024x512 -> 256x512x4
#define OG2 524288    // wg2 512x128  -> 128x128x4
#define OR1 589824    // wr1 954x512  -> 240x512x4 (pad)
#define OR2 1081344   // wr2 512x256  -> 128x256x4
#define OR3 1212416   // wr3 256x128  -> 64x128x4
#define OF1 1245184   // wf1 384x512  -> 96x512x4
#define OF2 1441792   // wf2 512x256  -> 128x256x4
#define TAILW_TOTAL 1572864

__global__ void prep_tail_kernel(const float* __restrict__ wg1, const float* __restrict__ wg2,
                                 const float* __restrict__ wr1, const float* __restrict__ wr2,
                                 const float* __restrict__ wr3, const float* __restrict__ wf1,
                                 const float* __restrict__ wf2, bf16* __restrict__ Wtp)
{
    int i = blockIdx.x*256 + threadIdx.x;
    if (i >= TAILW_TOTAL) return;
    const float* W; int N, K, base;
    if      (i < OG2){ W = wg1; N = 512; K = 1024; base = OG1; }
    else if (i < OR1){ W = wg2; N = 128; K = 512;  base = OG2; }
    else if (i < OR2){ W = wr1; N = 512; K = 954;  base = OR1; }
    else if (i < OR3){ W = wr2; N = 256; K = 512;  base = OR2; }
    else if (i < OF1){ W = wr3; N = 128; K = 256;  base = OR3; }
    else if (i < OF2){ W = wf1; N = 512; K = 384;  base = OF1; }
    else             { W = wf2; N = 256; K = 512;  base = OF2; }
    int loc = i - base;
    int u = loc & 3;
    int j = (loc >> 2) % N;
    int k4 = (loc >> 2) / N;
    int k = k4*4 + u;
    Wtp[i] = (k < K) ? (bf16)W[(size_t)k*N + j] : (bf16)0.f;
}

__global__ void cvt_x_kernel(const float* __restrict__ x1, const float* __restrict__ x2,
                             bf16* __restrict__ xa){
    int i = blockIdx.x*256 + threadIdx.x;          // 2*NN*96
    int r = i / 96, c = i - r*96;
    const float* x = (r >= NN) ? x2 : x1;
    int lr = r & (NN-1);
    xa[i] = (c < 78) ? (bf16)x[(size_t)lr*78 + c] : (bf16)0.f;
}

// ================= CSR build (both branches, stacked) =================
__global__ void hist_kernel(const int* __restrict__ ei1, const int* __restrict__ ei2,
                            int* __restrict__ cnt){
    int eg = blockIdx.x*256 + threadIdx.x;     // 0..2EE
    int br = eg >> 16, e = eg & (EE-1);
    const int* ei = br ? ei2 : ei1;
    atomicAdd(&cnt[br*NN + ei[EE + e]], 1);
}

// writes rowptr AND a cursor copy (rowcur) so scatter needs no cnt re-zero
__global__ __launch_bounds__(1024)
void scan_kernel(const int* __restrict__ hist, int* __restrict__ rowptr,
                 int* __restrict__ rowcur){
    const int br = blockIdx.x;
    hist   += br*NN;
    rowptr += br*(NN+1);
    rowcur += br*(NN+1);
    __shared__ int sums[1024];
    const int t = threadIdx.x;
    const int base = t*16;
    int loc[16]; int s = 0;
    #pragma unroll
    for (int i=0;i<16;i++){ loc[i]=s; s += hist[base+i]; }
    sums[t] = s; __syncthreads();
    for (int o=1;o<1024;o<<=1){
        int v = (t>=o) ? sums[t-o] : 0;
        __syncthreads();
        sums[t] += v;
        __syncthreads();
    }
    int pref = (t>0) ? sums[t-1] : 0;
    #pragma unroll
    for (int i=0;i<16;i++){
        int v = pref + loc[i];
        rowptr[base+i] = v;
        rowcur[base+i] = v;
    }
    if (t==1023) rowptr[NN] = sums[1023];
}

__global__ void scatter_kernel(const int* __restrict__ ei1, const int* __restrict__ ei2,
                               int* __restrict__ rowcur, int* __restrict__ srcs){
    int eg = blockIdx.x*256 + threadIdx.x;
    int br = eg >> 16, e = eg & (EE-1);
    const int* ei = br ? ei2 : ei1;
    int d = ei[EE + e];
    int pos = atomicAdd(&rowcur[br*(NN+1) + d], 1);
    srcs[br*EE + pos] = ei[e];
}

// init pooled-max keys to fkey(-inf)
__global__ void ginit_kernel(unsigned int* __restrict__ gkey){
    gkey[blockIdx.x*256 + threadIdx.x] = GKEY_NEGINF;
}

// ================= attention layer-1 (bf16 qkvs, stacked branches) =================
template<int D>
__global__ __launch_bounds__(256)
void attn_kernel(const bf16* __restrict__ qkvs, int ld, int qo, int ko, int vo, int so, int H,
                 bf16* __restrict__ hout, int ldo,
                 const int* __restrict__ rowptr, const int* __restrict__ srcs)
{
    constexpr int PER = D / 64;
    typedef __attribute__((ext_vector_type(PER))) short shortP;
    const int lane = threadIdx.x & 63;
    const int gw = blockIdx.x * 4 + (threadIdx.x >> 6);
    const int n = gw / H;                 // global node id (stacked: 0..2NN)
    const int h = gw - n*H;
    int br = n >> 14;
    int brNN = br*NN, nl = n - brNN;
    rowptr += br*(NN+1); srcs += br*EE;
    const float qscale = rsqrtf((float)D) * 1.44269504f;
    const int hd = h*D + lane*PER;

    const shortP qv = *(const shortP*)(qkvs + (size_t)n*ld + qo + hd);
    float qr[PER];
    #pragma unroll
    for (int i=0;i<PER;i++) qr[i] = b2f(qv[i]) * qscale;

    const int e0 = rowptr[nl], e1 = rowptr[nl+1];
    float m = -INFINITY, z = 0.f;
    float acc[PER];
    #pragma unroll
    for (int i=0;i<PER;i++) acc[i] = 0.f;

    for (int base = e0; base < e1; base += 4){
        const int cnt = min(4, e1 - base);
        int sl = srcs[min(base + (lane & 3), e1 - 1)];
        int src[4];
        #pragma unroll
        for (int j=0;j<4;j++) src[j] = __shfl(sl, j, 64);

        shortP kv[4], vv[4];
        #pragma unroll
        for (int j=0;j<4;j++){
            if (j < cnt){
                const bf16* rp = qkvs + (size_t)(brNN + src[j])*ld;
                kv[j] = *(const shortP*)(rp + ko + hd);
                vv[j] = *(const shortP*)(rp + vo + hd);
            }
        }
        float dt[4];
        #pragma unroll
        for (int j=0;j<4;j++){
            float d = 0.f;
            if (j < cnt){
                #pragma unroll
                for (int i=0;i<PER;i++) d += qr[i]*b2f(kv[j][i]);
            }
            dt[j] = d;
        }
        #pragma unroll
        for (int o=32;o;o>>=1){
            #pragma unroll
            for (int j=0;j<4;j++) dt[j] += __shfl_xor(dt[j], o, 64);
        }
        float cm = -INFINITY;
        #pragma unroll
        for (int j=0;j<4;j++) if (j < cnt) cm = fmaxf(cm, dt[j]);
        const float mn = fmaxf(m, cm);
        const float cs = exp2f(m - mn);
        z *= cs;
        #pragma unroll
        for (int i=0;i<PER;i++) acc[i] *= cs;
        #pragma unroll
        for (int j=0;j<4;j++){
            if (j < cnt){
                const float w = exp2f(dt[j] - mn);
                z += w;
                #pragma unroll
                for (int i=0;i<PER;i++) acc[i] += w*b2f(vv[j][i]);
            }
        }
        m = mn;
    }
    const float invz = 1.0f/(z + 1e-16f);
    const shortP sv = *(const shortP*)(qkvs + (size_t)n*ld + so + hd);
    shortP ov;
    #pragma unroll
    for (int i=0;i<PER;i++) ov[i] = f2b(lrelu_f(b2f(sv[i]) + acc[i]*invz));
    *(shortP*)(hout + (size_t)n*ldo + hd) = ov;
}

// ========== attention layer-2 + fused segment-max pool (atomicMax on float keys) ======
// q/s bf16 [NN,1024], k/v fp8 [NN,1024]. Output row is max-pooled into gkey directly
// (block = 4 consecutive nodes, sorted by graph -> segmented LDS reduce, ~1 atomic/col).
__global__ __launch_bounds__(256)
void attn512_f8(const bf16* __restrict__ qs, const unsigned char* __restrict__ kv,
                const int* __restrict__ rowptr, const int* __restrict__ srcs,
                const int* __restrict__ bt,
                unsigned int* __restrict__ gkey, int grow0, int gc0)
{
    __shared__ float Sh[4][512];
    __shared__ int Sgid[4];
    const int lane = threadIdx.x & 63;
    const int wave = threadIdx.x >> 6;
    const int n = blockIdx.x * 4 + wave;
    const float qscale = rsqrtf(512.f) * 1.44269504f;
    const int hd = lane*8;

    const short8 qv = *(const short8*)(qs + (size_t)n*1024 + hd);
    float qr[8];
    #pragma unroll
    for (int i=0;i<8;i++) qr[i] = b2f(qv[i]) * qscale;

    const int e0 = rowptr[n], e1 = rowptr[n+1];
    float m = -INFINITY, z = 0.f;
    float acc[8];
    #pragma unroll
    for (int i=0;i<8;i++) acc[i] = 0.f;

    for (int base = e0; base < e1; base += 4){
        const int cnt = min(4, e1 - base);
        int sl = srcs[min(base + (lane & 3), e1 - 1)];
        int src[4];
        #pragma unroll
        for (int j=0;j<4;j++) src[j] = __shfl(sl, j, 64);

        uchar8 k8[4], v8[4];
        #pragma unroll
        for (int j=0;j<4;j++){
            if (j < cnt){
                const unsigned char* rp = kv + (size_t)src[j]*1024;
                k8[j] = *(const uchar8*)(rp + hd);
                v8[j] = *(const uchar8*)(rp + 512 + hd);
            }
        }
        float dt[4];
        #pragma unroll
        for (int j=0;j<4;j++){
            float d = 0.f;
            if (j < cnt){
                #pragma unroll
                for (int i=0;i<8;i++) d += qr[i]*fp82f(k8[j][i]);
            }
            dt[j] = d;
        }
        #pragma unroll
        for (int o=32;o;o>>=1){
            #pragma unroll
            for (int j=0;j<4;j++) dt[j] += __shfl_xor(dt[j], o, 64);
        }
        float cm = -INFINITY;
        #pragma unroll
        for (int j=0;j<4;j++) if (j < cnt) cm = fmaxf(cm, dt[j]);
        const float mn = fmaxf(m, cm);
        const float cs = exp2f(m - mn);
        z *= cs;
        #pragma unroll
        for (int i=0;i<8;i++) acc[i] *= cs;
        #pragma unroll
        for (int j=0;j<4;j++){
            if (j < cnt){
                const float w = exp2f(dt[j] - mn);
                z += w;
                #pragma unroll
                for (int i=0;i<8;i++) acc[i] += w*fp82f(v8[j][i]);
            }
        }
        m = mn;
    }
    const float invz = 1.0f/(z + 1e-16f);
    const short8 sv = *(const short8*)(qs + (size_t)n*1024 + 512 + hd);
    #pragma unroll
    for (int i=0;i<8;i++) Sh[wave][hd + i] = lrelu_f(b2f(sv[i]) + acc[i]*invz);
    if (lane == 0) Sgid[wave] = bt[n];
    __syncthreads();

    // segmented max over the block's 4 rows, one atomic per (graph,col) run
    #pragma unroll
    for (int cc=0; cc<2; cc++){
        const int col = threadIdx.x*2 + cc;
        float mx = Sh[0][col];
        int gid = Sgid[0];
        #pragma unroll
        for (int r=1; r<4; r++){
            if (Sgid[r] == gid) mx = fmaxf(mx, Sh[r][col]);
            else {
                atomicMax(&gkey[(size_t)(grow0 + gid)*1024 + gc0 + col], fkey(mx));
                gid = Sgid[r]; mx = Sh[r][col];
            }
        }
        atomicMax(&gkey[(size_t)(grow0 + gid)*1024 + gc0 + col], fkey(mx));
    }
}

// ================= fused MLP tail (1024 threads): split-K dense step, bf16 weights ====
// CT=128 col-threads x KG=8 k-groups; CPT=N/128 cols/thread. Prefetched 16B weight
// loads; A from LDS (broadcast). Partials in Spart; combine adds bias+activation.
template<int R, int N, int ACT>
__device__ __forceinline__ void dense_split(
    const bf16* __restrict__ Wp, const float* __restrict__ bias,
    const float* __restrict__ gam, const float* __restrict__ bet, float bns,
    const float* A, int lda, float* C, int ldc, int K, int tid, float* Spart)
{
    constexpr int CPT = N / 128;
    constexpr int KG  = 8;
    const int ct = tid & 127;
    const int kg = tid >> 7;
    const int jt = ct * CPT;
    const int Kc = ((K + KG - 1) / KG + 3) & ~3;
    const int kb = kg * Kc;
    const int Kpad = (K + 3) & ~3;
    const int ke = min(Kpad, kb + Kc);

    float acc[R][CPT];
    #pragma unroll
    for (int r=0;r<R;r++)
        #pragma unroll
        for (int c=0;c<CPT;c++) acc[r][c] = 0.f;

    if (kb < ke){
        short8 p0, p1; short4v p4;
        {
            const bf16* wp = Wp + ((size_t)(kb>>2)*N + jt)*4;
            if (CPT==4){ p0 = ((const short8*)wp)[0]; p1 = ((const short8*)wp)[1]; }
            else if (CPT==2){ p0 = *(const short8*)wp; }
            else { p4 = *(const short4v*)wp; }
        }
        for (int k = kb; k < ke; k += 4){
            short8 c0 = p0, c1 = p1; short4v c4 = p4;
            const int kn = (k + 4 < ke) ? k + 4 : kb;
            const bf16* wn = Wp + ((size_t)(kn>>2)*N + jt)*4;
            if (CPT==4){ p0 = ((const short8*)wn)[0]; p1 = ((const short8*)wn)[1]; }
            else if (CPT==2){ p0 = *(const short8*)wn; }
            else { p4 = *(const short4v*)wn; }
            float w[4][CPT];
            if (CPT==4){
                #pragma unroll
                for (int u=0;u<4;u++){
                    w[u][0] = b2f(c0[u]); w[u][1] = b2f(c0[4+u]);
                    w[u][2] = b2f(c1[u]); w[u][3] = b2f(c1[4+u]);
                }
            } else if (CPT==2){
                #pragma unroll
                for (int u=0;u<4;u++){ w[u][0] = b2f(c0[u]); w[u][1] = b2f(c0[4+u]); }
            } else {
                #pragma unroll
                for (int u=0;u<4;u++) w[u][0] = b2f(c4[u]);
            }
            #pragma unroll
            for (int r=0;r<R;r++){
                const floatx4 av = *(const floatx4*)(A + r*lda + k);
                #pragma unroll
                for (int u=0;u<4;u++)
                    #pragma unroll
                    for (int c=0;c<CPT;c++) acc[r][c] += av[u]*w[u][c];
            }
        }
    }
    #pragma unroll
    for (int r=0;r<R;r++)
        #pragma unroll
        for (int c=0;c<CPT;c++)
            Spart[(kg*R + r)*N + jt + c] = acc[r][c];
    __syncthreads();
    for (int idx = tid; idx < R*N; idx += 1024){
        int r = idx / N, j = idx - r*N;
        float v = 0.f;
        #pragma unroll
        for (int g=0; g<KG; g++) v += Spart[(g*R + r)*N + j];
        v += bias[j];
        if (ACT==1) v = lrelu_f(v);
        if (ACT==2) v = lrelu_f(v*bns*gam[j] + bet[j]);
        C[r*ldc + j] = v;
    }
    __syncthreads();
}

// ================= fused tail: graph-head + cell branch + head MLP, 2 graphs/block ====
__global__ __launch_bounds__(1024)
void tail_kernel(const unsigned int* __restrict__ gkey,  // [2*BB][1024] encoded maxes
                 const float* __restrict__ cell,         // [BB][954]
                 const bf16*  __restrict__ Wtp,          // packed tail weights
                 const float* __restrict__ bg1, const float* __restrict__ bg2,
                 const float* __restrict__ br1, const float* __restrict__ br2,
                 const float* __restrict__ br3,
                 const float* __restrict__ bf1,
                 const float* __restrict__ gbn1, const float* __restrict__ bbn1,
                 const float* __restrict__ bf2,
                 const float* __restrict__ gbn2, const float* __restrict__ bbn2,
                 const float* __restrict__ wf3, const float* __restrict__ bf3,
                 float bns, float* __restrict__ outp)
{
    __shared__ float Sg[4][1024];    // rows: lg*2 + br
    __shared__ float Sgh[4][512];
    __shared__ float Sgout[4][128];
    __shared__ float Scell[2][960];
    __shared__ float Sc1[2][512];
    __shared__ float Sc2[2][256];
    __shared__ float Sc3[2][128];
    __shared__ float Sxc[2][384];
    __shared__ float Sf1[2][512];
    __shared__ float Sf2[2][256];
    __shared__ float Spart[16384];   // split-K partials (KG=8, max R*N = 4*512)
    __shared__ float inv4[4], invc[2], invx[2];

    const int tid = threadIdx.x;
    const int wv  = tid >> 6;
    const int ln  = tid & 63;
    const int b0  = blockIdx.x * 2;

    {
        int idx = tid*4;                 // 0..4092
        int r = idx >> 10, c = idx & 1023;
        int lg = r >> 1, br = r & 1;
        const unsigned int* gp = gkey + (size_t)(br*BB + b0 + lg)*1024 + c;
        #pragma unroll
        for (int i=0;i<4;i++) Sg[r][c+i] = fdec(gp[i]);
    }
    for (int idx = tid; idx < 2*954; idx += 1024){
        int r = (idx >= 954) ? 1 : 0;
        int c = idx - r*954;
        Scell[r][c] = cell[(size_t)(b0 + r)*954 + c];
    }
    if (tid < 12){ int r = tid/6; Scell[r][954 + tid%6] = 0.f; }
    __syncthreads();

    if (wv < 2){
        float s = 0.f;
        for (int c = ln; c < 954; c += 64){ float v = Scell[wv][c]; s += v*v; }
        #pragma unroll
        for (int o=32;o;o>>=1) s += __shfl_xor(s, o, 64);
        if (ln == 0) invc[wv] = 1.0f / fmaxf(sqrtf(s), 1e-12f);
    }
    __syncthreads();
    #pragma unroll
    for (int r=0;r<2;r++)
        for (int c = tid; c < 954; c += 1024) Scell[r][c] *= invc[r];
    __syncthreads();

    dense_split<4,512,1>(Wtp+OG1, bg1, nullptr, nullptr, 1.f, &Sg[0][0],   1024, &Sgh[0][0],  512, 1024, tid, Spart);
    dense_split<4,128,0>(Wtp+OG2, bg2, nullptr, nullptr, 1.f, &Sgh[0][0],  512,  &Sgout[0][0],128, 512,  tid, Spart);
    dense_split<2,512,1>(Wtp+OR1, br1, nullptr, nullptr, 1.f, &Scell[0][0], 960, &Sc1[0][0],  512, 954,  tid, Spart);
    dense_split<2,256,1>(Wtp+OR2, br2, nullptr, nullptr, 1.f, &Sc1[0][0],   512, &Sc2[0][0],  256, 512,  tid, Spart);
    dense_split<2,128,0>(Wtp+OR3, br3, nullptr, nullptr, 1.f, &Sc2[0][0],   256, &Sc3[0][0],  128, 256,  tid, Spart);

    if (wv < 4){
        float a = Sgout[wv][ln], bq = Sgout[wv][ln+64];
        float s = a*a + bq*bq;
        #pragma unroll
        for (int o=32;o;o>>=1) s += __shfl_xor(s, o, 64);
        if (ln == 0) inv4[wv] = 1.0f / fmaxf(sqrtf(s), 1e-12f);
    }
    __syncthreads();

    if (tid < 768){
        int lg = tid / 384, j = tid - lg*384;
        float v;
        if (j < 128)      v = Sgout[lg*2+0][j]     * inv4[lg*2+0];
        else if (j < 256) v = Sgout[lg*2+1][j-128] * inv4[lg*2+1];
        else              v = Sc3[lg][j-256];
        Sxc[lg][j] = v;
    }
    __syncthreads();
    if (wv < 2){
        float s = 0.f;
        #pragma unroll
        for (int i=0;i<6;i++){ float v = Sxc[wv][ln + i*64]; s += v*v; }
        #pragma unroll
        for (int o=32;o;o>>=1) s += __shfl_xor(s, o, 64);
        if (ln == 0) invx[wv] = 1.0f / fmaxf(sqrtf(s), 1e-12f);
    }
    __syncthreads();
    if (tid < 768){
        int lg = tid / 384, j = tid - lg*384;
        Sxc[lg][j] *= invx[lg];
    }
    __syncthreads();

    dense_split<2,512,2>(Wtp+OF1, bf1, gbn1, bbn1, bns, &Sxc[0][0], 384, &Sf1[0][0], 512, 384, tid, Spart);
    dense_split<2,256,2>(Wtp+OF2, bf2, gbn2, bbn2, bns, &Sf1[0][0], 512, &Sf2[0][0], 256, 512, tid, Spart);

    if (wv < 2){
        float s = 0.f;
        #pragma unroll
        for (int i=0;i<4;i++){ int c = ln + i*64; s += Sf2[wv][c]*wf3[c]; }
        #pragma unroll
        for (int o=32;o;o>>=1) s += __shfl_xor(s, o, 64);
        if (ln == 0) outp[b0 + wv] = 1.0f/(1.0f + expf(-(s + bf3[0])));
    }
}

extern "C" void kernel_launch(void* const* d_in, const int* in_sizes, int n_in,
                              void* d_out, int out_size, void* d_ws, size_t ws_size,
                              hipStream_t stream)
{
    const float* x1  = (const float*)d_in[0];
    const int*   ei1 = (const int*)  d_in[1];
    const int*   bt1 = (const int*)  d_in[2];
    const float* x2  = (const float*)d_in[3];
    const int*   ei2 = (const int*)  d_in[4];
    const int*   bt2 = (const int*)  d_in[5];
    const float* cell= (const float*)d_in[6];
    const float* wq1=(const float*)d_in[7];  const float* bq1=(const float*)d_in[8];
    const float* wk1=(const float*)d_in[9];  const float* bk1=(const float*)d_in[10];
    const float* wv1=(const float*)d_in[11]; const float* bv1=(const float*)d_in[12];
    const float* ws1=(const float*)d_in[13]; const float* bs1=(const float*)d_in[14];
    const float* wq2=(const float*)d_in[15]; const float* bq2=(const float*)d_in[16];
    const float* wk2=(const float*)d_in[17]; const float* bk2=(const float*)d_in[18];
    const float* wv2=(const float*)d_in[19]; const float* bv2=(const float*)d_in[20];
    const float* ws2=(const float*)d_in[21]; const float* bs2q=(const float*)d_in[22];
    const float* wg1=(const float*)d_in[23]; const float* bg1=(const float*)d_in[24];
    const float* wg2=(const float*)d_in[25]; const float* bg2=(const float*)d_in[26];
    const float* wr1=(const float*)d_in[27]; const float* br1=(const float*)d_in[28];
    const float* wr2=(const float*)d_in[29]; const float* br2=(const float*)d_in[30];
    const float* wr3=(const float*)d_in[31]; const float* br3=(const float*)d_in[32];
    const float* wf1=(const float*)d_in[33]; const float* bf1=(const float*)d_in[34];
    const float* gbn1=(const float*)d_in[35];const float* bbn1=(const float*)d_in[36];
    const float* wf2=(const float*)d_in[37]; const float* bf2=(const float*)d_in[38];
    const float* gbn2=(const float*)d_in[39];const float* bbn2=(const float*)d_in[40];
    const float* wf3=(const float*)d_in[41]; const float* bf3=(const float*)d_in[42];
    float* outp = (float*)d_out;
    (void)in_sizes; (void)n_in; (void)out_size; (void)ws_size;

    const float BNS = 1.0f / sqrtf(1.0f + 1e-5f);

    // ---- workspace arena (~96 MB peak) ----
    char* basep = (char*)d_ws;
    size_t off = 0;
    auto alloc = [&](size_t nbytes)->char* {
        char* p = basep + off;
        off += (nbytes + 255) & ~(size_t)255;
        return p;
    };
    int* rowptr2  = (int*)  alloc((size_t)2*(NN+1)*4);
    int* rowcur2  = (int*)  alloc((size_t)2*(NN+1)*4);
    int* cnt2     = (int*)  alloc((size_t)2*NN*4);
    int* srcs2    = (int*)  alloc((size_t)2*EE*4);
    unsigned int* gkey = (unsigned int*)alloc((size_t)2*BB*1024*4);  // pooled-max keys
    float* b1c    = (float*)alloc((size_t)1024*4);
    float* b2c    = (float*)alloc((size_t)4096*4);
    bf16* W1t     = (bf16*) alloc((size_t)1024*96*2);
    bf16* W2t     = (bf16*) alloc((size_t)2*2048*256*2);
    bf16* Wtp     = (bf16*) alloc((size_t)TAILW_TOTAL*2);
    bf16* h1      = (bf16*) alloc((size_t)2*NN*256*2);
    bf16* xa      = (bf16*) alloc((size_t)2*NN*96*2);
    // 64 MB arena: layer1 qkvs1 [2NN,1024] bf16; layer2 qs [NN,1024] bf16 + kv [NN,1024] u8
    char* QK      = alloc((size_t)2*NN*1024*2);
    bf16* qkvs1   = (bf16*)QK;
    bf16* qs2     = (bf16*)QK;
    unsigned char* kv2 = (unsigned char*)(QK + (size_t)NN*1024*2);

    // ---- prep + CSR (both branches in one pass) ----
    (void)hipMemsetAsync(cnt2, 0, (size_t)2*NN*4, stream);
    prep_all_kernel<<<4500,256,0,stream>>>(wq1,wk1,wv1,ws1, bq1,bk1,bv1,bs1,
                                           wq2,wk2,wv2,ws2, bq2,bk2,bv2,bs2q,
                                           W1t,b1c,W2t,b2c);
    prep_tail_kernel<<<(TAILW_TOTAL+255)/256,256,0,stream>>>(wg1,wg2,wr1,wr2,wr3,wf1,wf2, Wtp);
    hist_kernel<<<2*EE/256,256,0,stream>>>(ei1, ei2, cnt2);
    scan_kernel<<<2,1024,0,stream>>>(cnt2, rowptr2, rowcur2);
    scatter_kernel<<<2*EE/256,256,0,stream>>>(ei1, ei2, rowcur2, srcs2);
    ginit_kernel<<<(2*BB*1024)/256,256,0,stream>>>(gkey);

    // ---- layer 1 (both branches stacked): [2NN,96] x [96,1024] -> attn ----
    cvt_x_kernel<<<(2*NN*96)/256,256,0,stream>>>(x1, x2, xa);
    mfma_gemm<<<dim3(1024/128, 2*NN/128),256,0,stream>>>(xa,96, W1t,96, b1c,
                                                         qkvs1,1024, nullptr,0, 1<<30, 96);
    attn_kernel<128><<<2*NN*2/4,256,0,stream>>>(qkvs1,1024, 0,256,512,768, 2, h1,256, rowptr2, srcs2);

    // ---- layer 2: per (branch, head): GEMM (q|s bf16, k|v fp8) + attn+pool fused ----
    for (int br=0; br<2; br++){
        const int* bt = br ? bt2 : bt1;
        for (int h=0; h<2; h++){
            mfma_gemm<<<dim3(2048/128, NN/128),256,0,stream>>>(
                h1 + (size_t)br*NN*256, 256, W2t + (size_t)h*2048*256, 256,
                b2c + h*2048, qs2,1024, kv2,1024, 1024, 256);
            attn512_f8<<<NN/4,256,0,stream>>>(qs2, kv2,
                                              rowptr2 + br*(NN+1), srcs2 + br*EE, bt,
                                              gkey, br*BB, h*512);
        }
    }

    // ---- fused tail: graph-head + cell + head MLP + sigmoid, one dispatch ----
    tail_kernel<<<BB/2,1024,0,stream>>>(gkey, cell, Wtp,
                                        bg1,bg2, br1,br2,br3,
                                        bf1,gbn1,bbn1, bf2,gbn2,bbn2, wf3,bf3,
                                        BNS, outp);
}

// Round 14
// 555.383 us; speedup vs baseline: 1.4565x; 1.0090x over previous
//
#include <hip/hip_runtime.h>
#include <hip/hip_bf16.h>
#include <hip/hip_fp8.h>
#include <math.h>
#include <stdint.h>

typedef __hip_bfloat16 bf16;

#define NN 16384
#define EE 65536
#define BB 512

typedef __attribute__((ext_vector_type(8))) short short8;
typedef __attribute__((ext_vector_type(4))) short short4v;
typedef __attribute__((ext_vector_type(2))) short short2v;
typedef __attribute__((ext_vector_type(4))) float floatx4;
typedef __attribute__((ext_vector_type(8))) unsigned char uchar8;
typedef __attribute__((ext_vector_type(2))) unsigned char uchar2v;

#define GKEY_NEGINF 0x007FFFFFu   // fkey(-inf)

__device__ __forceinline__ float lrelu_f(float x){ return x >= 0.f ? x : 0.01f*x; }

__device__ __forceinline__ float b2f(short s){
    unsigned int u = ((unsigned int)(unsigned short)s) << 16;
    float f; __builtin_memcpy(&f, &u, 4); return f;
}
__device__ __forceinline__ short f2b(float f){
    bf16 b = (bf16)f;
    short s; __builtin_memcpy(&s, &b, 2); return s;
}
__device__ __forceinline__ unsigned char f2fp8(float f){
    __hip_fp8_e4m3 t(f);
    return (unsigned char)t.__x;
}
__device__ __forceinline__ float fp82f(unsigned char c){
    __hip_fp8_e4m3 t; t.__x = (__hip_fp8_storage_t)c;
    return (float)t;
}
// order-preserving float<->u32 for atomicMax pooling
__device__ __forceinline__ unsigned int fkey(float f){
    unsigned int u; __builtin_memcpy(&u, &f, 4);
    return (u & 0x80000000u) ? ~u : (u | 0x80000000u);
}
__device__ __forceinline__ float fdec(unsigned int k){
    if (k == GKEY_NEGINF) return 0.f;   // empty graph -> where(isfinite)=0
    unsigned int u = (k & 0x80000000u) ? (k ^ 0x80000000u) : ~k;
    float f; __builtin_memcpy(&f, &u, 4); return f;
}

// async 16B global->LDS. LDS dest is wave-uniform base; lane i lands at base+16*i.
__device__ __forceinline__ void gl2lds16(const void* g, void* l){
    __builtin_amdgcn_global_load_lds(
        (__attribute__((address_space(1))) unsigned int*)(uintptr_t)g,
        (__attribute__((address_space(3))) unsigned int*)(uintptr_t)l, 16, 0, 0);
}

// ================= MFMA bf16 GEMM: C[m,n] = A[m,:K] @ W[:,n] + bias[n] =================
// Blocks with n0 < nsplit store bf16 to C (ldc); blocks with n0 >= nsplit convert to
// fp8-e4m3 and store to C2 (ldc2) at col n-nsplit. LDS: staging and epilogue aliased.
__global__ __launch_bounds__(256)
void mfma_gemm(const bf16* __restrict__ A, int lda,
               const bf16* __restrict__ Bt, int ldb,
               const float* __restrict__ bias,
               bf16* __restrict__ C, int ldc,
               unsigned char* __restrict__ C2, int ldc2, int nsplit, int K)
{
    __shared__ __align__(16) char smem[20480];
    bf16* As  = (bf16*)smem;            // [128*32]
    bf16* Bs  = (bf16*)(smem + 8192);   // [128*32]
    bf16* epi = (bf16*)smem;            // [4*64*40] epilogue (aliases As/Bs)
    const int tid  = threadIdx.x;
    const int wave = tid >> 6;
    const int lane = tid & 63;
    const int wm = (wave & 1) * 64;
    const int wn = (wave >> 1) * 64;
    const int m0 = blockIdx.y * 128;
    const int n0 = blockIdx.x * 128;
    const bool isf8 = (n0 >= nsplit);

    const int srow = lane >> 2;
    const int scol = (lane & 3) * 8;
    const int arow = lane & 15;
    const int aq   = (lane >> 4) * 8;

    floatx4 acc[4][4];
    #pragma unroll
    for (int i=0;i<4;i++)
        #pragma unroll
        for (int j=0;j<4;j++) acc[i][j] = (floatx4){0.f,0.f,0.f,0.f};

    for (int k0 = 0; k0 < K; k0 += 32) {
        #pragma unroll
        for (int i = 0; i < 2; i++) {
            const int chunk = wave*2 + i;
            const int r = chunk*16 + srow;
            gl2lds16(A  + (size_t)(m0 + r)*lda + k0 + scol, As + chunk*512);
            gl2lds16(Bt + (size_t)(n0 + r)*ldb + k0 + scol, Bs + chunk*512);
        }
        __syncthreads();
        short8 af[4], bf_[4];
        #pragma unroll
        for (int i=0;i<4;i++) af[i]  = *(const short8*)(As + (wm + i*16 + arow)*32 + aq);
        #pragma unroll
        for (int j=0;j<4;j++) bf_[j] = *(const short8*)(Bs + (wn + j*16 + arow)*32 + aq);
        #pragma unroll
        for (int i=0;i<4;i++)
            #pragma unroll
            for (int j=0;j<4;j++)
                acc[i][j] = __builtin_amdgcn_mfma_f32_16x16x32_bf16(af[i], bf_[j], acc[i][j], 0,0,0);
        __syncthreads();
    }
    const int crow = (lane >> 4) * 4;
    const int ccol = lane & 15;
    const int erow = lane >> 2;
    const int ecol = (lane & 3) * 8;
    bf16* ep = epi + wave * (64*40);
    #pragma unroll
    for (int j2 = 0; j2 < 2; j2++){
        if (j2) __syncthreads();
        #pragma unroll
        for (int jj = 0; jj < 2; jj++){
            const int j = j2*2 + jj;
            const float bsv = bias[n0 + wn + j*16 + ccol];
            #pragma unroll
            for (int i = 0; i < 4; i++)
                #pragma unroll
                for (int r = 0; r < 4; r++)
                    ep[(i*16 + crow + r)*40 + jj*16 + ccol] = (bf16)(acc[i][j][r] + bsv);
        }
        __syncthreads();
        #pragma unroll
        for (int q = 0; q < 4; q++){
            const int rr = q*16 + erow;
            short8 vv = *(const short8*)(ep + rr*40 + ecol);
            if (!isf8){
                *(short8*)(C + (size_t)(m0 + wm + rr)*ldc + n0 + wn + j2*32 + ecol) = vv;
            } else {
                uchar8 ob;
                #pragma unroll
                for (int i=0;i<8;i++) ob[i] = f2fp8(b2f(vv[i]));
                *(uchar8*)(C2 + (size_t)(m0 + wm + rr)*ldc2 + (n0 - nsplit) + wn + j2*32 + ecol) = ob;
            }
        }
    }
}

// ---- tail weights: bf16 packed [K/4][N][4] (u = k%4). Offsets in Wtp arena ----
#define OG1 0         // wg1 1024x512 -> 256x512x4
#define OG2 524288    // wg2 512x128  -> 128x128x4
#define OR1 589824    // wr1 954x512  -> 240x512x4 (pad)
#define OR2 1081344   // wr2 512x256  -> 128x256x4
#define OR3 1212416   // wr3 256x128  -> 64x128x4
#define OF1 1245184   // wf1 384x512  -> 96x512x4
#define OF2 1441792   // wf2 512x256  -> 128x256x4
#define TAILW_TOTAL 1572864

// ============ merged prep: W1t,b1c,W2t,b2c + Wtp + xa + gkey in ONE dispatch ==========
// Weight order both layers: s | q | k | v  (s stays bf16 in epilogue; q/k/v -> fp8)
#define P_W1T 98304
#define P_B1C (P_W1T + 1024)
#define P_W2T (P_B1C + 1048576)
#define P_B2C (P_W2T + 4096)
#define P_WTP (P_B2C + TAILW_TOTAL)
#define P_XA  (P_WTP + 2*NN*96)
#define P_GK  (P_XA + 2*BB*1024)
__global__ void prep_mega_kernel(
    const float* __restrict__ wq1, const float* __restrict__ wk1,
    const float* __restrict__ wv1, const float* __restrict__ ws1,
    const float* __restrict__ bq1, const float* __restrict__ bk1,
    const float* __restrict__ bv1, const float* __restrict__ bs1,
    const float* __restrict__ wq2, const float* __restrict__ wk2,
    const float* __restrict__ wv2, const float* __restrict__ ws2,
    const float* __restrict__ bq2, const float* __restrict__ bk2,
    const float* __restrict__ bv2, const float* __restrict__ bs2v,
    const float* __restrict__ wg1, const float* __restrict__ wg2,
    const float* __restrict__ wr1, const float* __restrict__ wr2,
    const float* __restrict__ wr3, const float* __restrict__ wf1,
    const float* __restrict__ wf2,
    const float* __restrict__ x1,  const float* __restrict__ x2,
    bf16* __restrict__ W1t, float* __restrict__ b1c,
    bf16* __restrict__ W2t, float* __restrict__ b2c,
    bf16* __restrict__ Wtp, bf16* __restrict__ xa,
    unsigned int* __restrict__ gkey)
{
    int i = blockIdx.x*256 + threadIdx.x;
    if (i < P_W1T){                      // W1t: [1024][96], n order s|q|k|v (256 each)
        int n = i / 96, k = i - n*96;
        int seg = n >> 8;
        const float* w = (seg==0)?ws1:(seg==1)?wq1:(seg==2)?wk1:wv1;
        W1t[i] = (k < 78) ? (bf16)w[(size_t)k*256 + (n & 255)] : (bf16)0.f;
        return;
    }
    if (i < P_B1C){                      // b1c (s|q|k|v)
        int n = i - P_W1T;
        int seg = n >> 8;
        const float* b = (seg==0)?bs1:(seg==1)?bq1:(seg==2)?bk1:bv1;
        b1c[n] = b[n & 255];
        return;
    }
    if (i < P_W2T){                      // W2t: [2][2048][256], j order s|q|k|v (512 each)
        int loc = i - P_B1C;
        int k = loc & 255;
        int j = (loc >> 8) & 2047;
        int h = loc >> 19;
        const float* w = (j<512)?ws2:(j<1024)?wq2:(j<1536)?wk2:wv2;
        W2t[loc] = (bf16)w[(size_t)k*1024 + h*512 + (j & 511)];
        return;
    }
    if (i < P_B2C){                      // b2c (s|q|k|v)
        int loc = i - P_W2T;
        int j = loc & 2047, h = loc >> 11;
        const float* b = (j<512)?bs2v:(j<1024)?bq2:(j<1536)?bk2:bv2;
        b2c[loc] = b[h*512 + (j & 511)];
        return;
    }
    if (i < P_WTP){                      // packed tail weights
        int t = i - P_B2C;
        const float* W; int N, K, base;
        if      (t < OG2){ W = wg1; N = 512; K = 1024; base = OG1; }
        else if (t < OR1){ W = wg2; N = 128; K = 512;  base = OG2; }
        else if (t < OR2){ W = wr1; N = 512; K = 954;  base = OR1; }
        else if (t < OR3){ W = wr2; N = 256; K = 512;  base = OR2; }
        else if (t < OF1){ W = wr3; N = 128; K = 256;  base = OR3; }
        else if (t < OF2){ W = wf1; N = 512; K = 384;  base = OF1; }
        else             { W = wf2; N = 256; K = 512;  base = OF2; }
        int loc = t - base;
        int u = loc & 3;
        int j = (loc >> 2) % N;
        int k4 = (loc >> 2) / N;
        int k = k4*4 + u;
        Wtp[t] = (k < K) ? (bf16)W[(size_t)k*N + j] : (bf16)0.f;
        return;
    }
    if (i < P_XA){                       // xa: [2NN][96] bf16 (zero-padded K)
        int t = i - P_WTP;
        int r = t / 96, c = t - r*96;
        const float* x = (r >= NN) ? x2 : x1;
        int lr = r & (NN-1);
        xa[t] = (c < 78) ? (bf16)x[(size_t)lr*78 + c] : (bf16)0.f;
        return;
    }
    if (i < P_GK){                       // gkey init
        gkey[i - P_XA] = GKEY_NEGINF;
    }
}

// ================= CSR build (both branches, stacked) =================
__global__ void hist_kernel(const int* __restrict__ ei1, const int* __restrict__ ei2,
                            int* __restrict__ cnt){
    int eg = blockIdx.x*256 + threadIdx.x;     // 0..2EE
    int br = eg >> 16, e = eg & (EE-1);
    const int* ei = br ? ei2 : ei1;
    atomicAdd(&cnt[br*NN + ei[EE + e]], 1);
}

// writes rowptr AND a cursor copy (rowcur) so scatter needs no cnt re-zero
__global__ __launch_bounds__(1024)
void scan_kernel(const int* __restrict__ hist, int* __restrict__ rowptr,
                 int* __restrict__ rowcur){
    const int br = blockIdx.x;
    hist   += br*NN;
    rowptr += br*(NN+1);
    rowcur += br*(NN+1);
    __shared__ int sums[1024];
    const int t = threadIdx.x;
    const int base = t*16;
    int loc[16]; int s = 0;
    #pragma unroll
    for (int i=0;i<16;i++){ loc[i]=s; s += hist[base+i]; }
    sums[t] = s; __syncthreads();
    for (int o=1;o<1024;o<<=1){
        int v = (t>=o) ? sums[t-o] : 0;
        __syncthreads();
        sums[t] += v;
        __syncthreads();
    }
    int pref = (t>0) ? sums[t-1] : 0;
    #pragma unroll
    for (int i=0;i<16;i++){
        int v = pref + loc[i];
        rowptr[base+i] = v;
        rowcur[base+i] = v;
    }
    if (t==1023) rowptr[NN] = sums[1023];
}

__global__ void scatter_kernel(const int* __restrict__ ei1, const int* __restrict__ ei2,
                               int* __restrict__ rowcur, int* __restrict__ srcs){
    int eg = blockIdx.x*256 + threadIdx.x;
    int br = eg >> 16, e = eg & (EE-1);
    const int* ei = br ? ei2 : ei1;
    int d = ei[EE + e];
    int pos = atomicAdd(&rowcur[br*(NN+1) + d], 1);
    srcs[br*EE + pos] = ei[e];
}

// ======= attention layer-1: s bf16 [2NN,256], q/k/v fp8 [2NN,768], H=2, D=128 =========
__global__ __launch_bounds__(256)
void attn128_f8(const bf16* __restrict__ s1, const unsigned char* __restrict__ f81,
                bf16* __restrict__ hout,
                const int* __restrict__ rowptr, const int* __restrict__ srcs)
{
    const int lane = threadIdx.x & 63;
    const int gw = blockIdx.x * 4 + (threadIdx.x >> 6);
    const int n = gw >> 1;               // global node 0..2NN
    const int h = gw & 1;
    int br = n >> 14;
    int brNN = br*NN, nl = n - brNN;
    rowptr += br*(NN+1); srcs += br*EE;
    const float qscale = rsqrtf(128.f) * 1.44269504f;
    const int hd = h*128 + lane*2;

    const uchar2v q8 = *(const uchar2v*)(f81 + (size_t)n*768 + hd);
    float qr[2] = { fp82f(q8[0])*qscale, fp82f(q8[1])*qscale };

    const int e0 = rowptr[nl], e1 = rowptr[nl+1];
    float m = -INFINITY, z = 0.f;
    float acc[2] = {0.f, 0.f};

    for (int base = e0; base < e1; base += 4){
        const int cnt = min(4, e1 - base);
        int sl = srcs[min(base + (lane & 3), e1 - 1)];
        int src[4];
        #pragma unroll
        for (int j=0;j<4;j++) src[j] = __shfl(sl, j, 64);

        uchar2v kv[4], vv[4];
        #pragma unroll
        for (int j=0;j<4;j++){
            if (j < cnt){
                const unsigned char* rp = f81 + (size_t)(brNN + src[j])*768;
                kv[j] = *(const uchar2v*)(rp + 256 + hd);
                vv[j] = *(const uchar2v*)(rp + 512 + hd);
            }
        }
        float dt[4];
        #pragma unroll
        for (int j=0;j<4;j++){
            float d = 0.f;
            if (j < cnt) d = qr[0]*fp82f(kv[j][0]) + qr[1]*fp82f(kv[j][1]);
            dt[j] = d;
        }
        #pragma unroll
        for (int o=32;o;o>>=1){
            #pragma unroll
            for (int j=0;j<4;j++) dt[j] += __shfl_xor(dt[j], o, 64);
        }
        float cm = -INFINITY;
        #pragma unroll
        for (int j=0;j<4;j++) if (j < cnt) cm = fmaxf(cm, dt[j]);
        const float mn = fmaxf(m, cm);
        const float cs = exp2f(m - mn);
        z *= cs;
        acc[0] *= cs; acc[1] *= cs;
        #pragma unroll
        for (int j=0;j<4;j++){
            if (j < cnt){
                const float w = exp2f(dt[j] - mn);
                z += w;
                acc[0] += w*fp82f(vv[j][0]);
                acc[1] += w*fp82f(vv[j][1]);
            }
        }
        m = mn;
    }
    const float invz = 1.0f/(z + 1e-16f);
    const short2v sv = *(const short2v*)(s1 + (size_t)n*256 + hd);
    short2v ov;
    ov[0] = f2b(lrelu_f(b2f(sv[0]) + acc[0]*invz));
    ov[1] = f2b(lrelu_f(b2f(sv[1]) + acc[1]*invz));
    *(short2v*)(hout + (size_t)n*256 + hd) = ov;
}

// ========== attention layer-2 + fused segment-max pool (atomicMax on float keys) ======
// s bf16 [NN,512]; q/k/v fp8 [NN,1536] (q 0-511, k 512-1023, v 1024-1535).
__global__ __launch_bounds__(256)
void attn512_f8(const bf16* __restrict__ s2, const unsigned char* __restrict__ f82,
                const int* __restrict__ rowptr, const int* __restrict__ srcs,
                const int* __restrict__ bt,
                unsigned int* __restrict__ gkey, int grow0, int gc0)
{
    __shared__ float Sh[4][512];
    __shared__ int Sgid[4];
    const int lane = threadIdx.x & 63;
    const int wave = threadIdx.x >> 6;
    const int n = blockIdx.x * 4 + wave;
    const float qscale = rsqrtf(512.f) * 1.44269504f;
    const int hd = lane*8;

    const uchar8 q8 = *(const uchar8*)(f82 + (size_t)n*1536 + hd);
    float qr[8];
    #pragma unroll
    for (int i=0;i<8;i++) qr[i] = fp82f(q8[i]) * qscale;

    const int e0 = rowptr[n], e1 = rowptr[n+1];
    float m = -INFINITY, z = 0.f;
    float acc[8];
    #pragma unroll
    for (int i=0;i<8;i++) acc[i] = 0.f;

    for (int base = e0; base < e1; base += 4){
        const int cnt = min(4, e1 - base);
        int sl = srcs[min(base + (lane & 3), e1 - 1)];
        int src[4];
        #pragma unroll
        for (int j=0;j<4;j++) src[j] = __shfl(sl, j, 64);

        uchar8 k8[4], v8[4];
        #pragma unroll
        for (int j=0;j<4;j++){
            if (j < cnt){
                const unsigned char* rp = f82 + (size_t)src[j]*1536;
                k8[j] = *(const uchar8*)(rp + 512 + hd);
                v8[j] = *(const uchar8*)(rp + 1024 + hd);
            }
        }
        float dt[4];
        #pragma unroll
        for (int j=0;j<4;j++){
            float d = 0.f;
            if (j < cnt){
                #pragma unroll
                for (int i=0;i<8;i++) d += qr[i]*fp82f(k8[j][i]);
            }
            dt[j] = d;
        }
        #pragma unroll
        for (int o=32;o;o>>=1){
            #pragma unroll
            for (int j=0;j<4;j++) dt[j] += __shfl_xor(dt[j], o, 64);
        }
        float cm = -INFINITY;
        #pragma unroll
        for (int j=0;j<4;j++) if (j < cnt) cm = fmaxf(cm, dt[j]);
        const float mn = fmaxf(m, cm);
        const float cs = exp2f(m - mn);
        z *= cs;
        #pragma unroll
        for (int i=0;i<8;i++) acc[i] *= cs;
        #pragma unroll
        for (int j=0;j<4;j++){
            if (j < cnt){
                const float w = exp2f(dt[j] - mn);
                z += w;
                #pragma unroll
                for (int i=0;i<8;i++) acc[i] += w*fp82f(v8[j][i]);
            }
        }
        m = mn;
    }
    const float invz = 1.0f/(z + 1e-16f);
    const short8 sv = *(const short8*)(s2 + (size_t)n*512 + hd);
    #pragma unroll
    for (int i=0;i<8;i++) Sh[wave][hd + i] = lrelu_f(b2f(sv[i]) + acc[i]*invz);
    if (lane == 0) Sgid[wave] = bt[n];
    __syncthreads();

    // segmented max over the block's 4 rows, one atomic per (graph,col) run
    #pragma unroll
    for (int cc=0; cc<2; cc++){
        const int col = threadIdx.x*2 + cc;
        float mx = Sh[0][col];
        int gid = Sgid[0];
        #pragma unroll
        for (int r=1; r<4; r++){
            if (Sgid[r] == gid) mx = fmaxf(mx, Sh[r][col]);
            else {
                atomicMax(&gkey[(size_t)(grow0 + gid)*1024 + gc0 + col], fkey(mx));
                gid = Sgid[r]; mx = Sh[r][col];
            }
        }
        atomicMax(&gkey[(size_t)(grow0 + gid)*1024 + gc0 + col], fkey(mx));
    }
}

// ================= fused MLP tail (1024 threads): split-K dense step, bf16 weights ====
template<int R, int N, int ACT>
__device__ __forceinline__ void dense_split(
    const bf16* __restrict__ Wp, const float* __restrict__ bias,
    const float* __restrict__ gam, const float* __restrict__ bet, float bns,
    const float* A, int lda, float* C, int ldc, int K, int tid, float* Spart)
{
    constexpr int CPT = N / 128;
    constexpr int KG  = 8;
    const int ct = tid & 127;
    const int kg = tid >> 7;
    const int jt = ct * CPT;
    const int Kc = ((K + KG - 1) / KG + 3) & ~3;
    const int kb = kg * Kc;
    const int Kpad = (K + 3) & ~3;
    const int ke = min(Kpad, kb + Kc);

    float acc[R][CPT];
    #pragma unroll
    for (int r=0;r<R;r++)
        #pragma unroll
        for (int c=0;c<CPT;c++) acc[r][c] = 0.f;

    if (kb < ke){
        short8 p0, p1; short4v p4;
        {
            const bf16* wp = Wp + ((size_t)(kb>>2)*N + jt)*4;
            if (CPT==4){ p0 = ((const short8*)wp)[0]; p1 = ((const short8*)wp)[1]; }
            else if (CPT==2){ p0 = *(const short8*)wp; }
            else { p4 = *(const short4v*)wp; }
        }
        for (int k = kb; k < ke; k += 4){
            short8 c0 = p0, c1 = p1; short4v c4 = p4;
            const int kn = (k + 4 < ke) ? k + 4 : kb;
            const bf16* wn = Wp + ((size_t)(kn>>2)*N + jt)*4;
            if (CPT==4){ p0 = ((const short8*)wn)[0]; p1 = ((const short8*)wn)[1]; }
            else if (CPT==2){ p0 = *(const short8*)wn; }
            else { p4 = *(const short4v*)wn; }
            float w[4][CPT];
            if (CPT==4){
                #pragma unroll
                for (int u=0;u<4;u++){
                    w[u][0] = b2f(c0[u]); w[u][1] = b2f(c0[4+u]);
                    w[u][2] = b2f(c1[u]); w[u][3] = b2f(c1[4+u]);
                }
            } else if (CPT==2){
                #pragma unroll
                for (int u=0;u<4;u++){ w[u][0] = b2f(c0[u]); w[u][1] = b2f(c0[4+u]); }
            } else {
                #pragma unroll
                for (int u=0;u<4;u++) w[u][0] = b2f(c4[u]);
            }
            #pragma unroll
            for (int r=0;r<R;r++){
                const floatx4 av = *(const floatx4*)(A + r*lda + k);
                #pragma unroll
                for (int u=0;u<4;u++)
                    #pragma unroll
                    for (int c=0;c<CPT;c++) acc[r][c] += av[u]*w[u][c];
            }
        }
    }
    #pragma unroll
    for (int r=0;r<R;r++)
        #pragma unroll
        for (int c=0;c<CPT;c++)
            Spart[(kg*R + r)*N + jt + c] = acc[r][c];
    __syncthreads();
    for (int idx = tid; idx < R*N; idx += 1024){
        int r = idx / N, j = idx - r*N;
        float v = 0.f;
        #pragma unroll
        for (int g=0; g<KG; g++) v += Spart[(g*R + r)*N + j];
        v += bias[j];
        if (ACT==1) v = lrelu_f(v);
        if (ACT==2) v = lrelu_f(v*bns*gam[j] + bet[j]);
        C[r*ldc + j] = v;
    }
    __syncthreads();
}

// ================= fused tail: graph-head + cell branch + head MLP, 2 graphs/block ====
__global__ __launch_bounds__(1024)
void tail_kernel(const unsigned int* __restrict__ gkey,  // [2*BB][1024] encoded maxes
                 const float* __restrict__ cell,         // [BB][954]
                 const bf16*  __restrict__ Wtp,          // packed tail weights
                 const float* __restrict__ bg1, const float* __restrict__ bg2,
                 const float* __restrict__ br1, const float* __restrict__ br2,
                 const float* __restrict__ br3,
                 const float* __restrict__ bf1,
                 const float* __restrict__ gbn1, const float* __restrict__ bbn1,
                 const float* __restrict__ bf2,
                 const float* __restrict__ gbn2, const float* __restrict__ bbn2,
                 const float* __restrict__ wf3, const float* __restrict__ bf3,
                 float bns, float* __restrict__ outp)
{
    __shared__ float Sg[4][1024];    // rows: lg*2 + br
    __shared__ float Sgh[4][512];
    __shared__ float Sgout[4][128];
    __shared__ float Scell[2][960];
    __shared__ float Sc1[2][512];
    __shared__ float Sc2[2][256];
    __shared__ float Sc3[2][128];
    __shared__ float Sxc[2][384];
    __shared__ float Sf1[2][512];
    __shared__ float Sf2[2][256];
    __shared__ float Spart[16384];   // split-K partials (KG=8, max R*N = 4*512)
    __shared__ float inv4[4], invc[2], invx[2];

    const int tid = threadIdx.x;
    const int wv  = tid >> 6;
    const int ln  = tid & 63;
    const int b0  = blockIdx.x * 2;

    {
        int idx = tid*4;                 // 0..4092
        int r = idx >> 10, c = idx & 1023;
        int lg = r >> 1, br = r & 1;
        const unsigned int* gp = gkey + (size_t)(br*BB + b0 + lg)*1024 + c;
        #pragma unroll
        for (int i=0;i<4;i++) Sg[r][c+i] = fdec(gp[i]);
    }
    for (int idx = tid; idx < 2*954; idx += 1024){
        int r = (idx >= 954) ? 1 : 0;
        int c = idx - r*954;
        Scell[r][c] = cell[(size_t)(b0 + r)*954 + c];
    }
    if (tid < 12){ int r = tid/6; Scell[r][954 + tid%6] = 0.f; }
    __syncthreads();

    if (wv < 2){
        float s = 0.f;
        for (int c = ln; c < 954; c += 64){ float v = Scell[wv][c]; s += v*v; }
        #pragma unroll
        for (int o=32;o;o>>=1) s += __shfl_xor(s, o, 64);
        if (ln == 0) invc[wv] = 1.0f / fmaxf(sqrtf(s), 1e-12f);
    }
    __syncthreads();
    #pragma unroll
    for (int r=0;r<2;r++)
        for (int c = tid; c < 954; c += 1024) Scell[r][c] *= invc[r];
    __syncthreads();

    dense_split<4,512,1>(Wtp+OG1, bg1, nullptr, nullptr, 1.f, &Sg[0][0],   1024, &Sgh[0][0],  512, 1024, tid, Spart);
    dense_split<4,128,0>(Wtp+OG2, bg2, nullptr, nullptr, 1.f, &Sgh[0][0],  512,  &Sgout[0][0],128, 512,  tid, Spart);
    dense_split<2,512,1>(Wtp+OR1, br1, nullptr, nullptr, 1.f, &Scell[0][0], 960, &Sc1[0][0],  512, 954,  tid, Spart);
    dense_split<2,256,1>(Wtp+OR2, br2, nullptr, nullptr, 1.f, &Sc1[0][0],   512, &Sc2[0][0],  256, 512,  tid, Spart);
    dense_split<2,128,0>(Wtp+OR3, br3, nullptr, nullptr, 1.f, &Sc2[0][0],   256, &Sc3[0][0],  128, 256,  tid, Spart);

    if (wv < 4){
        float a = Sgout[wv][ln], bq = Sgout[wv][ln+64];
        float s = a*a + bq*bq;
        #pragma unroll
        for (int o=32;o;o>>=1) s += __shfl_xor(s, o, 64);
        if (ln == 0) inv4[wv] = 1.0f / fmaxf(sqrtf(s), 1e-12f);
    }
    __syncthreads();

    if (tid < 768){
        int lg = tid / 384, j = tid - lg*384;
        float v;
        if (j < 128)      v = Sgout[lg*2+0][j]     * inv4[lg*2+0];
        else if (j < 256) v = Sgout[lg*2+1][j-128] * inv4[lg*2+1];
        else              v = Sc3[lg][j-256];
        Sxc[lg][j] = v;
    }
    __syncthreads();
    if (wv < 2){
        float s = 0.f;
        #pragma unroll
        for (int i=0;i<6;i++){ float v = Sxc[wv][ln + i*64]; s += v*v; }
        #pragma unroll
        for (int o=32;o;o>>=1) s += __shfl_xor(s, o, 64);
        if (ln == 0) invx[wv] = 1.0f / fmaxf(sqrtf(s), 1e-12f);
    }
    __syncthreads();
    if (tid < 768){
        int lg = tid / 384, j = tid - lg*384;
        Sxc[lg][j] *= invx[lg];
    }
    __syncthreads();

    dense_split<2,512,2>(Wtp+OF1, bf1, gbn1, bbn1, bns, &Sxc[0][0], 384, &Sf1[0][0], 512, 384, tid, Spart);
    dense_split<2,256,2>(Wtp+OF2, bf2, gbn2, bbn2, bns, &Sf1[0][0], 512, &Sf2[0][0], 256, 512, tid, Spart);

    if (wv < 2){
        float s = 0.f;
        #pragma unroll
        for (int i=0;i<4;i++){ int c = ln + i*64; s += Sf2[wv][c]*wf3[c]; }
        #pragma unroll
        for (int o=32;o;o>>=1) s += __shfl_xor(s, o, 64);
        if (ln == 0) outp[b0 + wv] = 1.0f/(1.0f + expf(-(s + bf3[0])));
    }
}

extern "C" void kernel_launch(void* const* d_in, const int* in_sizes, int n_in,
                              void* d_out, int out_size, void* d_ws, size_t ws_size,
                              hipStream_t stream)
{
    const float* x1  = (const float*)d_in[0];
    const int*   ei1 = (const int*)  d_in[1];
    const int*   bt1 = (const int*)  d_in[2];
    const float* x2  = (const float*)d_in[3];
    const int*   ei2 = (const int*)  d_in[4];
    const int*   bt2 = (const int*)  d_in[5];
    const float* cell= (const float*)d_in[6];
    const float* wq1=(const float*)d_in[7];  const float* bq1=(const float*)d_in[8];
    const float* wk1=(const float*)d_in[9];  const float* bk1=(const float*)d_in[10];
    const float* wv1=(const float*)d_in[11]; const float* bv1=(const float*)d_in[12];
    const float* ws1=(const float*)d_in[13]; const float* bs1=(const float*)d_in[14];
    const float* wq2=(const float*)d_in[15]; const float* bq2=(const float*)d_in[16];
    const float* wk2=(const float*)d_in[17]; const float* bk2=(const float*)d_in[18];
    const float* wv2=(const float*)d_in[19]; const float* bv2=(const float*)d_in[20];
    const float* ws2=(const float*)d_in[21]; const float* bs2q=(const float*)d_in[22];
    const float* wg1=(const float*)d_in[23]; const float* bg1=(const float*)d_in[24];
    const float* wg2=(const float*)d_in[25]; const float* bg2=(const float*)d_in[26];
    const float* wr1=(const float*)d_in[27]; const float* br1=(const float*)d_in[28];
    const float* wr2=(const float*)d_in[29]; const float* br2=(const float*)d_in[30];
    const float* wr3=(const float*)d_in[31]; const float* br3=(const float*)d_in[32];
    const float* wf1=(const float*)d_in[33]; const float* bf1=(const float*)d_in[34];
    const float* gbn1=(const float*)d_in[35];const float* bbn1=(const float*)d_in[36];
    const float* wf2=(const float*)d_in[37]; const float* bf2=(const float*)d_in[38];
    const float* gbn2=(const float*)d_in[39];const float* bbn2=(const float*)d_in[40];
    const float* wf3=(const float*)d_in[41]; const float* bf3=(const float*)d_in[42];
    float* outp = (float*)d_out;
    (void)in_sizes; (void)n_in; (void)out_size; (void)ws_size;

    const float BNS = 1.0f / sqrtf(1.0f + 1e-5f);

    // ---- workspace arena (~72 MB peak) ----
    char* basep = (char*)d_ws;
    size_t off = 0;
    auto alloc = [&](size_t nbytes)->char* {
        char* p = basep + off;
        off += (nbytes + 255) & ~(size_t)255;
        return p;
    };
    int* rowptr2  = (int*)  alloc((size_t)2*(NN+1)*4);
    int* rowcur2  = (int*)  alloc((size_t)2*(NN+1)*4);
    int* cnt2     = (int*)  alloc((size_t)2*NN*4);
    int* srcs2    = (int*)  alloc((size_t)2*EE*4);
    unsigned int* gkey = (unsigned int*)alloc((size_t)2*BB*1024*4);  // pooled-max keys
    float* b1c    = (float*)alloc((size_t)1024*4);
    float* b2c    = (float*)alloc((size_t)4096*4);
    bf16* W1t     = (bf16*) alloc((size_t)1024*96*2);
    bf16* W2t     = (bf16*) alloc((size_t)2*2048*256*2);
    bf16* Wtp     = (bf16*) alloc((size_t)TAILW_TOTAL*2);
    bf16* h1      = (bf16*) alloc((size_t)2*NN*256*2);
    bf16* xa      = (bf16*) alloc((size_t)2*NN*96*2);
    // 40 MB QK arena (identical layout both layers):
    //   layer1: s1 [2NN,256] bf16 (16MB) + f81 [2NN,768] u8 (24MB)
    //   layer2: s2 [NN,512]  bf16 (16MB) + f82 [NN,1536] u8 (24MB)
    char* QK      = alloc((size_t)16777216 + 25165824);
    bf16* s1a     = (bf16*)QK;
    unsigned char* f81 = (unsigned char*)(QK + 16777216);
    bf16* s2a     = (bf16*)QK;
    unsigned char* f82 = (unsigned char*)(QK + 16777216);

    // ---- prep (1 mega dispatch) + CSR ----
    (void)hipMemsetAsync(cnt2, 0, (size_t)2*NN*4, stream);
    prep_mega_kernel<<<P_GK/256,256,0,stream>>>(
        wq1,wk1,wv1,ws1, bq1,bk1,bv1,bs1,
        wq2,wk2,wv2,ws2, bq2,bk2,bv2,bs2q,
        wg1,wg2,wr1,wr2,wr3,wf1,wf2,
        x1,x2,
        W1t,b1c,W2t,b2c, Wtp, xa, gkey);
    hist_kernel<<<2*EE/256,256,0,stream>>>(ei1, ei2, cnt2);
    scan_kernel<<<2,1024,0,stream>>>(cnt2, rowptr2, rowcur2);
    scatter_kernel<<<2*EE/256,256,0,stream>>>(ei1, ei2, rowcur2, srcs2);

    // ---- layer 1 (both branches stacked): [2NN,96]x[96,1024], s bf16 / q,k,v fp8 ----
    mfma_gemm<<<dim3(8, 2*NN/128),256,0,stream>>>(xa,96, W1t,96, b1c,
                                                  s1a,256, f81,768, 256, 96);
    attn128_f8<<<2*NN*2/4,256,0,stream>>>(s1a, f81, h1, rowptr2, srcs2);

    // ---- layer 2: per (branch, head): GEMM (s bf16, q/k/v fp8) + attn+pool fused ----
    for (int br=0; br<2; br++){
        const int* bt = br ? bt2 : bt1;
        for (int h=0; h<2; h++){
            mfma_gemm<<<dim3(16, NN/128),256,0,stream>>>(
                h1 + (size_t)br*NN*256, 256, W2t + (size_t)h*2048*256, 256,
                b2c + h*2048, s2a,512, f82,1536, 512, 256);
            attn512_f8<<<NN/4,256,0,stream>>>(s2a, f82,
                                              rowptr2 + br*(NN+1), srcs2 + br*EE, bt,
                                              gkey, br*BB, h*512);
        }
    }

    // ---- fused tail: graph-head + cell + head MLP + sigmoid, one dispatch ----
    tail_kernel<<<BB/2,1024,0,stream>>>(gkey, cell, Wtp,
                                        bg1,bg2, br1,br2,br3,
                                        bf1,gbn1,bbn1, bf2,gbn2,bbn2, wf3,bf3,
                                        BNS, outp);
}

// Round 15
// 543.074 us; speedup vs baseline: 1.4896x; 1.0227x over previous
//
#include <hip/hip_runtime.h>
#include <hip/hip_bf16.h>
#include <hip/hip_fp8.h>
#include <math.h>
#include <stdint.h>

typedef __hip_bfloat16 bf16;

#define NN 16384
#define EE 65536
#define BB 512

typedef __attribute__((ext_vector_type(8))) short short8;
typedef __attribute__((ext_vector_type(2))) short short2v;
typedef __attribute__((ext_vector_type(4))) float floatx4;
typedef __attribute__((ext_vector_type(8))) unsigned char uchar8;
typedef __attribute__((ext_vector_type(2))) unsigned char uchar2v;

#define GKEY_NEGINF 0x007FFFFFu   // fkey(-inf)

__device__ __forceinline__ float lrelu_f(float x){ return x >= 0.f ? x : 0.01f*x; }

__device__ __forceinline__ float b2f(short s){
    unsigned int u = ((unsigned int)(unsigned short)s) << 16;
    float f; __builtin_memcpy(&f, &u, 4); return f;
}
__device__ __forceinline__ short f2b(float f){
    bf16 b = (bf16)f;
    short s; __builtin_memcpy(&s, &b, 2); return s;
}
__device__ __forceinline__ unsigned char f2fp8(float f){
    __hip_fp8_e4m3 t(f);
    return (unsigned char)t.__x;
}
__device__ __forceinline__ float fp82f(unsigned char c){
    __hip_fp8_e4m3 t; t.__x = (__hip_fp8_storage_t)c;
    return (float)t;
}
// order-preserving float<->u32 for atomicMax pooling
__device__ __forceinline__ unsigned int fkey(float f){
    unsigned int u; __builtin_memcpy(&u, &f, 4);
    return (u & 0x80000000u) ? ~u : (u | 0x80000000u);
}
__device__ __forceinline__ float fdec(unsigned int k){
    if (k == GKEY_NEGINF) return 0.f;   // empty graph -> where(isfinite)=0
    unsigned int u = (k & 0x80000000u) ? (k ^ 0x80000000u) : ~k;
    float f; __builtin_memcpy(&f, &u, 4); return f;
}

// async 16B global->LDS. LDS dest is wave-uniform base; lane i lands at base+16*i.
__device__ __forceinline__ void gl2lds16(const void* g, void* l){
    __builtin_amdgcn_global_load_lds(
        (__attribute__((address_space(1))) unsigned int*)(uintptr_t)g,
        (__attribute__((address_space(3))) unsigned int*)(uintptr_t)l, 16, 0, 0);
}

// ================= MFMA bf16 GEMM: C[m,n] = A[m,:K] @ W[:,n] + bias[n] =================
// Blocks with n0 < nsplit store bf16 to C (ldc); blocks with n0 >= nsplit convert to
// fp8-e4m3 and store to C2 (ldc2) at col n-nsplit. LDS: staging and epilogue aliased.
__global__ __launch_bounds__(256)
void mfma_gemm(const bf16* __restrict__ A, int lda,
               const bf16* __restrict__ Bt, int ldb,
               const float* __restrict__ bias,
               bf16* __restrict__ C, int ldc,
               unsigned char* __restrict__ C2, int ldc2, int nsplit, int K)
{
    __shared__ __align__(16) char smem[20480];
    bf16* As  = (bf16*)smem;            // [128*32]
    bf16* Bs  = (bf16*)(smem + 8192);   // [128*32]
    bf16* epi = (bf16*)smem;            // [4*64*40] epilogue (aliases As/Bs)
    const int tid  = threadIdx.x;
    const int wave = tid >> 6;
    const int lane = tid & 63;
    const int wm = (wave & 1) * 64;
    const int wn = (wave >> 1) * 64;
    const int m0 = blockIdx.y * 128;
    const int n0 = blockIdx.x * 128;
    const bool isf8 = (n0 >= nsplit);

    const int srow = lane >> 2;
    const int scol = (lane & 3) * 8;
    const int arow = lane & 15;
    const int aq   = (lane >> 4) * 8;

    floatx4 acc[4][4];
    #pragma unroll
    for (int i=0;i<4;i++)
        #pragma unroll
        for (int j=0;j<4;j++) acc[i][j] = (floatx4){0.f,0.f,0.f,0.f};

    for (int k0 = 0; k0 < K; k0 += 32) {
        #pragma unroll
        for (int i = 0; i < 2; i++) {
            const int chunk = wave*2 + i;
            const int r = chunk*16 + srow;
            gl2lds16(A  + (size_t)(m0 + r)*lda + k0 + scol, As + chunk*512);
            gl2lds16(Bt + (size_t)(n0 + r)*ldb + k0 + scol, Bs + chunk*512);
        }
        __syncthreads();
        short8 af[4], bf_[4];
        #pragma unroll
        for (int i=0;i<4;i++) af[i]  = *(const short8*)(As + (wm + i*16 + arow)*32 + aq);
        #pragma unroll
        for (int j=0;j<4;j++) bf_[j] = *(const short8*)(Bs + (wn + j*16 + arow)*32 + aq);
        #pragma unroll
        for (int i=0;i<4;i++)
            #pragma unroll
            for (int j=0;j<4;j++)
                acc[i][j] = __builtin_amdgcn_mfma_f32_16x16x32_bf16(af[i], bf_[j], acc[i][j], 0,0,0);
        __syncthreads();
    }
    const int crow = (lane >> 4) * 4;
    const int ccol = lane & 15;
    const int erow = lane >> 2;
    const int ecol = (lane & 3) * 8;
    bf16* ep = epi + wave * (64*40);
    #pragma unroll
    for (int j2 = 0; j2 < 2; j2++){
        if (j2) __syncthreads();
        #pragma unroll
        for (int jj = 0; jj < 2; jj++){
            const int j = j2*2 + jj;
            const float bsv = bias[n0 + wn + j*16 + ccol];
            #pragma unroll
            for (int i = 0; i < 4; i++)
                #pragma unroll
                for (int r = 0; r < 4; r++)
                    ep[(i*16 + crow + r)*40 + jj*16 + ccol] = (bf16)(acc[i][j][r] + bsv);
        }
        __syncthreads();
        #pragma unroll
        for (int q = 0; q < 4; q++){
            const int rr = q*16 + erow;
            short8 vv = *(const short8*)(ep + rr*40 + ecol);
            if (!isf8){
                *(short8*)(C + (size_t)(m0 + wm + rr)*ldc + n0 + wn + j2*32 + ecol) = vv;
            } else {
                uchar8 ob;
                #pragma unroll
                for (int i=0;i<8;i++) ob[i] = f2fp8(b2f(vv[i]));
                *(uchar8*)(C2 + (size_t)(m0 + wm + rr)*ldc2 + (n0 - nsplit) + wn + j2*32 + ecol) = ob;
            }
        }
    }
}

// ---- tail weights: MFMA B-fragment order [tile][ks][lane][8]. Offsets in Wtp arena ----
// Wm[((tile*KS+ks))*512 + lane*8 + j] = W[k][n], n=tile*16+(lane&15), k=ks*32+(lane>>4)*8+j
#define OG1 0         // wg1 1024x512: T=32 KS=32
#define OG2 524288    // wg2 512x128:  T=8  KS=16
#define OR1 589824    // wr1 954x512:  T=32 KS=30
#define OR2 1081344   // wr2 512x256:  T=16 KS=16
#define OR3 1212416   // wr3 256x128:  T=8  KS=8
#define OF1 1245184   // wf1 384x512:  T=32 KS=12
#define OF2 1441792   // wf2 512x256:  T=16 KS=16
#define TAILW_TOTAL 1572864

// ============ merged prep: W1t,b1c,W2t,b2c + Wtp + xa + gkey in ONE dispatch ==========
// Weight order both layers: s | q | k | v  (s stays bf16 in epilogue; q/k/v -> fp8)
#define P_W1T 98304
#define P_B1C (P_W1T + 1024)
#define P_W2T (P_B1C + 1048576)
#define P_B2C (P_W2T + 4096)
#define P_WTP (P_B2C + TAILW_TOTAL)
#define P_XA  (P_WTP + 2*NN*96)
#define P_GK  (P_XA + 2*BB*1024)
__global__ void prep_mega_kernel(
    const float* __restrict__ wq1, const float* __restrict__ wk1,
    const float* __restrict__ wv1, const float* __restrict__ ws1,
    const float* __restrict__ bq1, const float* __restrict__ bk1,
    const float* __restrict__ bv1, const float* __restrict__ bs1,
    const float* __restrict__ wq2, const float* __restrict__ wk2,
    const float* __restrict__ wv2, const float* __restrict__ ws2,
    const float* __restrict__ bq2, const float* __restrict__ bk2,
    const float* __restrict__ bv2, const float* __restrict__ bs2v,
    const float* __restrict__ wg1, const float* __restrict__ wg2,
    const float* __restrict__ wr1, const float* __restrict__ wr2,
    const float* __restrict__ wr3, const float* __restrict__ wf1,
    const float* __restrict__ wf2,
    const float* __restrict__ x1,  const float* __restrict__ x2,
    bf16* __restrict__ W1t, float* __restrict__ b1c,
    bf16* __restrict__ W2t, float* __restrict__ b2c,
    bf16* __restrict__ Wtp, bf16* __restrict__ xa,
    unsigned int* __restrict__ gkey)
{
    int i = blockIdx.x*256 + threadIdx.x;
    if (i < P_W1T){                      // W1t: [1024][96], n order s|q|k|v (256 each)
        int n = i / 96, k = i - n*96;
        int seg = n >> 8;
        const float* w = (seg==0)?ws1:(seg==1)?wq1:(seg==2)?wk1:wv1;
        W1t[i] = (k < 78) ? (bf16)w[(size_t)k*256 + (n & 255)] : (bf16)0.f;
        return;
    }
    if (i < P_B1C){                      // b1c (s|q|k|v)
        int n = i - P_W1T;
        int seg = n >> 8;
        const float* b = (seg==0)?bs1:(seg==1)?bq1:(seg==2)?bk1:bv1;
        b1c[n] = b[n & 255];
        return;
    }
    if (i < P_W2T){                      // W2t: [2][2048][256], j order s|q|k|v (512 each)
        int loc = i - P_B1C;
        int k = loc & 255;
        int j = (loc >> 8) & 2047;
        int h = loc >> 19;
        const float* w = (j<512)?ws2:(j<1024)?wq2:(j<1536)?wk2:wv2;
        W2t[loc] = (bf16)w[(size_t)k*1024 + h*512 + (j & 511)];
        return;
    }
    if (i < P_B2C){                      // b2c (s|q|k|v)
        int loc = i - P_W2T;
        int j = loc & 2047, h = loc >> 11;
        const float* b = (j<512)?bs2v:(j<1024)?bq2:(j<1536)?bk2:bv2;
        b2c[loc] = b[h*512 + (j & 511)];
        return;
    }
    if (i < P_WTP){                      // packed tail weights, MFMA B-fragment order
        int t = i - P_B2C;
        const float* W; int N, K, KS, base;
        if      (t < OG2){ W = wg1; N = 512; K = 1024; KS = 32; base = OG1; }
        else if (t < OR1){ W = wg2; N = 128; K = 512;  KS = 16; base = OG2; }
        else if (t < OR2){ W = wr1; N = 512; K = 954;  KS = 30; base = OR1; }
        else if (t < OR3){ W = wr2; N = 256; K = 512;  KS = 16; base = OR2; }
        else if (t < OF1){ W = wr3; N = 128; K = 256;  KS = 8;  base = OR3; }
        else if (t < OF2){ W = wf1; N = 512; K = 384;  KS = 12; base = OF1; }
        else             { W = wf2; N = 256; K = 512;  KS = 16; base = OF2; }
        int loc = t - base;
        int j  = loc & 7;
        int ln = (loc >> 3) & 63;
        int rest = loc >> 9;
        int ks = rest % KS;
        int tile = rest / KS;
        int n = tile*16 + (ln & 15);
        int k = ks*32 + (ln >> 4)*8 + j;
        Wtp[t] = (k < K) ? (bf16)W[(size_t)k*N + n] : (bf16)0.f;
        return;
    }
    if (i < P_XA){                       // xa: [2NN][96] bf16 (zero-padded K)
        int t = i - P_WTP;
        int r = t / 96, c = t - r*96;
        const float* x = (r >= NN) ? x2 : x1;
        int lr = r & (NN-1);
        xa[t] = (c < 78) ? (bf16)x[(size_t)lr*78 + c] : (bf16)0.f;
        return;
    }
    if (i < P_GK){                       // gkey init
        gkey[i - P_XA] = GKEY_NEGINF;
    }
}

// ================= CSR build (both branches, stacked) =================
__global__ void hist_kernel(const int* __restrict__ ei1, const int* __restrict__ ei2,
                            int* __restrict__ cnt){
    int eg = blockIdx.x*256 + threadIdx.x;     // 0..2EE
    int br = eg >> 16, e = eg & (EE-1);
    const int* ei = br ? ei2 : ei1;
    atomicAdd(&cnt[br*NN + ei[EE + e]], 1);
}

// writes rowptr AND a cursor copy (rowcur) so scatter needs no cnt re-zero
__global__ __launch_bounds__(1024)
void scan_kernel(const int* __restrict__ hist, int* __restrict__ rowptr,
                 int* __restrict__ rowcur){
    const int br = blockIdx.x;
    hist   += br*NN;
    rowptr += br*(NN+1);
    rowcur += br*(NN+1);
    __shared__ int sums[1024];
    const int t = threadIdx.x;
    const int base = t*16;
    int loc[16]; int s = 0;
    #pragma unroll
    for (int i=0;i<16;i++){ loc[i]=s; s += hist[base+i]; }
    sums[t] = s; __syncthreads();
    for (int o=1;o<1024;o<<=1){
        int v = (t>=o) ? sums[t-o] : 0;
        __syncthreads();
        sums[t] += v;
        __syncthreads();
    }
    int pref = (t>0) ? sums[t-1] : 0;
    #pragma unroll
    for (int i=0;i<16;i++){
        int v = pref + loc[i];
        rowptr[base+i] = v;
        rowcur[base+i] = v;
    }
    if (t==1023) rowptr[NN] = sums[1023];
}

__global__ void scatter_kernel(const int* __restrict__ ei1, const int* __restrict__ ei2,
                               int* __restrict__ rowcur, int* __restrict__ srcs){
    int eg = blockIdx.x*256 + threadIdx.x;
    int br = eg >> 16, e = eg & (EE-1);
    const int* ei = br ? ei2 : ei1;
    int d = ei[EE + e];
    int pos = atomicAdd(&rowcur[br*(NN+1) + d], 1);
    srcs[br*EE + pos] = ei[e];
}

// ======= attention layer-1: s bf16 [2NN,256], q/k/v fp8 [2NN,768], H=2, D=128 =========
__global__ __launch_bounds__(256)
void attn128_f8(const bf16* __restrict__ s1, const unsigned char* __restrict__ f81,
                bf16* __restrict__ hout,
                const int* __restrict__ rowptr, const int* __restrict__ srcs)
{
    const int lane = threadIdx.x & 63;
    const int gw = blockIdx.x * 4 + (threadIdx.x >> 6);
    const int n = gw >> 1;               // global node 0..2NN
    const int h = gw & 1;
    int br = n >> 14;
    int brNN = br*NN, nl = n - brNN;
    rowptr += br*(NN+1); srcs += br*EE;
    const float qscale = rsqrtf(128.f) * 1.44269504f;
    const int hd = h*128 + lane*2;

    const uchar2v q8 = *(const uchar2v*)(f81 + (size_t)n*768 + hd);
    float qr[2] = { fp82f(q8[0])*qscale, fp82f(q8[1])*qscale };

    const int e0 = rowptr[nl], e1 = rowptr[nl+1];
    float m = -INFINITY, z = 0.f;
    float acc[2] = {0.f, 0.f};

    for (int base = e0; base < e1; base += 4){
        const int cnt = min(4, e1 - base);
        int sl = srcs[min(base + (lane & 3), e1 - 1)];
        int src[4];
        #pragma unroll
        for (int j=0;j<4;j++) src[j] = __shfl(sl, j, 64);

        uchar2v kv[4], vv[4];
        #pragma unroll
        for (int j=0;j<4;j++){
            if (j < cnt){
                const unsigned char* rp = f81 + (size_t)(brNN + src[j])*768;
                kv[j] = *(const uchar2v*)(rp + 256 + hd);
                vv[j] = *(const uchar2v*)(rp + 512 + hd);
            }
        }
        float dt[4];
        #pragma unroll
        for (int j=0;j<4;j++){
            float d = 0.f;
            if (j < cnt) d = qr[0]*fp82f(kv[j][0]) + qr[1]*fp82f(kv[j][1]);
            dt[j] = d;
        }
        #pragma unroll
        for (int o=32;o;o>>=1){
            #pragma unroll
            for (int j=0;j<4;j++) dt[j] += __shfl_xor(dt[j], o, 64);
        }
        float cm = -INFINITY;
        #pragma unroll
        for (int j=0;j<4;j++) if (j < cnt) cm = fmaxf(cm, dt[j]);
        const float mn = fmaxf(m, cm);
        const float cs = exp2f(m - mn);
        z *= cs;
        acc[0] *= cs; acc[1] *= cs;
        #pragma unroll
        for (int j=0;j<4;j++){
            if (j < cnt){
                const float w = exp2f(dt[j] - mn);
                z += w;
                acc[0] += w*fp82f(vv[j][0]);
                acc[1] += w*fp82f(vv[j][1]);
            }
        }
        m = mn;
    }
    const float invz = 1.0f/(z + 1e-16f);
    const short2v sv = *(const short2v*)(s1 + (size_t)n*256 + hd);
    short2v ov;
    ov[0] = f2b(lrelu_f(b2f(sv[0]) + acc[0]*invz));
    ov[1] = f2b(lrelu_f(b2f(sv[1]) + acc[1]*invz));
    *(short2v*)(hout + (size_t)n*256 + hd) = ov;
}

// ====== attention layer-2 (stacked branches) + fused segment-max pool ================
// s bf16 [2NN,512]; q/k/v fp8 [2NN,1536] (q 0-511, k 512-1023, v 1024-1535).
__global__ __launch_bounds__(256)
void attn512_f8(const bf16* __restrict__ s2, const unsigned char* __restrict__ f82,
                const int* __restrict__ rowptr, const int* __restrict__ srcs,
                const int* __restrict__ bt1, const int* __restrict__ bt2,
                unsigned int* __restrict__ gkey, int gc0)
{
    __shared__ float Sh[4][512];
    __shared__ int Sgid[4];
    const int lane = threadIdx.x & 63;
    const int wave = threadIdx.x >> 6;
    const int n = blockIdx.x * 4 + wave;     // global node 0..2NN (block never spans br)
    const int br = n >> 14;
    const int brNN = br*NN, nl = n - brNN;
    const int* rp_ = rowptr + br*(NN+1);
    const int* sp_ = srcs + br*EE;
    const float qscale = rsqrtf(512.f) * 1.44269504f;
    const int hd = lane*8;

    const uchar8 q8 = *(const uchar8*)(f82 + (size_t)n*1536 + hd);
    float qr[8];
    #pragma unroll
    for (int i=0;i<8;i++) qr[i] = fp82f(q8[i]) * qscale;

    const int e0 = rp_[nl], e1 = rp_[nl+1];
    float m = -INFINITY, z = 0.f;
    float acc[8];
    #pragma unroll
    for (int i=0;i<8;i++) acc[i] = 0.f;

    for (int base = e0; base < e1; base += 4){
        const int cnt = min(4, e1 - base);
        int sl = sp_[min(base + (lane & 3), e1 - 1)];
        int src[4];
        #pragma unroll
        for (int j=0;j<4;j++) src[j] = __shfl(sl, j, 64);

        uchar8 k8[4], v8[4];
        #pragma unroll
        for (int j=0;j<4;j++){
            if (j < cnt){
                const unsigned char* rp = f82 + (size_t)(brNN + src[j])*1536;
                k8[j] = *(const uchar8*)(rp + 512 + hd);
                v8[j] = *(const uchar8*)(rp + 1024 + hd);
            }
        }
        float dt[4];
        #pragma unroll
        for (int j=0;j<4;j++){
            float d = 0.f;
            if (j < cnt){
                #pragma unroll
                for (int i=0;i<8;i++) d += qr[i]*fp82f(k8[j][i]);
            }
            dt[j] = d;
        }
        #pragma unroll
        for (int o=32;o;o>>=1){
            #pragma unroll
            for (int j=0;j<4;j++) dt[j] += __shfl_xor(dt[j], o, 64);
        }
        float cm = -INFINITY;
        #pragma unroll
        for (int j=0;j<4;j++) if (j < cnt) cm = fmaxf(cm, dt[j]);
        const float mn = fmaxf(m, cm);
        const float cs = exp2f(m - mn);
        z *= cs;
        #pragma unroll
        for (int i=0;i<8;i++) acc[i] *= cs;
        #pragma unroll
        for (int j=0;j<4;j++){
            if (j < cnt){
                const float w = exp2f(dt[j] - mn);
                z += w;
                #pragma unroll
                for (int i=0;i<8;i++) acc[i] += w*fp82f(v8[j][i]);
            }
        }
        m = mn;
    }
    const float invz = 1.0f/(z + 1e-16f);
    const short8 sv = *(const short8*)(s2 + (size_t)n*512 + hd);
    #pragma unroll
    for (int i=0;i<8;i++) Sh[wave][hd + i] = lrelu_f(b2f(sv[i]) + acc[i]*invz);
    if (lane == 0) Sgid[wave] = br*BB + (br ? bt2[nl] : bt1[nl]);
    __syncthreads();

    // segmented max over the block's 4 rows, one atomic per (graph,col) run
    #pragma unroll
    for (int cc=0; cc<2; cc++){
        const int col = threadIdx.x*2 + cc;
        float mx = Sh[0][col];
        int gid = Sgid[0];
        #pragma unroll
        for (int r=1; r<4; r++){
            if (Sgid[r] == gid) mx = fmaxf(mx, Sh[r][col]);
            else {
                atomicMax(&gkey[(size_t)gid*1024 + gc0 + col], fkey(mx));
                gid = Sgid[r]; mx = Sh[r][col];
            }
        }
        atomicMax(&gkey[(size_t)gid*1024 + gc0 + col], fkey(mx));
    }
}

// ================= tail dense layer via MFMA (1024 threads = 16 waves) ===============
// 16 waves partition N into 16-col tiles; each wave runs full K for its tiles.
// A: LDS f32 [R][lda] (rows >= R contribute zeros). Wm: MFMA B-fragment packed.
// ACT: 0 none, 1 lrelu, 2 BN+lrelu. Ends with __syncthreads().
template<int R, int N, int ACT>
__device__ __forceinline__ void dense_mfma(
    const bf16* __restrict__ Wm, const float* __restrict__ bias,
    const float* __restrict__ gam, const float* __restrict__ bet, float bns,
    const float* A, int lda, float* C, int ldc, int K, int tid)
{
    constexpr int T   = N / 16;
    constexpr int TPW = (T + 15) / 16;
    const int wave = tid >> 6;
    const int lane = tid & 63;
    const int am = lane & 15;
    const int ak = (lane >> 4) * 8;
    const int KS = ((K + 31) & ~31) >> 5;

    floatx4 acc[TPW];
    #pragma unroll
    for (int tp=0; tp<TPW; tp++) acc[tp] = (floatx4){0.f,0.f,0.f,0.f};

    for (int ks = 0; ks < KS; ks++){
        short8 af = (short8){0,0,0,0,0,0,0,0};
        if (am < R){
            const float* ap = A + am*lda + ks*32 + ak;
            const floatx4 a0 = *(const floatx4*)ap;
            const floatx4 a1 = *(const floatx4*)(ap + 4);
            af[0]=f2b(a0[0]); af[1]=f2b(a0[1]); af[2]=f2b(a0[2]); af[3]=f2b(a0[3]);
            af[4]=f2b(a1[0]); af[5]=f2b(a1[1]); af[6]=f2b(a1[2]); af[7]=f2b(a1[3]);
        }
        #pragma unroll
        for (int tp=0; tp<TPW; tp++){
            const int tile = wave + tp*16;
            if (tile < T){
                const short8 bfv = *(const short8*)(Wm + ((size_t)(tile*KS + ks))*512 + lane*8);
                acc[tp] = __builtin_amdgcn_mfma_f32_16x16x32_bf16(af, bfv, acc[tp], 0,0,0);
            }
        }
    }
    const int crow = (lane >> 4) * 4;
    const int ccol = lane & 15;
    #pragma unroll
    for (int tp=0; tp<TPW; tp++){
        const int tile = wave + tp*16;
        if (tile < T){
            #pragma unroll
            for (int r=0; r<4; r++){
                const int row = crow + r;
                if (row < R){
                    const int n = tile*16 + ccol;
                    float v = acc[tp][r] + bias[n];
                    if (ACT==1) v = lrelu_f(v);
                    if (ACT==2) v = lrelu_f(v*bns*gam[n] + bet[n]);
                    C[row*ldc + n] = v;
                }
            }
        }
    }
    __syncthreads();
}

// ================= fused tail: graph-head + cell branch + head MLP, 2 graphs/block ====
__global__ __launch_bounds__(1024)
void tail_kernel(const unsigned int* __restrict__ gkey,  // [2*BB][1024] encoded maxes
                 const float* __restrict__ cell,         // [BB][954]
                 const bf16*  __restrict__ Wtp,          // packed tail weights
                 const float* __restrict__ bg1, const float* __restrict__ bg2,
                 const float* __restrict__ br1, const float* __restrict__ br2,
                 const float* __restrict__ br3,
                 const float* __restrict__ bf1,
                 const float* __restrict__ gbn1, const float* __restrict__ bbn1,
                 const float* __restrict__ bf2,
                 const float* __restrict__ gbn2, const float* __restrict__ bbn2,
                 const float* __restrict__ wf3, const float* __restrict__ bf3,
                 float bns, float* __restrict__ outp)
{
    __shared__ float Sg[4][1024];    // rows: lg*2 + br
    __shared__ float Sgh[4][512];
    __shared__ float Sgout[4][128];
    __shared__ float Scell[2][960];
    __shared__ float Sc1[2][512];
    __shared__ float Sc2[2][256];
    __shared__ float Sc3[2][128];
    __shared__ float Sxc[2][384];
    __shared__ float Sf1[2][512];
    __shared__ float Sf2[2][256];
    __shared__ float inv4[4], invc[2], invx[2];

    const int tid = threadIdx.x;
    const int wv  = tid >> 6;
    const int ln  = tid & 63;
    const int b0  = blockIdx.x * 2;

    {
        int idx = tid*4;                 // 0..4092
        int r = idx >> 10, c = idx & 1023;
        int lg = r >> 1, br = r & 1;
        const unsigned int* gp = gkey + (size_t)(br*BB + b0 + lg)*1024 + c;
        #pragma unroll
        for (int i=0;i<4;i++) Sg[r][c+i] = fdec(gp[i]);
    }
    for (int idx = tid; idx < 2*954; idx += 1024){
        int r = (idx >= 954) ? 1 : 0;
        int c = idx - r*954;
        Scell[r][c] = cell[(size_t)(b0 + r)*954 + c];
    }
    if (tid < 12){ int r = tid/6; Scell[r][954 + tid%6] = 0.f; }
    __syncthreads();

    if (wv < 2){
        float s = 0.f;
        for (int c = ln; c < 954; c += 64){ float v = Scell[wv][c]; s += v*v; }
        #pragma unroll
        for (int o=32;o;o>>=1) s += __shfl_xor(s, o, 64);
        if (ln == 0) invc[wv] = 1.0f / fmaxf(sqrtf(s), 1e-12f);
    }
    __syncthreads();
    #pragma unroll
    for (int r=0;r<2;r++)
        for (int c = tid; c < 954; c += 1024) Scell[r][c] *= invc[r];
    __syncthreads();

    dense_mfma<4,512,1>(Wtp+OG1, bg1, nullptr, nullptr, 1.f, &Sg[0][0],   1024, &Sgh[0][0],  512, 1024, tid);
    dense_mfma<4,128,0>(Wtp+OG2, bg2, nullptr, nullptr, 1.f, &Sgh[0][0],  512,  &Sgout[0][0],128, 512,  tid);
    dense_mfma<2,512,1>(Wtp+OR1, br1, nullptr, nullptr, 1.f, &Scell[0][0], 960, &Sc1[0][0],  512, 954,  tid);
    dense_mfma<2,256,1>(Wtp+OR2, br2, nullptr, nullptr, 1.f, &Sc1[0][0],   512, &Sc2[0][0],  256, 512,  tid);
    dense_mfma<2,128,0>(Wtp+OR3, br3, nullptr, nullptr, 1.f, &Sc2[0][0],   256, &Sc3[0][0],  128, 256,  tid);

    if (wv < 4){
        float a = Sgout[wv][ln], bq = Sgout[wv][ln+64];
        float s = a*a + bq*bq;
        #pragma unroll
        for (int o=32;o;o>>=1) s += __shfl_xor(s, o, 64);
        if (ln == 0) inv4[wv] = 1.0f / fmaxf(sqrtf(s), 1e-12f);
    }
    __syncthreads();

    if (tid < 768){
        int lg = tid / 384, j = tid - lg*384;
        float v;
        if (j < 128)      v = Sgout[lg*2+0][j]     * inv4[lg*2+0];
        else if (j < 256) v = Sgout[lg*2+1][j-128] * inv4[lg*2+1];
        else              v = Sc3[lg][j-256];
        Sxc[lg][j] = v;
    }
    __syncthreads();
    if (wv < 2){
        float s = 0.f;
        #pragma unroll
        for (int i=0;i<6;i++){ float v = Sxc[wv][ln + i*64]; s += v*v; }
        #pragma unroll
        for (int o=32;o;o>>=1) s += __shfl_xor(s, o, 64);
        if (ln == 0) invx[wv] = 1.0f / fmaxf(sqrtf(s), 1e-12f);
    }
    __syncthreads();
    if (tid < 768){
        int lg = tid / 384, j = tid - lg*384;
        Sxc[lg][j] *= invx[lg];
    }
    __syncthreads();

    dense_mfma<2,512,2>(Wtp+OF1, bf1, gbn1, bbn1, bns, &Sxc[0][0], 384, &Sf1[0][0], 512, 384, tid);
    dense_mfma<2,256,2>(Wtp+OF2, bf2, gbn2, bbn2, bns, &Sf1[0][0], 512, &Sf2[0][0], 256, 512, tid);

    if (wv < 2){
        float s = 0.f;
        #pragma unroll
        for (int i=0;i<4;i++){ int c = ln + i*64; s += Sf2[wv][c]*wf3[c]; }
        #pragma unroll
        for (int o=32;o;o>>=1) s += __shfl_xor(s, o, 64);
        if (ln == 0) outp[b0 + wv] = 1.0f/(1.0f + expf(-(s + bf3[0])));
    }
}

extern "C" void kernel_launch(void* const* d_in, const int* in_sizes, int n_in,
                              void* d_out, int out_size, void* d_ws, size_t ws_size,
                              hipStream_t stream)
{
    const float* x1  = (const float*)d_in[0];
    const int*   ei1 = (const int*)  d_in[1];
    const int*   bt1 = (const int*)  d_in[2];
    const float* x2  = (const float*)d_in[3];
    const int*   ei2 = (const int*)  d_in[4];
    const int*   bt2 = (const int*)  d_in[5];
    const float* cell= (const float*)d_in[6];
    const float* wq1=(const float*)d_in[7];  const float* bq1=(const float*)d_in[8];
    const float* wk1=(const float*)d_in[9];  const float* bk1=(const float*)d_in[10];
    const float* wv1=(const float*)d_in[11]; const float* bv1=(const float*)d_in[12];
    const float* ws1=(const float*)d_in[13]; const float* bs1=(const float*)d_in[14];
    const float* wq2=(const float*)d_in[15]; const float* bq2=(const float*)d_in[16];
    const float* wk2=(const float*)d_in[17]; const float* bk2=(const float*)d_in[18];
    const float* wv2=(const float*)d_in[19]; const float* bv2=(const float*)d_in[20];
    const float* ws2=(const float*)d_in[21]; const float* bs2q=(const float*)d_in[22];
    const float* wg1=(const float*)d_in[23]; const float* bg1=(const float*)d_in[24];
    const float* wg2=(const float*)d_in[25]; const float* bg2=(const float*)d_in[26];
    const float* wr1=(const float*)d_in[27]; const float* br1=(const float*)d_in[28];
    const float* wr2=(const float*)d_in[29]; const float* br2=(const float*)d_in[30];
    const float* wr3=(const float*)d_in[31]; const float* br3=(const float*)d_in[32];
    const float* wf1=(const float*)d_in[33]; const float* bf1=(const float*)d_in[34];
    const float* gbn1=(const float*)d_in[35];const float* bbn1=(const float*)d_in[36];
    const float* wf2=(const float*)d_in[37]; const float* bf2=(const float*)d_in[38];
    const float* gbn2=(const float*)d_in[39];const float* bbn2=(const float*)d_in[40];
    const float* wf3=(const float*)d_in[41]; const float* bf3=(const float*)d_in[42];
    float* outp = (float*)d_out;
    (void)in_sizes; (void)n_in; (void)out_size; (void)ws_size;

    const float BNS = 1.0f / sqrtf(1.0f + 1e-5f);

    // ---- workspace arena (~107 MB peak; BIG region phase-aliased) ----
    char* basep = (char*)d_ws;
    size_t off = 0;
    auto alloc = [&](size_t nbytes)->char* {
        char* p = basep + off;
        off += (nbytes + 255) & ~(size_t)255;
        return p;
    };
    int* rowptr2  = (int*)  alloc((size_t)2*(NN+1)*4);
    int* rowcur2  = (int*)  alloc((size_t)2*(NN+1)*4);
    int* cnt2     = (int*)  alloc((size_t)2*NN*4);
    int* srcs2    = (int*)  alloc((size_t)2*EE*4);
    unsigned int* gkey = (unsigned int*)alloc((size_t)2*BB*1024*4);  // pooled-max keys
    float* b1c    = (float*)alloc((size_t)1024*4);
    float* b2c    = (float*)alloc((size_t)4096*4);
    bf16* W1t     = (bf16*) alloc((size_t)1024*96*2);
    bf16* W2t     = (bf16*) alloc((size_t)2*2048*256*2);
    bf16* Wtp     = (bf16*) alloc((size_t)TAILW_TOTAL*2);
    bf16* h1      = (bf16*) alloc((size_t)2*NN*256*2);    // layer-1 out, both branches
    // BIG phase-aliased region (80 MB):
    //   phase1: xa [2NN,96] bf16 (6.3MB) | s1 [2NN,256] bf16 (16MB) | f81 [2NN,768] u8 (24MB)
    //   phase2: s2 [2NN,512] bf16 (32MB) | f82 [2NN,1536] u8 (48MB)
    char* BIG     = alloc((size_t)2*NN*512*2 + (size_t)2*NN*1536);
    bf16* xa      = (bf16*)BIG;
    bf16* s1a     = (bf16*)(BIG + 6291456);
    unsigned char* f81 = (unsigned char*)(BIG + 6291456 + 16777216);
    bf16* s2a     = (bf16*)BIG;
    unsigned char* f82 = (unsigned char*)(BIG + (size_t)2*NN*512*2);

    // ---- prep (1 mega dispatch) + CSR ----
    (void)hipMemsetAsync(cnt2, 0, (size_t)2*NN*4, stream);
    prep_mega_kernel<<<P_GK/256,256,0,stream>>>(
        wq1,wk1,wv1,ws1, bq1,bk1,bv1,bs1,
        wq2,wk2,wv2,ws2, bq2,bk2,bv2,bs2q,
        wg1,wg2,wr1,wr2,wr3,wf1,wf2,
        x1,x2,
        W1t,b1c,W2t,b2c, Wtp, xa, gkey);
    hist_kernel<<<2*EE/256,256,0,stream>>>(ei1, ei2, cnt2);
    scan_kernel<<<2,1024,0,stream>>>(cnt2, rowptr2, rowcur2);
    scatter_kernel<<<2*EE/256,256,0,stream>>>(ei1, ei2, rowcur2, srcs2);

    // ---- layer 1 (both branches stacked): [2NN,96]x[96,1024], s bf16 / q,k,v fp8 ----
    mfma_gemm<<<dim3(8, 2*NN/128),256,0,stream>>>(xa,96, W1t,96, b1c,
                                                  s1a,256, f81,768, 256, 96);
    attn128_f8<<<2*NN*2/4,256,0,stream>>>(s1a, f81, h1, rowptr2, srcs2);

    // ---- layer 2 (branches stacked): per head GEMM + attn+pool fused ----
    for (int h=0; h<2; h++){
        mfma_gemm<<<dim3(16, 2*NN/128),256,0,stream>>>(
            h1, 256, W2t + (size_t)h*2048*256, 256,
            b2c + h*2048, s2a,512, f82,1536, 512, 256);
        attn512_f8<<<2*NN/4,256,0,stream>>>(s2a, f82, rowptr2, srcs2, bt1, bt2,
                                            gkey, h*512);
    }

    // ---- fused tail: graph-head + cell + head MLP + sigmoid, one dispatch ----
    tail_kernel<<<BB/2,1024,0,stream>>>(gkey, cell, Wtp,
                                        bg1,bg2, br1,br2,br3,
                                        bf1,gbn1,bbn1, bf2,gbn2,bbn2, wf3,bf3,
                                        BNS, outp);
}

// Round 16
// 514.653 us; speedup vs baseline: 1.5718x; 1.0552x over previous
//
#include <hip/hip_runtime.h>
#include <hip/hip_bf16.h>
#include <hip/hip_fp8.h>
#include <math.h>
#include <stdint.h>

typedef __hip_bfloat16 bf16;

#define NN 16384
#define EE 65536
#define BB 512

typedef __attribute__((ext_vector_type(8))) short short8;
typedef __attribute__((ext_vector_type(2))) short short2v;
typedef __attribute__((ext_vector_type(4))) float floatx4;
typedef __attribute__((ext_vector_type(2))) float floatx2;
typedef __attribute__((ext_vector_type(2))) unsigned int uint2v;

#define GKEY_NEGINF 0x007FFFFFu   // fkey(-inf)

__device__ __forceinline__ float lrelu_f(float x){ return x >= 0.f ? x : 0.01f*x; }

__device__ __forceinline__ float b2f(short s){
    unsigned int u = ((unsigned int)(unsigned short)s) << 16;
    float f; __builtin_memcpy(&f, &u, 4); return f;
}
__device__ __forceinline__ short f2b(float f){
    bf16 b = (bf16)f;
    short s; __builtin_memcpy(&s, &b, 2); return s;
}
// order-preserving float<->u32 for atomicMax pooling
__device__ __forceinline__ unsigned int fkey(float f){
    unsigned int u; __builtin_memcpy(&u, &f, 4);
    return (u & 0x80000000u) ? ~u : (u | 0x80000000u);
}
__device__ __forceinline__ float fdec(unsigned int k){
    if (k == GKEY_NEGINF) return 0.f;   // empty graph -> where(isfinite)=0
    unsigned int u = (k & 0x80000000u) ? (k ^ 0x80000000u) : ~k;
    float f; __builtin_memcpy(&f, &u, 4); return f;
}

// async 16B global->LDS. LDS dest is wave-uniform base; lane i lands at base+16*i.
__device__ __forceinline__ void gl2lds16(const void* g, void* l){
    __builtin_amdgcn_global_load_lds(
        (__attribute__((address_space(1))) unsigned int*)(uintptr_t)g,
        (__attribute__((address_space(3))) unsigned int*)(uintptr_t)l, 16, 0, 0);
}

// ================= MFMA bf16 GEMM: C[m,n] = A[m,:K] @ W[:,n] + bias[n] =================
// grid: x = m-blocks (consecutive blocks -> disjoint A rows -> no cross-XCD A re-fetch),
// y = n-blocks. Blocks with n0 < nsplit store bf16 to C; else HW-pack fp8-e4m3 to C2.
__global__ __launch_bounds__(256)
void mfma_gemm(const bf16* __restrict__ A, int lda,
               const bf16* __restrict__ Bt, int ldb,
               const float* __restrict__ bias,
               bf16* __restrict__ C, int ldc,
               unsigned char* __restrict__ C2, int ldc2, int nsplit, int K)
{
    __shared__ __align__(16) char smem[20480];
    bf16* As  = (bf16*)smem;            // [128*32]
    bf16* Bs  = (bf16*)(smem + 8192);   // [128*32]
    bf16* epi = (bf16*)smem;            // [4*64*40] epilogue (aliases As/Bs)
    const int tid  = threadIdx.x;
    const int wave = tid >> 6;
    const int lane = tid & 63;
    const int wm = (wave & 1) * 64;
    const int wn = (wave >> 1) * 64;
    const int m0 = blockIdx.x * 128;
    const int n0 = blockIdx.y * 128;
    const bool isf8 = (n0 >= nsplit);

    const int srow = lane >> 2;
    const int scol = (lane & 3) * 8;
    const int arow = lane & 15;
    const int aq   = (lane >> 4) * 8;

    floatx4 acc[4][4];
    #pragma unroll
    for (int i=0;i<4;i++)
        #pragma unroll
        for (int j=0;j<4;j++) acc[i][j] = (floatx4){0.f,0.f,0.f,0.f};

    for (int k0 = 0; k0 < K; k0 += 32) {
        #pragma unroll
        for (int i = 0; i < 2; i++) {
            const int chunk = wave*2 + i;
            const int r = chunk*16 + srow;
            gl2lds16(A  + (size_t)(m0 + r)*lda + k0 + scol, As + chunk*512);
            gl2lds16(Bt + (size_t)(n0 + r)*ldb + k0 + scol, Bs + chunk*512);
        }
        __syncthreads();
        short8 af[4], bf_[4];
        #pragma unroll
        for (int i=0;i<4;i++) af[i]  = *(const short8*)(As + (wm + i*16 + arow)*32 + aq);
        #pragma unroll
        for (int j=0;j<4;j++) bf_[j] = *(const short8*)(Bs + (wn + j*16 + arow)*32 + aq);
        #pragma unroll
        for (int i=0;i<4;i++)
            #pragma unroll
            for (int j=0;j<4;j++)
                acc[i][j] = __builtin_amdgcn_mfma_f32_16x16x32_bf16(af[i], bf_[j], acc[i][j], 0,0,0);
        __syncthreads();
    }
    const int crow = (lane >> 4) * 4;
    const int ccol = lane & 15;
    const int erow = lane >> 2;
    const int ecol = (lane & 3) * 8;
    bf16* ep = epi + wave * (64*40);
    #pragma unroll
    for (int j2 = 0; j2 < 2; j2++){
        if (j2) __syncthreads();
        #pragma unroll
        for (int jj = 0; jj < 2; jj++){
            const int j = j2*2 + jj;
            const float bsv = bias[n0 + wn + j*16 + ccol];
            #pragma unroll
            for (int i = 0; i < 4; i++)
                #pragma unroll
                for (int r = 0; r < 4; r++)
                    ep[(i*16 + crow + r)*40 + jj*16 + ccol] = (bf16)(acc[i][j][r] + bsv);
        }
        __syncthreads();
        #pragma unroll
        for (int q = 0; q < 4; q++){
            const int rr = q*16 + erow;
            short8 vv = *(const short8*)(ep + rr*40 + ecol);
            if (!isf8){
                *(short8*)(C + (size_t)(m0 + wm + rr)*ldc + n0 + wn + j2*32 + ecol) = vv;
            } else {
                // HW fp8 pack: 4 ops per 8 values (was ~15-op SW encode each)
                int d0 = 0, d1 = 0;
                d0 = __builtin_amdgcn_cvt_pk_fp8_f32(b2f(vv[0]), b2f(vv[1]), d0, false);
                d0 = __builtin_amdgcn_cvt_pk_fp8_f32(b2f(vv[2]), b2f(vv[3]), d0, true);
                d1 = __builtin_amdgcn_cvt_pk_fp8_f32(b2f(vv[4]), b2f(vv[5]), d1, false);
                d1 = __builtin_amdgcn_cvt_pk_fp8_f32(b2f(vv[6]), b2f(vv[7]), d1, true);
                uint2v ob; ob[0] = (unsigned int)d0; ob[1] = (unsigned int)d1;
                *(uint2v*)(C2 + (size_t)(m0 + wm + rr)*ldc2 + (n0 - nsplit) + wn + j2*32 + ecol) = ob;
            }
        }
    }
}

// ---- tail weights: MFMA B-fragment order [tile][ks][lane][8]. Offsets in Wtp arena ----
#define OG1 0         // wg1 1024x512: T=32 KS=32
#define OG2 524288    // wg2 512x128:  T=8  KS=16
#define OR1 589824    // wr1 954x512:  T=32 KS=30
#define OR2 1081344   // wr2 512x256:  T=16 KS=16
#define OR3 1212416   // wr3 256x128:  T=8  KS=8
#define OF1 1245184   // wf1 384x512:  T=32 KS=12
#define OF2 1441792   // wf2 512x256:  T=16 KS=16
#define TAILW_TOTAL 1572864

// ============ merged prep: W1t,b1c,W2t,b2c + Wtp + xa + gkey in ONE dispatch ==========
// Weight order both layers: s | q | k | v  (s stays bf16 in epilogue; q/k/v -> fp8)
#define P_W1T 98304
#define P_B1C (P_W1T + 1024)
#define P_W2T (P_B1C + 1048576)
#define P_B2C (P_W2T + 4096)
#define P_WTP (P_B2C + TAILW_TOTAL)
#define P_XA  (P_WTP + 2*NN*96)
#define P_GK  (P_XA + 2*BB*1024)
__global__ void prep_mega_kernel(
    const float* __restrict__ wq1, const float* __restrict__ wk1,
    const float* __restrict__ wv1, const float* __restrict__ ws1,
    const float* __restrict__ bq1, const float* __restrict__ bk1,
    const float* __restrict__ bv1, const float* __restrict__ bs1,
    const float* __restrict__ wq2, const float* __restrict__ wk2,
    const float* __restrict__ wv2, const float* __restrict__ ws2,
    const float* __restrict__ bq2, const float* __restrict__ bk2,
    const float* __restrict__ bv2, const float* __restrict__ bs2v,
    const float* __restrict__ wg1, const float* __restrict__ wg2,
    const float* __restrict__ wr1, const float* __restrict__ wr2,
    const float* __restrict__ wr3, const float* __restrict__ wf1,
    const float* __restrict__ wf2,
    const float* __restrict__ x1,  const float* __restrict__ x2,
    bf16* __restrict__ W1t, float* __restrict__ b1c,
    bf16* __restrict__ W2t, float* __restrict__ b2c,
    bf16* __restrict__ Wtp, bf16* __restrict__ xa,
    unsigned int* __restrict__ gkey)
{
    int i = blockIdx.x*256 + threadIdx.x;
    if (i < P_W1T){                      // W1t: [1024][96], n order s|q|k|v (256 each)
        int n = i / 96, k = i - n*96;
        int seg = n >> 8;
        const float* w = (seg==0)?ws1:(seg==1)?wq1:(seg==2)?wk1:wv1;
        W1t[i] = (k < 78) ? (bf16)w[(size_t)k*256 + (n & 255)] : (bf16)0.f;
        return;
    }
    if (i < P_B1C){                      // b1c (s|q|k|v)
        int n = i - P_W1T;
        int seg = n >> 8;
        const float* b = (seg==0)?bs1:(seg==1)?bq1:(seg==2)?bk1:bv1;
        b1c[n] = b[n & 255];
        return;
    }
    if (i < P_W2T){                      // W2t: [2][2048][256], j order s|q|k|v (512 each)
        int loc = i - P_B1C;
        int k = loc & 255;
        int j = (loc >> 8) & 2047;
        int h = loc >> 19;
        const float* w = (j<512)?ws2:(j<1024)?wq2:(j<1536)?wk2:wv2;
        W2t[loc] = (bf16)w[(size_t)k*1024 + h*512 + (j & 511)];
        return;
    }
    if (i < P_B2C){                      // b2c (s|q|k|v)
        int loc = i - P_W2T;
        int j = loc & 2047, h = loc >> 11;
        const float* b = (j<512)?bs2v:(j<1024)?bq2:(j<1536)?bk2:bv2;
        b2c[loc] = b[h*512 + (j & 511)];
        return;
    }
    if (i < P_WTP){                      // packed tail weights, MFMA B-fragment order
        int t = i - P_B2C;
        const float* W; int N, K, KS, base;
        if      (t < OG2){ W = wg1; N = 512; K = 1024; KS = 32; base = OG1; }
        else if (t < OR1){ W = wg2; N = 128; K = 512;  KS = 16; base = OG2; }
        else if (t < OR2){ W = wr1; N = 512; K = 954;  KS = 30; base = OR1; }
        else if (t < OR3){ W = wr2; N = 256; K = 512;  KS = 16; base = OR2; }
        else if (t < OF1){ W = wr3; N = 128; K = 256;  KS = 8;  base = OR3; }
        else if (t < OF2){ W = wf1; N = 512; K = 384;  KS = 12; base = OF1; }
        else             { W = wf2; N = 256; K = 512;  KS = 16; base = OF2; }
        int loc = t - base;
        int j  = loc & 7;
        int ln = (loc >> 3) & 63;
        int rest = loc >> 9;
        int ks = rest % KS;
        int tile = rest / KS;
        int n = tile*16 + (ln & 15);
        int k = ks*32 + (ln >> 4)*8 + j;
        Wtp[t] = (k < K) ? (bf16)W[(size_t)k*N + n] : (bf16)0.f;
        return;
    }
    if (i < P_XA){                       // xa: [2NN][96] bf16 (zero-padded K)
        int t = i - P_WTP;
        int r = t / 96, c = t - r*96;
        const float* x = (r >= NN) ? x2 : x1;
        int lr = r & (NN-1);
        xa[t] = (c < 78) ? (bf16)x[(size_t)lr*78 + c] : (bf16)0.f;
        return;
    }
    if (i < P_GK){                       // gkey init
        gkey[i - P_XA] = GKEY_NEGINF;
    }
}

// ================= CSR build (both branches, stacked) =================
__global__ void hist_kernel(const int* __restrict__ ei1, const int* __restrict__ ei2,
                            int* __restrict__ cnt){
    int eg = blockIdx.x*256 + threadIdx.x;     // 0..2EE
    int br = eg >> 16, e = eg & (EE-1);
    const int* ei = br ? ei2 : ei1;
    atomicAdd(&cnt[br*NN + ei[EE + e]], 1);
}

__global__ __launch_bounds__(1024)
void scan_kernel(const int* __restrict__ hist, int* __restrict__ rowptr,
                 int* __restrict__ rowcur){
    const int br = blockIdx.x;
    hist   += br*NN;
    rowptr += br*(NN+1);
    rowcur += br*(NN+1);
    __shared__ int sums[1024];
    const int t = threadIdx.x;
    const int base = t*16;
    int loc[16]; int s = 0;
    #pragma unroll
    for (int i=0;i<16;i++){ loc[i]=s; s += hist[base+i]; }
    sums[t] = s; __syncthreads();
    for (int o=1;o<1024;o<<=1){
        int v = (t>=o) ? sums[t-o] : 0;
        __syncthreads();
        sums[t] += v;
        __syncthreads();
    }
    int pref = (t>0) ? sums[t-1] : 0;
    #pragma unroll
    for (int i=0;i<16;i++){
        int v = pref + loc[i];
        rowptr[base+i] = v;
        rowcur[base+i] = v;
    }
    if (t==1023) rowptr[NN] = sums[1023];
}

__global__ void scatter_kernel(const int* __restrict__ ei1, const int* __restrict__ ei2,
                               int* __restrict__ rowcur, int* __restrict__ srcs){
    int eg = blockIdx.x*256 + threadIdx.x;
    int br = eg >> 16, e = eg & (EE-1);
    const int* ei = br ? ei2 : ei1;
    int d = ei[EE + e];
    int pos = atomicAdd(&rowcur[br*(NN+1) + d], 1);
    srcs[br*EE + pos] = ei[e];
}

// ======= attention layer-1: s bf16 [2NN,256], q/k/v fp8 [2NN,768], H=2, D=128 =========
__global__ __launch_bounds__(256)
void attn128_f8(const bf16* __restrict__ s1, const unsigned char* __restrict__ f81,
                bf16* __restrict__ hout,
                const int* __restrict__ rowptr, const int* __restrict__ srcs)
{
    const int lane = threadIdx.x & 63;
    const int gw = blockIdx.x * 4 + (threadIdx.x >> 6);
    const int n = gw >> 1;               // global node 0..2NN
    const int h = gw & 1;
    int br = n >> 14;
    int brNN = br*NN, nl = n - brNN;
    rowptr += br*(NN+1); srcs += br*EE;
    const float qscale = rsqrtf(128.f) * 1.44269504f;
    const int hd = h*128 + lane*2;

    unsigned short qw; __builtin_memcpy(&qw, f81 + (size_t)n*768 + hd, 2);
    floatx2 qd = __builtin_amdgcn_cvt_pk_f32_fp8((int)qw, false);
    float qr[2] = { qd[0]*qscale, qd[1]*qscale };

    const int e0 = rowptr[nl], e1 = rowptr[nl+1];
    float m = -INFINITY, z = 0.f;
    float acc[2] = {0.f, 0.f};

    for (int base = e0; base < e1; base += 4){
        const int cnt = min(4, e1 - base);
        int sl = srcs[min(base + (lane & 3), e1 - 1)];
        int src[4];
        #pragma unroll
        for (int j=0;j<4;j++) src[j] = __shfl(sl, j, 64);

        unsigned short kw[4], vw[4];
        #pragma unroll
        for (int j=0;j<4;j++){
            if (j < cnt){
                const unsigned char* rp = f81 + (size_t)(brNN + src[j])*768;
                __builtin_memcpy(&kw[j], rp + 256 + hd, 2);
                __builtin_memcpy(&vw[j], rp + 512 + hd, 2);
            }
        }
        float dt[4];
        #pragma unroll
        for (int j=0;j<4;j++){
            float d = 0.f;
            if (j < cnt){
                floatx2 kd = __builtin_amdgcn_cvt_pk_f32_fp8((int)kw[j], false);
                d = qr[0]*kd[0] + qr[1]*kd[1];
            }
            dt[j] = d;
        }
        #pragma unroll
        for (int o=32;o;o>>=1){
            #pragma unroll
            for (int j=0;j<4;j++) dt[j] += __shfl_xor(dt[j], o, 64);
        }
        float cm = -INFINITY;
        #pragma unroll
        for (int j=0;j<4;j++) if (j < cnt) cm = fmaxf(cm, dt[j]);
        const float mn = fmaxf(m, cm);
        const float cs = exp2f(m - mn);
        z *= cs;
        acc[0] *= cs; acc[1] *= cs;
        #pragma unroll
        for (int j=0;j<4;j++){
            if (j < cnt){
                const float w = exp2f(dt[j] - mn);
                z += w;
                floatx2 vd = __builtin_amdgcn_cvt_pk_f32_fp8((int)vw[j], false);
                acc[0] += w*vd[0];
                acc[1] += w*vd[1];
            }
        }
        m = mn;
    }
    const float invz = 1.0f/(z + 1e-16f);
    const short2v sv = *(const short2v*)(s1 + (size_t)n*256 + hd);
    short2v ov;
    ov[0] = f2b(lrelu_f(b2f(sv[0]) + acc[0]*invz));
    ov[1] = f2b(lrelu_f(b2f(sv[1]) + acc[1]*invz));
    *(short2v*)(hout + (size_t)n*256 + hd) = ov;
}

// ====== attention layer-2 (stacked branches) + fused segment-max pool ================
// s bf16 [2NN,512]; q/k/v fp8 [2NN,1536] (q 0-511, k 512-1023, v 1024-1535).
__global__ __launch_bounds__(256)
void attn512_f8(const bf16* __restrict__ s2, const unsigned char* __restrict__ f82,
                const int* __restrict__ rowptr, const int* __restrict__ srcs,
                const int* __restrict__ bt1, const int* __restrict__ bt2,
                unsigned int* __restrict__ gkey, int gc0)
{
    __shared__ float Sh[4][512];
    __shared__ int Sgid[4];
    const int lane = threadIdx.x & 63;
    const int wave = threadIdx.x >> 6;
    const int n = blockIdx.x * 4 + wave;     // global node 0..2NN (block never spans br)
    const int br = n >> 14;
    const int brNN = br*NN, nl = n - brNN;
    const int* rp_ = rowptr + br*(NN+1);
    const int* sp_ = srcs + br*EE;
    const float qscale = rsqrtf(512.f) * 1.44269504f;
    const int hd = lane*8;

    float qr[8];
    {
        const uint2v qv = *(const uint2v*)(f82 + (size_t)n*1536 + hd);
        floatx2 a = __builtin_amdgcn_cvt_pk_f32_fp8((int)qv[0], false);
        floatx2 b = __builtin_amdgcn_cvt_pk_f32_fp8((int)qv[0], true);
        floatx2 c = __builtin_amdgcn_cvt_pk_f32_fp8((int)qv[1], false);
        floatx2 d = __builtin_amdgcn_cvt_pk_f32_fp8((int)qv[1], true);
        qr[0]=a[0]*qscale; qr[1]=a[1]*qscale; qr[2]=b[0]*qscale; qr[3]=b[1]*qscale;
        qr[4]=c[0]*qscale; qr[5]=c[1]*qscale; qr[6]=d[0]*qscale; qr[7]=d[1]*qscale;
    }

    const int e0 = rp_[nl], e1 = rp_[nl+1];
    float m = -INFINITY, z = 0.f;
    float acc[8];
    #pragma unroll
    for (int i=0;i<8;i++) acc[i] = 0.f;

    for (int base = e0; base < e1; base += 4){
        const int cnt = min(4, e1 - base);
        int sl = sp_[min(base + (lane & 3), e1 - 1)];
        int src[4];
        #pragma unroll
        for (int j=0;j<4;j++) src[j] = __shfl(sl, j, 64);

        uint2v k2[4], v2[4];
        #pragma unroll
        for (int j=0;j<4;j++){
            if (j < cnt){
                const unsigned char* rp = f82 + (size_t)(brNN + src[j])*1536;
                k2[j] = *(const uint2v*)(rp + 512 + hd);
                v2[j] = *(const uint2v*)(rp + 1024 + hd);
            }
        }
        float dt[4];
        #pragma unroll
        for (int j=0;j<4;j++){
            float d = 0.f;
            if (j < cnt){
                floatx2 p0 = __builtin_amdgcn_cvt_pk_f32_fp8((int)k2[j][0], false);
                floatx2 p1 = __builtin_amdgcn_cvt_pk_f32_fp8((int)k2[j][0], true);
                floatx2 p2 = __builtin_amdgcn_cvt_pk_f32_fp8((int)k2[j][1], false);
                floatx2 p3 = __builtin_amdgcn_cvt_pk_f32_fp8((int)k2[j][1], true);
                d = qr[0]*p0[0] + qr[1]*p0[1] + qr[2]*p1[0] + qr[3]*p1[1]
                  + qr[4]*p2[0] + qr[5]*p2[1] + qr[6]*p3[0] + qr[7]*p3[1];
            }
            dt[j] = d;
        }
        #pragma unroll
        for (int o=32;o;o>>=1){
            #pragma unroll
            for (int j=0;j<4;j++) dt[j] += __shfl_xor(dt[j], o, 64);
        }
        float cm = -INFINITY;
        #pragma unroll
        for (int j=0;j<4;j++) if (j < cnt) cm = fmaxf(cm, dt[j]);
        const float mn = fmaxf(m, cm);
        const float cs = exp2f(m - mn);
        z *= cs;
        #pragma unroll
        for (int i=0;i<8;i++) acc[i] *= cs;
        #pragma unroll
        for (int j=0;j<4;j++){
            if (j < cnt){
                const float w = exp2f(dt[j] - mn);
                z += w;
                floatx2 p0 = __builtin_amdgcn_cvt_pk_f32_fp8((int)v2[j][0], false);
                floatx2 p1 = __builtin_amdgcn_cvt_pk_f32_fp8((int)v2[j][0], true);
                floatx2 p2 = __builtin_amdgcn_cvt_pk_f32_fp8((int)v2[j][1], false);
                floatx2 p3 = __builtin_amdgcn_cvt_pk_f32_fp8((int)v2[j][1], true);
                acc[0] += w*p0[0]; acc[1] += w*p0[1]; acc[2] += w*p1[0]; acc[3] += w*p1[1];
                acc[4] += w*p2[0]; acc[5] += w*p2[1]; acc[6] += w*p3[0]; acc[7] += w*p3[1];
            }
        }
        m = mn;
    }
    const float invz = 1.0f/(z + 1e-16f);
    const short8 sv = *(const short8*)(s2 + (size_t)n*512 + hd);
    #pragma unroll
    for (int i=0;i<8;i++) Sh[wave][hd + i] = lrelu_f(b2f(sv[i]) + acc[i]*invz);
    if (lane == 0) Sgid[wave] = br*BB + (br ? bt2[nl] : bt1[nl]);
    __syncthreads();

    // segmented max over the block's 4 rows, one atomic per (graph,col) run
    #pragma unroll
    for (int cc=0; cc<2; cc++){
        const int col = threadIdx.x*2 + cc;
        float mx = Sh[0][col];
        int gid = Sgid[0];
        #pragma unroll
        for (int r=1; r<4; r++){
            if (Sgid[r] == gid) mx = fmaxf(mx, Sh[r][col]);
            else {
                atomicMax(&gkey[(size_t)gid*1024 + gc0 + col], fkey(mx));
                gid = Sgid[r]; mx = Sh[r][col];
            }
        }
        atomicMax(&gkey[(size_t)gid*1024 + gc0 + col], fkey(mx));
    }
}

// ================= tail dense layer via MFMA (1024 threads = 16 waves) ===============
template<int R, int N, int ACT>
__device__ __forceinline__ void dense_mfma(
    const bf16* __restrict__ Wm, const float* __restrict__ bias,
    const float* __restrict__ gam, const float* __restrict__ bet, float bns,
    const float* A, int lda, float* C, int ldc, int K, int tid)
{
    constexpr int T   = N / 16;
    constexpr int TPW = (T + 15) / 16;
    const int wave = tid >> 6;
    const int lane = tid & 63;
    const int am = lane & 15;
    const int ak = (lane >> 4) * 8;
    const int KS = ((K + 31) & ~31) >> 5;

    floatx4 acc[TPW];
    #pragma unroll
    for (int tp=0; tp<TPW; tp++) acc[tp] = (floatx4){0.f,0.f,0.f,0.f};

    for (int ks = 0; ks < KS; ks++){
        short8 af = (short8){0,0,0,0,0,0,0,0};
        if (am < R){
            const float* ap = A + am*lda + ks*32 + ak;
            const floatx4 a0 = *(const floatx4*)ap;
            const floatx4 a1 = *(const floatx4*)(ap + 4);
            af[0]=f2b(a0[0]); af[1]=f2b(a0[1]); af[2]=f2b(a0[2]); af[3]=f2b(a0[3]);
            af[4]=f2b(a1[0]); af[5]=f2b(a1[1]); af[6]=f2b(a1[2]); af[7]=f2b(a1[3]);
        }
        #pragma unroll
        for (int tp=0; tp<TPW; tp++){
            const int tile = wave + tp*16;
            if (tile < T){
                const short8 bfv = *(const short8*)(Wm + ((size_t)(tile*KS + ks))*512 + lane*8);
                acc[tp] = __builtin_amdgcn_mfma_f32_16x16x32_bf16(af, bfv, acc[tp], 0,0,0);
            }
        }
    }
    const int crow = (lane >> 4) * 4;
    const int ccol = lane & 15;
    #pragma unroll
    for (int tp=0; tp<TPW; tp++){
        const int tile = wave + tp*16;
        if (tile < T){
            #pragma unroll
            for (int r=0; r<4; r++){
                const int row = crow + r;
                if (row < R){
                    const int n = tile*16 + ccol;
                    float v = acc[tp][r] + bias[n];
                    if (ACT==1) v = lrelu_f(v);
                    if (ACT==2) v = lrelu_f(v*bns*gam[n] + bet[n]);
                    C[row*ldc + n] = v;
                }
            }
        }
    }
    __syncthreads();
}

// ================= fused tail: graph-head + cell branch + head MLP, 2 graphs/block ====
__global__ __launch_bounds__(1024)
void tail_kernel(const unsigned int* __restrict__ gkey,  // [2*BB][1024] encoded maxes
                 const float* __restrict__ cell,         // [BB][954]
                 const bf16*  __restrict__ Wtp,          // packed tail weights
                 const float* __restrict__ bg1, const float* __restrict__ bg2,
                 const float* __restrict__ br1, const float* __restrict__ br2,
                 const float* __restrict__ br3,
                 const float* __restrict__ bf1,
                 const float* __restrict__ gbn1, const float* __restrict__ bbn1,
                 const float* __restrict__ bf2,
                 const float* __restrict__ gbn2, const float* __restrict__ bbn2,
                 const float* __restrict__ wf3, const float* __restrict__ bf3,
                 float bns, float* __restrict__ outp)
{
    __shared__ float Sg[4][1024];    // rows: lg*2 + br
    __shared__ float Sgh[4][512];
    __shared__ float Sgout[4][128];
    __shared__ float Scell[2][960];
    __shared__ float Sc1[2][512];
    __shared__ float Sc2[2][256];
    __shared__ float Sc3[2][128];
    __shared__ float Sxc[2][384];
    __shared__ float Sf1[2][512];
    __shared__ float Sf2[2][256];
    __shared__ float inv4[4], invc[2], invx[2];

    const int tid = threadIdx.x;
    const int wv  = tid >> 6;
    const int ln  = tid & 63;
    const int b0  = blockIdx.x * 2;

    {
        int idx = tid*4;                 // 0..4092
        int r = idx >> 10, c = idx & 1023;
        int lg = r >> 1, br = r & 1;
        const unsigned int* gp = gkey + (size_t)(br*BB + b0 + lg)*1024 + c;
        #pragma unroll
        for (int i=0;i<4;i++) Sg[r][c+i] = fdec(gp[i]);
    }
    for (int idx = tid; idx < 2*954; idx += 1024){
        int r = (idx >= 954) ? 1 : 0;
        int c = idx - r*954;
        Scell[r][c] = cell[(size_t)(b0 + r)*954 + c];
    }
    if (tid < 12){ int r = tid/6; Scell[r][954 + tid%6] = 0.f; }
    __syncthreads();

    if (wv < 2){
        float s = 0.f;
        for (int c = ln; c < 954; c += 64){ float v = Scell[wv][c]; s += v*v; }
        #pragma unroll
        for (int o=32;o;o>>=1) s += __shfl_xor(s, o, 64);
        if (ln == 0) invc[wv] = 1.0f / fmaxf(sqrtf(s), 1e-12f);
    }
    __syncthreads();
    #pragma unroll
    for (int r=0;r<2;r++)
        for (int c = tid; c < 954; c += 1024) Scell[r][c] *= invc[r];
    __syncthreads();

    dense_mfma<4,512,1>(Wtp+OG1, bg1, nullptr, nullptr, 1.f, &Sg[0][0],   1024, &Sgh[0][0],  512, 1024, tid);
    dense_mfma<4,128,0>(Wtp+OG2, bg2, nullptr, nullptr, 1.f, &Sgh[0][0],  512,  &Sgout[0][0],128, 512,  tid);
    dense_mfma<2,512,1>(Wtp+OR1, br1, nullptr, nullptr, 1.f, &Scell[0][0], 960, &Sc1[0][0],  512, 954,  tid);
    dense_mfma<2,256,1>(Wtp+OR2, br2, nullptr, nullptr, 1.f, &Sc1[0][0],   512, &Sc2[0][0],  256, 512,  tid);
    dense_mfma<2,128,0>(Wtp+OR3, br3, nullptr, nullptr, 1.f, &Sc2[0][0],   256, &Sc3[0][0],  128, 256,  tid);

    if (wv < 4){
        float a = Sgout[wv][ln], bq = Sgout[wv][ln+64];
        float s = a*a + bq*bq;
        #pragma unroll
        for (int o=32;o;o>>=1) s += __shfl_xor(s, o, 64);
        if (ln == 0) inv4[wv] = 1.0f / fmaxf(sqrtf(s), 1e-12f);
    }
    __syncthreads();

    if (tid < 768){
        int lg = tid / 384, j = tid - lg*384;
        float v;
        if (j < 128)      v = Sgout[lg*2+0][j]     * inv4[lg*2+0];
        else if (j < 256) v = Sgout[lg*2+1][j-128] * inv4[lg*2+1];
        else              v = Sc3[lg][j-256];
        Sxc[lg][j] = v;
    }
    __syncthreads();
    if (wv < 2){
        float s = 0.f;
        #pragma unroll
        for (int i=0;i<6;i++){ float v = Sxc[wv][ln + i*64]; s += v*v; }
        #pragma unroll
        for (int o=32;o;o>>=1) s += __shfl_xor(s, o, 64);
        if (ln == 0) invx[wv] = 1.0f / fmaxf(sqrtf(s), 1e-12f);
    }
    __syncthreads();
    if (tid < 768){
        int lg = tid / 384, j = tid - lg*384;
        Sxc[lg][j] *= invx[lg];
    }
    __syncthreads();

    dense_mfma<2,512,2>(Wtp+OF1, bf1, gbn1, bbn1, bns, &Sxc[0][0], 384, &Sf1[0][0], 512, 384, tid);
    dense_mfma<2,256,2>(Wtp+OF2, bf2, gbn2, bbn2, bns, &Sf1[0][0], 512, &Sf2[0][0], 256, 512, tid);

    if (wv < 2){
        float s = 0.f;
        #pragma unroll
        for (int i=0;i<4;i++){ int c = ln + i*64; s += Sf2[wv][c]*wf3[c]; }
        #pragma unroll
        for (int o=32;o;o>>=1) s += __shfl_xor(s, o, 64);
        if (ln == 0) outp[b0 + wv] = 1.0f/(1.0f + expf(-(s + bf3[0])));
    }
}

extern "C" void kernel_launch(void* const* d_in, const int* in_sizes, int n_in,
                              void* d_out, int out_size, void* d_ws, size_t ws_size,
                              hipStream_t stream)
{
    const float* x1  = (const float*)d_in[0];
    const int*   ei1 = (const int*)  d_in[1];
    const int*   bt1 = (const int*)  d_in[2];
    const float* x2  = (const float*)d_in[3];
    const int*   ei2 = (const int*)  d_in[4];
    const int*   bt2 = (const int*)  d_in[5];
    const float* cell= (const float*)d_in[6];
    const float* wq1=(const float*)d_in[7];  const float* bq1=(const float*)d_in[8];
    const float* wk1=(const float*)d_in[9];  const float* bk1=(const float*)d_in[10];
    const float* wv1=(const float*)d_in[11]; const float* bv1=(const float*)d_in[12];
    const float* ws1=(const float*)d_in[13]; const float* bs1=(const float*)d_in[14];
    const float* wq2=(const float*)d_in[15]; const float* bq2=(const float*)d_in[16];
    const float* wk2=(const float*)d_in[17]; const float* bk2=(const float*)d_in[18];
    const float* wv2=(const float*)d_in[19]; const float* bv2=(const float*)d_in[20];
    const float* ws2=(const float*)d_in[21]; const float* bs2q=(const float*)d_in[22];
    const float* wg1=(const float*)d_in[23]; const float* bg1=(const float*)d_in[24];
    const float* wg2=(const float*)d_in[25]; const float* bg2=(const float*)d_in[26];
    const float* wr1=(const float*)d_in[27]; const float* br1=(const float*)d_in[28];
    const float* wr2=(const float*)d_in[29]; const float* br2=(const float*)d_in[30];
    const float* wr3=(const float*)d_in[31]; const float* br3=(const float*)d_in[32];
    const float* wf1=(const float*)d_in[33]; const float* bf1=(const float*)d_in[34];
    const float* gbn1=(const float*)d_in[35];const float* bbn1=(const float*)d_in[36];
    const float* wf2=(const float*)d_in[37]; const float* bf2=(const float*)d_in[38];
    const float* gbn2=(const float*)d_in[39];const float* bbn2=(const float*)d_in[40];
    const float* wf3=(const float*)d_in[41]; const float* bf3=(const float*)d_in[42];
    float* outp = (float*)d_out;
    (void)in_sizes; (void)n_in; (void)out_size; (void)ws_size;

    const float BNS = 1.0f / sqrtf(1.0f + 1e-5f);

    // ---- workspace arena (~107 MB peak; BIG region phase-aliased) ----
    char* basep = (char*)d_ws;
    size_t off = 0;
    auto alloc = [&](size_t nbytes)->char* {
        char* p = basep + off;
        off += (nbytes + 255) & ~(size_t)255;
        return p;
    };
    int* rowptr2  = (int*)  alloc((size_t)2*(NN+1)*4);
    int* rowcur2  = (int*)  alloc((size_t)2*(NN+1)*4);
    int* cnt2     = (int*)  alloc((size_t)2*NN*4);
    int* srcs2    = (int*)  alloc((size_t)2*EE*4);
    unsigned int* gkey = (unsigned int*)alloc((size_t)2*BB*1024*4);  // pooled-max keys
    float* b1c    = (float*)alloc((size_t)1024*4);
    float* b2c    = (float*)alloc((size_t)4096*4);
    bf16* W1t     = (bf16*) alloc((size_t)1024*96*2);
    bf16* W2t     = (bf16*) alloc((size_t)2*2048*256*2);
    bf16* Wtp     = (bf16*) alloc((size_t)TAILW_TOTAL*2);
    bf16* h1      = (bf16*) alloc((size_t)2*NN*256*2);    // layer-1 out, both branches
    // BIG phase-aliased region (80 MB):
    //   phase1: xa [2NN,96] bf16 (6.3MB) | s1 [2NN,256] bf16 (16MB) | f81 [2NN,768] u8 (24MB)
    //   phase2: s2 [2NN,512] bf16 (32MB) | f82 [2NN,1536] u8 (48MB)
    char* BIG     = alloc((size_t)2*NN*512*2 + (size_t)2*NN*1536);
    bf16* xa      = (bf16*)BIG;
    bf16* s1a     = (bf16*)(BIG + 6291456);
    unsigned char* f81 = (unsigned char*)(BIG + 6291456 + 16777216);
    bf16* s2a     = (bf16*)BIG;
    unsigned char* f82 = (unsigned char*)(BIG + (size_t)2*NN*512*2);

    // ---- prep (1 mega dispatch) + CSR ----
    (void)hipMemsetAsync(cnt2, 0, (size_t)2*NN*4, stream);
    prep_mega_kernel<<<P_GK/256,256,0,stream>>>(
        wq1,wk1,wv1,ws1, bq1,bk1,bv1,bs1,
        wq2,wk2,wv2,ws2, bq2,bk2,bv2,bs2q,
        wg1,wg2,wr1,wr2,wr3,wf1,wf2,
        x1,x2,
        W1t,b1c,W2t,b2c, Wtp, xa, gkey);
    hist_kernel<<<2*EE/256,256,0,stream>>>(ei1, ei2, cnt2);
    scan_kernel<<<2,1024,0,stream>>>(cnt2, rowptr2, rowcur2);
    scatter_kernel<<<2*EE/256,256,0,stream>>>(ei1, ei2, rowcur2, srcs2);

    // ---- layer 1 (both branches stacked): [2NN,96]x[96,1024], s bf16 / q,k,v fp8 ----
    mfma_gemm<<<dim3(2*NN/128, 8),256,0,stream>>>(xa,96, W1t,96, b1c,
                                                  s1a,256, f81,768, 256, 96);
    attn128_f8<<<2*NN*2/4,256,0,stream>>>(s1a, f81, h1, rowptr2, srcs2);

    // ---- layer 2 (branches stacked): per head GEMM + attn+pool fused ----
    for (int h=0; h<2; h++){
        mfma_gemm<<<dim3(2*NN/128, 16),256,0,stream>>>(
            h1, 256, W2t + (size_t)h*2048*256, 256,
            b2c + h*2048, s2a,512, f82,1536, 512, 256);
        attn512_f8<<<2*NN/4,256,0,stream>>>(s2a, f82, rowptr2, srcs2, bt1, bt2,
                                            gkey, h*512);
    }

    // ---- fused tail: graph-head + cell + head MLP + sigmoid, one dispatch ----
    tail_kernel<<<BB/2,1024,0,stream>>>(gkey, cell, Wtp,
                                        bg1,bg2, br1,br2,br3,
                                        bf1,gbn1,bbn1, bf2,gbn2,bbn2, wf3,bf3,
                                        BNS, outp);
}